// Round 5
// baseline (194.344 us; speedup 1.0000x reference)
//
#include <hip/hip_runtime.h>

// CrossAttentionPro on MI355X — Round 17:
//  Revert flash to the R15 shape that measured best (48 KB LDS: K dbuf +
//  V single => 3 blocks/CU; 768 blocks x 8 tiles balanced), but with only
//  2 barriers/tile: V(t) staged at tile top right after barrier A (which
//  already guarantees PV(t-1) reads done), killing R15's post-PV barrier.
//  Keep R16's combine fusion: att0 writes unnormalized O f32 (2 s-half
//  slabs) + row-sum L[2]; proj GEMM stages A = DH2 - (O0+O1)/(l0+l1) in
//  registers (iteration t <=> head h=t), counted vmcnt.
//  Kept: swapped-operand S^T=mfma(K,Q), no-max exp2 softmax, pkrtz+permlane
//  P-frag butterfly, BK=64 dbuf counted-vmcnt GEMMs, fused qkv epilogue,
//  wtq2 fusion, bit-packed mask, XCD z-locality, s_setprio on MFMA clusters.
//  R16 lesson (occupancy 13.9%): at this sync density 3 blocks/CU + balanced
//  768-grid beats fewer barriers at 2 blocks/CU.

typedef _Float16 half_t;
typedef _Float16 half8 __attribute__((ext_vector_type(8)));
typedef _Float16 half4v __attribute__((ext_vector_type(4)));
typedef float floatx4 __attribute__((ext_vector_type(4)));
typedef int int4v __attribute__((ext_vector_type(4)));

constexpr int Bc = 2, Tc = 2048, Mc = 1024, Cc = 512, Hc = 8, Dc = 64;
constexpr long BTC = (long)Bc * Tc * Cc;
constexpr long ZT  = (long)Bc * Hc * Tc;
constexpr float S1 = 0.18033688f;                 // 0.125 * log2(e)

enum { EPI_F16STORE = 0, EPI_QKV_XY = 1, EPI_PROJ = 2 };

struct EpiParams {
  half_t* h0;        // QXs  / f16 dest
  half_t* h1;        // KX
  half_t* h2;        // VXT
  half_t* h3;        // QYT
  half_t* h4;        // KY
  half_t* h5;        // KYT
  half_t* h6;        // VYT
  float* f0;
  const float* bias;
  float scale;
  int ldc;
  long bstride;
};

// async global->LDS, 16B per lane; dst must be wave-uniform base + lane*16.
__device__ __forceinline__ void gld_lds16(const half_t* g, half_t* l) {
  __builtin_amdgcn_global_load_lds(
      (const __attribute__((address_space(1))) void*)g,
      (__attribute__((address_space(3))) void*)l, 16, 0, 0);
}

// pack 2 f32 -> 2 f16 (RTZ) as one u32
__device__ __forceinline__ int pkrtz(float a, float b) {
  return __builtin_bit_cast(int, __builtin_amdgcn_cvt_pkrtz(a, b));
}
// v_permlane16_swap: a.row1<->b.row0, a.row3<->b.row2 (rows = 16-lane groups)
__device__ __forceinline__ void pl16(int& a, int& b) {
  asm volatile("v_permlane16_swap_b32 %0, %1" : "+v"(a), "+v"(b));
}
// v_permlane32_swap: a.rows{2,3} <-> b.rows{0,1}
__device__ __forceinline__ void pl32(int& a, int& b) {
  asm volatile("v_permlane32_swap_b32 %0, %1" : "+v"(a), "+v"(b));
}

// ---------------------------------------------------------------- GEMM (NT)
// C[r,c] = sum_k A[r,k]*Bt[c,k]. BK=64 double-buffered async staging with
// counted vmcnt, swizzled chunks (conflict-free ds_read_b128).
template <int BM, int BN, int WMG, int WNG, int EPI>
__global__ __launch_bounds__(256) void gemm_nt(
    const half_t* __restrict__ A, const half_t* __restrict__ Bt,
    int K, int lda, int ldb, long bsA, long bsB, EpiParams ep)
{
  constexpr int BK = 64;
  constexpr int WTM = BM / WMG, WTN = BN / WNG;
  constexpr int MI = WTM / 16, NI = WTN / 16;
  constexpr int AIT = BM * BK / 8 / 256;
  constexpr int BIT = BN * BK / 8 / 256;
  constexpr int NLD = AIT + BIT;
  __shared__ __align__(16) half_t As[2][BM * BK];
  __shared__ __align__(16) half_t Bs[2][BN * BK];

  const int tid = threadIdx.x;
  const int lane = tid & 63;
  const int wave = tid >> 6;
  const int wm = wave / WNG, wn = wave % WNG;
  const int r16 = lane & 15, g = lane >> 4;
  const int z = blockIdx.z;
  const long m0 = (long)blockIdx.y * BM;
  const long n0 = (long)blockIdx.x * BN;
  const half_t* Abase = A + (long)z * bsA + m0 * (long)lda;
  const half_t* Bbase = Bt + (long)z * bsB + n0 * (long)ldb;

  const int rA = wm * WTM + r16;
  const int rB = wn * WTN + r16;

  floatx4 acc[MI][NI];
#pragma unroll
  for (int mi = 0; mi < MI; ++mi)
#pragma unroll
    for (int ni = 0; ni < NI; ++ni)
      acc[mi][ni] = floatx4{0.f, 0.f, 0.f, 0.f};

  auto stage = [&](int kt, int buf) {
#pragma unroll
    for (int i = 0; i < AIT; ++i) {
      const int c = tid + i * 256;
      const int row = c >> 3, js = c & 7;
      const int jg = js ^ (row & 7);
      gld_lds16(Abase + (long)row * lda + kt + jg * 8, &As[buf][c * 8]);
    }
#pragma unroll
    for (int i = 0; i < BIT; ++i) {
      const int c = tid + i * 256;
      const int row = c >> 3, js = c & 7;
      const int jg = js ^ (row & 7);
      gld_lds16(Bbase + (long)row * ldb + kt + jg * 8, &Bs[buf][c * 8]);
    }
  };

  const int NIT = K / BK;
  stage(0, 0);
  asm volatile("" ::: "memory");

  for (int it = 0; it < NIT; ++it) {
    const bool hn = (it + 1 < NIT);
    if (hn) stage((it + 1) * BK, (it + 1) & 1);
    asm volatile("" ::: "memory");
    if (hn) {
      if constexpr (NLD == 6) asm volatile("s_waitcnt vmcnt(6)" ::: "memory");
      else if constexpr (NLD == 4) asm volatile("s_waitcnt vmcnt(4)" ::: "memory");
      else if constexpr (NLD == 8) asm volatile("s_waitcnt vmcnt(8)" ::: "memory");
      else asm volatile("s_waitcnt vmcnt(0)" ::: "memory");
    } else {
      asm volatile("s_waitcnt vmcnt(0)" ::: "memory");
    }
    __builtin_amdgcn_s_barrier();
    asm volatile("" ::: "memory");

    const half_t* Ab = As[it & 1];
    const half_t* Bb = Bs[it & 1];
    half8 aF[MI][2], bF[NI][2];
#pragma unroll
    for (int mi = 0; mi < MI; ++mi)
#pragma unroll
      for (int k2 = 0; k2 < 2; ++k2)
        aF[mi][k2] = *reinterpret_cast<const half8*>(
            &Ab[(rA + mi * 16) * BK + ((k2 * 4 + g) ^ (r16 & 7)) * 8]);
#pragma unroll
    for (int ni = 0; ni < NI; ++ni)
#pragma unroll
      for (int k2 = 0; k2 < 2; ++k2)
        bF[ni][k2] = *reinterpret_cast<const half8*>(
            &Bb[(rB + ni * 16) * BK + ((k2 * 4 + g) ^ (r16 & 7)) * 8]);
    __builtin_amdgcn_s_setprio(1);
#pragma unroll
    for (int k2 = 0; k2 < 2; ++k2)
#pragma unroll
      for (int mi = 0; mi < MI; ++mi)
#pragma unroll
        for (int ni = 0; ni < NI; ++ni)
          acc[mi][ni] = __builtin_amdgcn_mfma_f32_16x16x32_f16(
              aF[mi][k2], bF[ni][k2], acc[mi][ni], 0, 0, 0);
    __builtin_amdgcn_s_setprio(0);
    asm volatile("s_waitcnt lgkmcnt(0)" ::: "memory");
    __builtin_amdgcn_s_barrier();
    asm volatile("" ::: "memory");
  }

  // epilogue: C/D layout col=lane&15, row=(lane>>4)*4+reg  [m89-verified]
#pragma unroll
  for (int mi = 0; mi < MI; ++mi) {
#pragma unroll
    for (int ni = 0; ni < NI; ++ni) {
#pragma unroll
      for (int reg = 0; reg < 4; ++reg) {
        const int r = (int)m0 + wm * WTM + mi * 16 + g * 4 + reg;
        const int c = (int)n0 + wn * WTN + ni * 16 + r16;
        const float v = acc[mi][ni][reg];
        if constexpr (EPI == EPI_F16STORE) {
          ep.h0[(long)z * ep.bstride + (long)r * ep.ldc + c] = (half_t)(v * ep.scale);
        } else if constexpr (EPI == EPI_QKV_XY) {
          const float val = v + ep.bias[c];
          const int which = c >> 9;     // 0=q 1=k 2=v
          const int cc2 = c & 511;
          const int h = cc2 >> 6, d = cc2 & 63;
          if (r < Bc * Tc) {            // x rows
            const int b = r >> 11, t = r & (Tc - 1);
            const long bh = (long)(b * Hc + h);
            if (which == 0)      ep.h0[(bh * Tc + t) * Dc + d] = (half_t)(val * S1);  // QXs (log2e folded)
            else if (which == 1) ep.h1[(bh * Tc + t) * Dc + d] = (half_t)val;         // KX
            else                 ep.h2[(bh * Dc + d) * Tc + t] = (half_t)val;         // VXT
          } else {                      // y rows
            const int r2 = r - Bc * Tc;
            const int b = r2 >> 10, t = r2 & (Mc - 1);
            const long bh = (long)(b * Hc + h);
            if (which == 0)      ep.h3[(bh * Dc + d) * Mc + t] = (half_t)(val * 0.125f); // QYTs
            else if (which == 1) { ep.h4[(bh * Mc + t) * Dc + d] = (half_t)val;          // KY
                                   ep.h5[(bh * Dc + d) * Mc + t] = (half_t)val; }        // KYT
            else                 ep.h6[(bh * Dc + d) * Mc + t] = (half_t)val;            // VYT
          }
        } else {  // EPI_PROJ
          ep.f0[(long)r * Cc + c] = v + ep.bias[c];
        }
      }
    }
  }
}

// --------------------------------------------- fused WT+Q2 kernel
// grid (16 t-chunks, 16 z). Phase 1: WT[64][64] = 0.125 * QYTs[z] KYT[z]^T
// (K=1024, pipelined dbuf) -> LDS in phase-2 fragment layout. Phase 2:
// Q2[z, t0..t0+127, :] = QXs * WT^T (K=64, single tile, A staged async).
__global__ __launch_bounds__(256) void wtq2(
    const half_t* __restrict__ QYT, const half_t* __restrict__ KYT,
    const half_t* __restrict__ QX, half_t* __restrict__ Q2)
{
  __shared__ __align__(16) half_t As[2][4096];
  __shared__ __align__(16) half_t Bs[2][4096];
  __shared__ __align__(16) half_t WTs[4096];
  const int tid = threadIdx.x, lane = tid & 63, wave = tid >> 6;
  const int wm = wave >> 1, wn = wave & 1;
  const int r16 = lane & 15, g = lane >> 4;
  const int z = blockIdx.y;
  const int t0 = blockIdx.x * 128;
  const half_t* Aq = QYT + (long)z * Dc * Mc;
  const half_t* Bk = KYT + (long)z * Dc * Mc;

  auto stage1 = [&](int kt, int buf) {
#pragma unroll
    for (int i = 0; i < 2; ++i) {
      const int c = tid + i * 256;
      const int row = c >> 3, js = c & 7, jg = js ^ (row & 7);
      gld_lds16(Aq + (long)row * Mc + kt + jg * 8, &As[buf][c * 8]);
    }
#pragma unroll
    for (int i = 0; i < 2; ++i) {
      const int c = tid + i * 256;
      const int row = c >> 3, js = c & 7, jg = js ^ (row & 7);
      gld_lds16(Bk + (long)row * Mc + kt + jg * 8, &Bs[buf][c * 8]);
    }
  };

  floatx4 acc[2][2];
#pragma unroll
  for (int mi = 0; mi < 2; ++mi)
#pragma unroll
    for (int ni = 0; ni < 2; ++ni) acc[mi][ni] = floatx4{0.f, 0.f, 0.f, 0.f};

  const int rA = wm * 32 + r16, rB = wn * 32 + r16;
  stage1(0, 0);
  asm volatile("" ::: "memory");
  for (int it = 0; it < 16; ++it) {
    const bool hn = (it < 15);
    if (hn) stage1((it + 1) * 64, (it + 1) & 1);
    asm volatile("" ::: "memory");
    if (hn) asm volatile("s_waitcnt vmcnt(4)" ::: "memory");
    else    asm volatile("s_waitcnt vmcnt(0)" ::: "memory");
    __builtin_amdgcn_s_barrier();
    asm volatile("" ::: "memory");
    const half_t* Ab = As[it & 1];
    const half_t* Bb = Bs[it & 1];
    half8 aF[2][2], bF[2][2];
#pragma unroll
    for (int mi = 0; mi < 2; ++mi)
#pragma unroll
      for (int k2 = 0; k2 < 2; ++k2)
        aF[mi][k2] = *reinterpret_cast<const half8*>(
            &Ab[(rA + mi * 16) * 64 + ((k2 * 4 + g) ^ (r16 & 7)) * 8]);
#pragma unroll
    for (int ni = 0; ni < 2; ++ni)
#pragma unroll
      for (int k2 = 0; k2 < 2; ++k2)
        bF[ni][k2] = *reinterpret_cast<const half8*>(
            &Bb[(rB + ni * 16) * 64 + ((k2 * 4 + g) ^ (r16 & 7)) * 8]);
    __builtin_amdgcn_s_setprio(1);
#pragma unroll
    for (int k2 = 0; k2 < 2; ++k2)
#pragma unroll
      for (int mi = 0; mi < 2; ++mi)
#pragma unroll
        for (int ni = 0; ni < 2; ++ni)
          acc[mi][ni] = __builtin_amdgcn_mfma_f32_16x16x32_f16(
              aF[mi][k2], bF[ni][k2], acc[mi][ni], 0, 0, 0);
    __builtin_amdgcn_s_setprio(0);
    asm volatile("s_waitcnt lgkmcnt(0)" ::: "memory");
    __builtin_amdgcn_s_barrier();
    asm volatile("" ::: "memory");
  }

  // phase-2 A stage (As fully free after final barrier): QX rows t0..t0+127
  half_t* P2 = &As[0][0];
#pragma unroll
  for (int i = 0; i < 4; ++i) {
    const int c = tid + i * 256;
    const int row = c >> 3, js = c & 7, jg = js ^ (row & 7);
    gld_lds16(QX + ((long)z * Tc + t0 + row) * 64 + jg * 8, P2 + c * 8);
  }
  // WT -> LDS f16 in phase-2 fragment layout (chunk swizzle js^(row&7))
#pragma unroll
  for (int mi = 0; mi < 2; ++mi)
#pragma unroll
    for (int ni = 0; ni < 2; ++ni)
#pragma unroll
      for (int reg = 0; reg < 4; ++reg) {
        const int r = wm * 32 + mi * 16 + g * 4 + reg;   // d2
        const int c = wn * 32 + ni * 16 + r16;           // d1
        WTs[r * 64 + (((c >> 3) ^ (r & 7)) << 3) + (c & 7)] =
            (half_t)(acc[mi][ni][reg] * 0.125f);
      }
  __syncthreads();   // drains vmcnt (QX stage) + lgkm (WTs writes)

  // phase 2: per wave 32 t-rows, full 64 d2 cols, K=64
  floatx4 a2[2][4];
#pragma unroll
  for (int mi = 0; mi < 2; ++mi)
#pragma unroll
    for (int ni = 0; ni < 4; ++ni) a2[mi][ni] = floatx4{0.f, 0.f, 0.f, 0.f};
  const int rA2 = wave * 32 + r16;
  half8 aF2[2][2], bF2[4][2];
#pragma unroll
  for (int mi = 0; mi < 2; ++mi)
#pragma unroll
    for (int k2 = 0; k2 < 2; ++k2)
      aF2[mi][k2] = *reinterpret_cast<const half8*>(
          &P2[(rA2 + mi * 16) * 64 + ((k2 * 4 + g) ^ (r16 & 7)) * 8]);
#pragma unroll
  for (int ni = 0; ni < 4; ++ni)
#pragma unroll
    for (int k2 = 0; k2 < 2; ++k2)
      bF2[ni][k2] = *reinterpret_cast<const half8*>(
          &WTs[(ni * 16 + r16) * 64 + ((k2 * 4 + g) ^ (r16 & 7)) * 8]);
#pragma unroll
  for (int k2 = 0; k2 < 2; ++k2)
#pragma unroll
    for (int mi = 0; mi < 2; ++mi)
#pragma unroll
      for (int ni = 0; ni < 4; ++ni)
        a2[mi][ni] = __builtin_amdgcn_mfma_f32_16x16x32_f16(
            aF2[mi][k2], bF2[ni][k2], a2[mi][ni], 0, 0, 0);
#pragma unroll
  for (int mi = 0; mi < 2; ++mi)
#pragma unroll
    for (int ni = 0; ni < 4; ++ni)
#pragma unroll
      for (int reg = 0; reg < 4; ++reg) {
        const int t = t0 + wave * 32 + mi * 16 + g * 4 + reg;
        const int c = ni * 16 + r16;
        Q2[((long)z * Tc + t) * 64 + c] = (half_t)a2[mi][ni][reg];
      }
}

// ------------------------------------------------------------ flash staging
__device__ __forceinline__ void stageK128(const half_t* Kz, int s0, half_t* dst, int tid) {
#pragma unroll
  for (int i = 0; i < 4; ++i) {
    const int c = tid + i * 256;
    const int row = c >> 3, js = c & 7;
    const int jg = js ^ (row & 7);
    gld_lds16(Kz + (long)(s0 + row) * 64 + jg * 8, dst + c * 8);
  }
}
__device__ __forceinline__ void stageV128(const half_t* Vz, int s0, int Slen, half_t* dst, int tid) {
#pragma unroll
  for (int i = 0; i < 4; ++i) {
    const int c = tid + i * 256;
    const int row = c >> 4, js = c & 15;
    const int jg = js ^ (row & 15);
    gld_lds16(Vz + (long)row * Slen + s0 + jg * 8, dst + c * 8);
  }
}

// --------------------------------------------------------- flash body (MI=2)
// 128 q-rows/block, 8 s-tiles of 128 over [sbeg, sbeg+scount). Scores in
// log2 domain (log2e folded into Q), no-max softmax. 2 barriers/tile:
//  top: vmcnt(0) [K(t) issued mid tile t-1 -> free] ; barrier A [also
//  guarantees PV(t-1) reads done -> Vb restage safe] ; mask loads ;
//  stage V(t) ; QK on K dbuf ; issue K(t+1) ; softmax ; vmcnt(4) [V(t)
//  arrived, K(t+1) flying] ; barrier B ; PV.
// PARTIAL: unnormalized O f32 -> PO + row-sum -> Lp. else normalized f16.
template <bool MASKED, bool PARTIAL>
__device__ __forceinline__ void flash_body(
    const half_t* __restrict__ Qp, const half_t* __restrict__ Kp,
    const half_t* __restrict__ Vp, const unsigned char* __restrict__ mpk,
    float* __restrict__ PO, float* __restrict__ Lp, half_t* __restrict__ outF,
    int Slen, int sbeg, int scount, int z, int q0,
    half_t* Kb0, half_t* Kb1, half_t* Vb)
{
  const int tid = threadIdx.x, lane = tid & 63, w = tid >> 6;
  const int r16 = lane & 15, g = lane >> 4;
  const int b = z >> 3, h = z & 7;
  const int NT = Slen >> 7;
  const half_t* Qz = Qp + ((long)z * Tc + q0) * 64;
  const half_t* Kz = Kp + (long)z * Slen * 64;
  const half_t* Vz = Vp + (long)z * 64 * Slen;

  stageK128(Kz, sbeg, Kb0, tid);
  asm volatile("" ::: "memory");

  half8 aQ[2][2];
#pragma unroll
  for (int mi = 0; mi < 2; ++mi)
#pragma unroll
    for (int k2 = 0; k2 < 2; ++k2)
      aQ[mi][k2] = *reinterpret_cast<const half8*>(
          Qz + (w * 32 + mi * 16 + r16) * 64 + k2 * 32 + g * 8);

  floatx4 oaccT[2][4];
  float lsum[2];
#pragma unroll
  for (int mi = 0; mi < 2; ++mi) {
    lsum[mi] = 0.f;
#pragma unroll
    for (int no = 0; no < 4; ++no) oaccT[mi][no] = floatx4{0.f, 0.f, 0.f, 0.f};
  }

  const int nt = scount >> 7;
  for (int t = 0; t < nt; ++t) {
    const bool hn = (t + 1 < nt);
    const int s0 = sbeg + (t << 7);
    // K(t) ready (issued mid tile t-1); barrier A: PV(t-1) done -> Vb safe
    asm volatile("s_waitcnt vmcnt(0)" ::: "memory");
    __builtin_amdgcn_s_barrier();
    asm volatile("" ::: "memory");

    // mask loads first so later waits don't serialize on them
    unsigned int mb32[2];
    if constexpr (MASKED) {
      const int tile = s0 >> 7;
#pragma unroll
      for (int mi = 0; mi < 2; ++mi) {
        const int q = q0 + w * 32 + mi * 16 + r16;
        mb32[mi] = *reinterpret_cast<const unsigned int*>(
            mpk + ((long)q * NT + tile) * 16 + 4 * g);
      }
    }
    // stage V(t); arrival enforced by vmcnt(4) before PV
    stageV128(Vz, s0, Slen, Vb, tid);
    asm volatile("" ::: "memory");

    // S^T = K Q^T : 16 b128 reads feed 32 MFMAs
    floatx4 sacc[2][8];
#pragma unroll
    for (int mi = 0; mi < 2; ++mi)
#pragma unroll
      for (int ni = 0; ni < 8; ++ni) sacc[mi][ni] = floatx4{0.f, 0.f, 0.f, 0.f};
    const half_t* Kc = (t & 1) ? Kb1 : Kb0;
    __builtin_amdgcn_s_setprio(1);
#pragma unroll
    for (int ni = 0; ni < 8; ++ni) {
      const int rB = ni * 16 + r16;
      const half8 b0 = *reinterpret_cast<const half8*>(&Kc[rB * 64 + (g ^ (rB & 7)) * 8]);
      const half8 b1 = *reinterpret_cast<const half8*>(&Kc[rB * 64 + ((4 + g) ^ (rB & 7)) * 8]);
#pragma unroll
      for (int mi = 0; mi < 2; ++mi) {
        sacc[mi][ni] = __builtin_amdgcn_mfma_f32_16x16x32_f16(b0, aQ[mi][0], sacc[mi][ni], 0, 0, 0);
        sacc[mi][ni] = __builtin_amdgcn_mfma_f32_16x16x32_f16(b1, aQ[mi][1], sacc[mi][ni], 0, 0, 0);
      }
    }
    __builtin_amdgcn_s_setprio(0);
    // prefetch K(t+1) into the other K buffer; lands under softmax+PV
    if (hn) stageK128(Kz, s0 + 128, (t & 1) ? Kb0 : Kb1, tid);
    asm volatile("" ::: "memory");

    // in-register softmax, no running max: P = exp2(S) directly
#pragma unroll
    for (int mi = 0; mi < 2; ++mi) {
      if constexpr (MASKED) {
        if (mb32[mi] != 0xffffffffu) {
#pragma unroll
          for (int reg = 0; reg < 4; ++reg)
#pragma unroll
            for (int ni = 0; ni < 8; ++ni)
              if (!((mb32[mi] >> (reg * 8 + ni)) & 1)) sacc[mi][ni][reg] = -__builtin_inff();
        }
      }
      float ls = 0.f;
#pragma unroll
      for (int ni = 0; ni < 8; ++ni)
#pragma unroll
        for (int reg = 0; reg < 4; ++reg) {
          const float e = __builtin_amdgcn_exp2f(sacc[mi][ni][reg]);
          sacc[mi][ni][reg] = e;
          ls += e;
        }
      lsum[mi] += ls;
    }

    // V(t) ready (K(t+1) = newest 4 still in flight when hn)
    if (hn) { asm volatile("s_waitcnt vmcnt(4)" ::: "memory"); }
    else    { asm volatile("s_waitcnt vmcnt(0)" ::: "memory"); }
    __builtin_amdgcn_s_barrier();
    asm volatile("" ::: "memory");

    // O^T += V^T P^T : P-fragment built in-register via pkrtz + permlane
#pragma unroll
    for (int c = 0; c < 4; ++c) {
      half8 bVv[4];
#pragma unroll
      for (int no = 0; no < 4; ++no) {
        const int rV = no * 16 + r16;
        bVv[no] = *reinterpret_cast<const half8*>(
            &Vb[rV * 128 + ((c * 4 + g) ^ (rV & 15)) * 8]);
      }
#pragma unroll
      for (int mi = 0; mi < 2; ++mi) {
        // butterfly P^T frag: target word p_t at lane g <-
        // pk[2c+(g>>1)][p_t&1] of lane 2(g&1)+(p_t>>1)
        int x0 = pkrtz(sacc[mi][2 * c][0],     sacc[mi][2 * c][1]);
        int x1 = pkrtz(sacc[mi][2 * c][2],     sacc[mi][2 * c][3]);
        int x2 = pkrtz(sacc[mi][2 * c + 1][0], sacc[mi][2 * c + 1][1]);
        int x3 = pkrtz(sacc[mi][2 * c + 1][2], sacc[mi][2 * c + 1][3]);
        pl32(x0, x2); pl32(x1, x3);   // resolve g1 <-> ni bit
        pl16(x0, x2); pl16(x1, x3);   // resolve g0 <-> word bit
        int4v wv; wv[0] = x0; wv[1] = x1; wv[2] = x2; wv[3] = x3;
        const half8 aP = __builtin_bit_cast(half8, wv);
        __builtin_amdgcn_s_setprio(1);
#pragma unroll
        for (int no = 0; no < 4; ++no)
          oaccT[mi][no] = __builtin_amdgcn_mfma_f32_16x16x32_f16(bVv[no], aP, oaccT[mi][no], 0, 0, 0);
        __builtin_amdgcn_s_setprio(0);
      }
    }
  }

  // all waves past last PV -> Vb reusable as per-wave slab
  __builtin_amdgcn_s_barrier();
  asm volatile("" ::: "memory");

  float ls2[2];
#pragma unroll
  for (int mi = 0; mi < 2; ++mi) {
    float ls = lsum[mi];
    ls += __shfl_xor(ls, 16);
    ls += __shfl_xor(ls, 32);
    ls2[mi] = ls;
  }
  float* slab = reinterpret_cast<float*>(Vb) + w * 1024;
#pragma unroll
  for (int mi = 0; mi < 2; ++mi) {
    const int tq = q0 + w * 32 + mi * 16;
    if constexpr (PARTIAL) {
      if (lane < 16) Lp[(long)z * Tc + tq + r16] = ls2[mi];
    }
    const float sc = PARTIAL ? 1.f : (1.f / ls2[mi]);
#pragma unroll
    for (int no = 0; no < 4; ++no) {
      floatx4 v = oaccT[mi][no];
      if constexpr (!PARTIAL) v *= sc;
      *reinterpret_cast<floatx4*>(&slab[r16 * 64 + no * 16 + (g ^ (r16 & 3)) * 4]) = v;
    }
#pragma unroll
    for (int it = 0; it < 4; ++it) {
      const int q2 = it * 4 + g;
      const int d4 = r16;
      const floatx4 v = *reinterpret_cast<const floatx4*>(
          &slab[q2 * 64 + (d4 >> 2) * 16 + ((d4 & 3) ^ (q2 & 3)) * 4]);
      const long off = ((long)(b * Tc + tq + q2)) * Cc + h * 64 + d4 * 4;
      if constexpr (PARTIAL) {
        *reinterpret_cast<floatx4*>(&PO[off]) = v;
      } else {
        half4v hh; hh[0] = (half_t)v[0]; hh[1] = (half_t)v[1];
        hh[2] = (half_t)v[2]; hh[3] = (half_t)v[3];
        *reinterpret_cast<half4v*>(&outF[off]) = hh;
      }
    }
  }
}

// 768 blocks, each exactly 8 s-tiles (= 3 blocks/CU, one balanced round):
//  bx < 512:  att0 (chained, masked), s-half sh=(bx>>4)&1, unnormalized f32+L
//  bx >= 512: att1 (first), full s-range, normalized f16 -> DH2
__global__ __launch_bounds__(256, 3) void flash_both(
    const half_t* __restrict__ Q2, const half_t* __restrict__ KX,
    const half_t* __restrict__ VXT, const unsigned char* __restrict__ mpk,
    const half_t* __restrict__ QX, const half_t* __restrict__ KY,
    const half_t* __restrict__ VYT,
    float* __restrict__ PO, float* __restrict__ Lp, half_t* __restrict__ DH2)
{
  __shared__ __align__(16) half_t Kb0[8192];
  __shared__ __align__(16) half_t Kb1[8192];
  __shared__ __align__(16) half_t Vb[8192];
  const int bx = blockIdx.x;
  if (bx < 512) {
    const int z  = ((bx & 7) << 1) | ((bx >> 3) & 1);   // z-local per XCD
    const int sh = (bx >> 4) & 1;
    const int q0 = (bx >> 5) * 128;
    flash_body<true, true>(Q2, KX, VXT, mpk,
                           PO + (long)sh * BTC, Lp + (long)sh * ZT, nullptr,
                           Tc, sh * 1024, 1024, z, q0, Kb0, Kb1, Vb);
  } else {
    const int b2 = bx - 512;
    const int z  = ((b2 & 7) << 1) | ((b2 >> 3) & 1);
    const int q0 = (b2 >> 4) * 128;
    flash_body<false, false>(QX, KY, VYT, nullptr,
                             nullptr, nullptr, DH2,
                             Mc, 0, Mc, z, q0, Kb0, Kb1, Vb);
  }
}

// ---------------------- proj GEMM with fused combine
// out[r,c] = sum_k (DH2[r,k] - (O0[r,k]+O1[r,k])/(l0+l1)) * WP[c,k] + bias.
// BK=64 <=> head h = iteration t, so l is one scalar pair per row-chunk.
// K=512 fully unrolled (compile-time buffer indices), A reg-staged with
// counted vmcnt(16), B async gld_lds16.
__global__ __launch_bounds__(256) void gemm_proj(
    const half_t* __restrict__ DH2, const float* __restrict__ PO,
    const float* __restrict__ Lp, const half_t* __restrict__ WP,
    const float* __restrict__ bias, float* __restrict__ out)
{
  constexpr int NIT = 8;   // K = 512, BK = 64
  __shared__ __align__(16) half_t As[2][64 * 64];
  __shared__ __align__(16) half_t Bs[2][64 * 64];
  const int tid = threadIdx.x, lane = tid & 63, wave = tid >> 6;
  const int wm = wave >> 1, wn = wave & 1;
  const int r16 = lane & 15, g = lane >> 4;
  const long m0 = (long)blockIdx.y * 64;
  const long n0 = (long)blockIdx.x * 64;

  half8  a_d2[2][2];
  float4 a_p0[2][2][2], a_p1[2][2][2];
  float  a_l0[2][2], a_l1[2][2];

  auto issueA = [&](int t, int buf) {
#pragma unroll
    for (int i = 0; i < 2; ++i) {
      const int c = tid + i * 256;
      const int row = c >> 3, js = c & 7, jg = js ^ (row & 7);
      const long r = m0 + row;
      const long off = r * Cc + t * 64 + jg * 8;
      a_d2[buf][i]    = *reinterpret_cast<const half8*>(&DH2[off]);
      a_p0[buf][i][0] = *reinterpret_cast<const float4*>(&PO[off]);
      a_p0[buf][i][1] = *reinterpret_cast<const float4*>(&PO[off + 4]);
      a_p1[buf][i][0] = *reinterpret_cast<const float4*>(&PO[BTC + off]);
      a_p1[buf][i][1] = *reinterpret_cast<const float4*>(&PO[BTC + off + 4]);
      const long zt = ((r >> 11) * 8 + t) * (long)Tc + (r & (Tc - 1));
      a_l0[buf][i] = Lp[zt];
      a_l1[buf][i] = Lp[ZT + zt];
    }
  };
  auto issueB = [&](int t, int buf) {
#pragma unroll
    for (int i = 0; i < 2; ++i) {
      const int c = tid + i * 256;
      const int row = c >> 3, js = c & 7, jg = js ^ (row & 7);
      gld_lds16(WP + (n0 + row) * Cc + t * 64 + jg * 8, &Bs[buf][c * 8]);
    }
  };

  floatx4 acc[2][2];
#pragma unroll
  for (int mi = 0; mi < 2; ++mi)
#pragma unroll
    for (int ni = 0; ni < 2; ++ni) acc[mi][ni] = floatx4{0.f, 0.f, 0.f, 0.f};

  const int rA = wm * 32 + r16, rB = wn * 32 + r16;

  issueA(0, 0); issueB(0, 0);
  asm volatile("" ::: "memory");

#pragma unroll
  for (int t = 0; t < NIT; ++t) {
    const bool hn = (t + 1 < NIT);
    if (hn) { issueA(t + 1, (t + 1) & 1); issueB(t + 1, (t + 1) & 1); }
    asm volatile("" ::: "memory");
    if (hn) asm volatile("s_waitcnt vmcnt(16)" ::: "memory");  // stage t done
    else    asm volatile("s_waitcnt vmcnt(0)" ::: "memory");
    // diff + pack + ds_write As[t&1]
#pragma unroll
    for (int i = 0; i < 2; ++i) {
      const int c = tid + i * 256;
      const float inv = 1.f / (a_l0[t & 1][i] + a_l1[t & 1][i]);
      const float4 p00 = a_p0[t & 1][i][0], p01 = a_p0[t & 1][i][1];
      const float4 p10 = a_p1[t & 1][i][0], p11 = a_p1[t & 1][i][1];
      const half8 d2 = a_d2[t & 1][i];
      int w0 = pkrtz((float)d2[0] - (p00.x + p10.x) * inv,
                     (float)d2[1] - (p00.y + p10.y) * inv);
      int w1 = pkrtz((float)d2[2] - (p00.z + p10.z) * inv,
                     (float)d2[3] - (p00.w + p10.w) * inv);
      int w2 = pkrtz((float)d2[4] - (p01.x + p11.x) * inv,
                     (float)d2[5] - (p01.y + p11.y) * inv);
      int w3 = pkrtz((float)d2[6] - (p01.z + p11.z) * inv,
                     (float)d2[7] - (p01.w + p11.w) * inv);
      int4v wv; wv[0] = w0; wv[1] = w1; wv[2] = w2; wv[3] = w3;
      *reinterpret_cast<int4v*>(&As[t & 1][c * 8]) = wv;
    }
    asm volatile("s_waitcnt lgkmcnt(0)" ::: "memory");
    __builtin_amdgcn_s_barrier();
    asm volatile("" ::: "memory");

    half8 aF[2][2], bF[2][2];
#pragma unroll
    for (int mi = 0; mi < 2; ++mi)
#pragma unroll
      for (int k2 = 0; k2 < 2; ++k2)
        aF[mi][k2] = *reinterpret_cast<const half8*>(
            &As[t & 1][(rA + mi * 16) * 64 + ((k2 * 4 + g) ^ (r16 & 7)) * 8]);
#pragma unroll
    for (int ni = 0; ni < 2; ++ni)
#pragma unroll
      for (int k2 = 0; k2 < 2; ++k2)
        bF[ni][k2] = *reinterpret_cast<const half8*>(
            &Bs[t & 1][(rB + ni * 16) * 64 + ((k2 * 4 + g) ^ (r16 & 7)) * 8]);
    __builtin_amdgcn_s_setprio(1);
#pragma unroll
    for (int k2 = 0; k2 < 2; ++k2)
#pragma unroll
      for (int mi = 0; mi < 2; ++mi)
#pragma unroll
        for (int ni = 0; ni < 2; ++ni)
          acc[mi][ni] = __builtin_amdgcn_mfma_f32_16x16x32_f16(
              aF[mi][k2], bF[ni][k2], acc[mi][ni], 0, 0, 0);
    __builtin_amdgcn_s_setprio(0);
    asm volatile("s_waitcnt lgkmcnt(0)" ::: "memory");
    __builtin_amdgcn_s_barrier();
    asm volatile("" ::: "memory");
  }

#pragma unroll
  for (int mi = 0; mi < 2; ++mi)
#pragma unroll
    for (int ni = 0; ni < 2; ++ni)
#pragma unroll
      for (int reg = 0; reg < 4; ++reg) {
        const long r = m0 + wm * 32 + mi * 16 + g * 4 + reg;
        const int  c = (int)n0 + wn * 32 + ni * 16 + r16;
        out[r * Cc + c] = acc[mi][ni][reg] + bias[c];
      }
}

// ----------------------------------------------- prep: converts + mask pack
__device__ __forceinline__ void cvt4(const float* in, half_t* out, long i) {
  const float4 f = reinterpret_cast<const float4*>(in)[i];
  half4v h; h[0] = (half_t)f.x; h[1] = (half_t)f.y; h[2] = (half_t)f.z; h[3] = (half_t)f.w;
  reinterpret_cast<half4v*>(out)[i] = h;
}

__global__ __launch_bounds__(256) void prep(
    const float* __restrict__ x, const float* __restrict__ y,
    const float* __restrict__ qw, const float* __restrict__ pw,
    const int* __restrict__ mask,
    half_t* __restrict__ XH, half_t* __restrict__ YH,
    half_t* __restrict__ WQ, half_t* __restrict__ WP,
    unsigned char* __restrict__ mpk)
{
  const long i = (long)blockIdx.x * 256 + threadIdx.x;
  constexpr long n0 = 524288;            // x/4
  constexpr long n1 = n0 + 262144;       // y/4
  constexpr long n2 = n1 + 196608;       // qkv_w/4
  constexpr long n3 = n2 + 65536;        // proj_w/4
  if (i < n0) cvt4(x, XH, i);
  else if (i < n1) cvt4(y, YH, i - n0);
  else if (i < n2) cvt4(qw, WQ, i - n1);
  else if (i < n3) cvt4(pw, WP, i - n2);
  else {
    const long idx = i - n3;             // [0, Tc*256)
    const int t = (int)(idx >> 8), tile = (int)((idx >> 4) & 15), r16 = (int)(idx & 15);
    const int* row = mask + (long)t * Tc + tile * 128 + r16;
    unsigned int bbits = 0;
#pragma unroll
    for (int ni = 0; ni < 8; ++ni)
      bbits |= (row[ni * 16] != 0 ? 1u : 0u) << ni;
    mpk[idx] = (unsigned char)bbits;
  }
}

// ------------------------------------------------------------- workspace map
constexpr size_t OFF_XH   = 0;                                   // [B*T,C] f16 (YH must follow!)
constexpr size_t OFF_YH   = OFF_XH   + (size_t)Bc*Tc*Cc*2;       // contiguous rows after XH
constexpr size_t OFF_WQ   = OFF_YH   + (size_t)Bc*Mc*Cc*2;
constexpr size_t OFF_WP   = OFF_WQ   + (size_t)3*Cc*Cc*2;
constexpr size_t OFF_QX   = OFF_WP   + (size_t)Cc*Cc*2;          // [z,T,D] *0.125*log2e
constexpr size_t OFF_KX   = OFF_QX   + (size_t)Bc*Hc*Tc*Dc*2;    // [z,T,D]
constexpr size_t OFF_VXT  = OFF_KX   + (size_t)Bc*Hc*Tc*Dc*2;    // [z,D,T]
constexpr size_t OFF_QYT  = OFF_VXT  + (size_t)Bc*Hc*Tc*Dc*2;    // [z,D,M] *0.125
constexpr size_t OFF_KY   = OFF_QYT  + (size_t)Bc*Hc*Mc*Dc*2;    // [z,M,D]
constexpr size_t OFF_KYT  = OFF_KY   + (size_t)Bc*Hc*Mc*Dc*2;    // [z,D,M]
constexpr size_t OFF_VYT  = OFF_KYT  + (size_t)Bc*Hc*Mc*Dc*2;    // [z,D,M]
constexpr size_t OFF_Q2   = OFF_VYT  + (size_t)Bc*Hc*Mc*Dc*2;    // [z,T,D]
constexpr size_t OFF_DH2  = OFF_Q2   + (size_t)Bc*Hc*Tc*Dc*2;    // [B,T,C] cval_x2y f16
constexpr size_t OFF_MPK  = OFF_DH2  + (size_t)Bc*Tc*Cc*2;       // [T,16,16] u8
constexpr size_t OFF_PO   = OFF_MPK  + (size_t)Tc*256;           // [2][B,T,C] f32 unnormalized
constexpr size_t OFF_L    = OFF_PO   + (size_t)2*BTC*4;          // [2][ZT] f32 row sums
// total ~55 MB

extern "C" void kernel_launch(void* const* d_in, const int* in_sizes, int n_in,
                              void* d_out, int out_size, void* d_ws, size_t ws_size,
                              hipStream_t stream) {
  const float* x      = (const float*)d_in[0];
  const float* y      = (const float*)d_in[1];
  const int*   mask   = (const int*)  d_in[2];
  const float* qkv_b  = (const float*)d_in[4];
  const float* proj_b = (const float*)d_in[6];
  float* out = (float*)d_out;
  char* ws = (char*)d_ws;

  half_t* XH   = (half_t*)(ws + OFF_XH);
  half_t* YH   = (half_t*)(ws + OFF_YH);
  half_t* WQ   = (half_t*)(ws + OFF_WQ);
  half_t* WP   = (half_t*)(ws + OFF_WP);
  half_t* QX   = (half_t*)(ws + OFF_QX);
  half_t* KX   = (half_t*)(ws + OFF_KX);
  half_t* VXT  = (half_t*)(ws + OFF_VXT);
  half_t* QYT  = (half_t*)(ws + OFF_QYT);
  half_t* KY   = (half_t*)(ws + OFF_KY);
  half_t* KYT  = (half_t*)(ws + OFF_KYT);
  half_t* VYT  = (half_t*)(ws + OFF_VYT);
  half_t* Q2   = (half_t*)(ws + OFF_Q2);
  half_t* DH2  = (half_t*)(ws + OFF_DH2);
  unsigned char* MPK = (unsigned char*)(ws + OFF_MPK);
  float*  PO   = (float*) (ws + OFF_PO);
  float*  Lp   = (float*) (ws + OFF_L);

  // converts + mask packing (one launch)
  prep<<<6144, 256, 0, stream>>>(x, y, (const float*)d_in[3], (const float*)d_in[5],
                                 mask, XH, YH, WQ, WP, MPK);

  // fused qkv projection for x and y (XH||YH contiguous: 6144 rows)
  {
    EpiParams ep{};
    ep.h0 = QX; ep.h1 = KX; ep.h2 = VXT; ep.h3 = QYT;
    ep.h4 = KY; ep.h5 = KYT; ep.h6 = VYT; ep.bias = qkv_b;
    gemm_nt<128,64,2,2,EPI_QKV_XY><<<dim3(24, 48, 1), 256, 0, stream>>>(
        XH, WQ, Cc, Cc, Cc, 0, 0, ep);
  }

  // fused WT+Q2: 16 t-chunks x 16 z = 256 blocks
  wtq2<<<dim3(16, 16), 256, 0, stream>>>(QYT, KYT, QX, Q2);

  // balanced flash: 512 att0-half blocks + 256 att1 blocks = 768 (3/CU)
  flash_both<<<dim3(768), 256, 0, stream>>>(
      Q2, KX, VXT, MPK, QX, KY, VYT, PO, Lp, DH2);

  // out = (DH2 - (O0+O1)/(l0+l1)) @ proj_w^T + proj_b  (combine fused)
  gemm_proj<<<dim3(8, 64), 256, 0, stream>>>(DH2, PO, Lp, WP, proj_b, out);
}

// Round 6
// 179.199 us; speedup vs baseline: 1.0845x; 1.0845x over previous
//
#include <hip/hip_runtime.h>

// CrossAttentionPro on MI355X — Round 18:
//  Revert to the R15 flash schedule (measured best 42.7us): 48 KB LDS
//  (K dbuf + V single, 3 blk/CU), 768 blocks x 8 tiles, 3 barriers/tile
//  with V(t+1) prefetched at END of tile t (full-tile latency hiding —
//  R17 lesson: staging V at tile top exposes its latency on every tile).
//  Separate combine_k + f16-A proj GEMM (R17 lesson: fusing combine into
//  proj re-reads 2x16MB f32 A-panels 8x = +100MB HBM).
//  NEW: QK->softmax software pipelining — mask+exp2+sum for ni-1 issued
//  between ni's MFMAs (intra-wave matrix/VALU overlap; previously the
//  asm "memory" fence after the K-prefetch split them into separate
//  scheduling regions). lsum shuffles deferred to epilogue; L as float.
//  Kept: swapped-operand S^T=mfma(K,Q), no-max exp2 softmax (log2-domain),
//  pkrtz+permlane P-frag butterfly, BK=64 dbuf counted-vmcnt GEMMs, fused
//  qkv epilogue, wtq2 fusion, bit-packed mask, XCD z-locality, s_setprio.

typedef _Float16 half_t;
typedef _Float16 half8 __attribute__((ext_vector_type(8)));
typedef _Float16 half4v __attribute__((ext_vector_type(4)));
typedef float floatx4 __attribute__((ext_vector_type(4)));
typedef int int4v __attribute__((ext_vector_type(4)));

constexpr int Bc = 2, Tc = 2048, Mc = 1024, Cc = 512, Hc = 8, Dc = 64;
constexpr long BTC = (long)Bc * Tc * Cc;
constexpr long ZT  = (long)Bc * Hc * Tc;
constexpr float S1 = 0.18033688f;                 // 0.125 * log2(e)

enum { EPI_F16STORE = 0, EPI_QKV_XY = 1, EPI_PROJ = 2 };

struct EpiParams {
  half_t* h0;        // QXs  / f16 dest
  half_t* h1;        // KX
  half_t* h2;        // VXT
  half_t* h3;        // QYT
  half_t* h4;        // KY
  half_t* h5;        // KYT
  half_t* h6;        // VYT
  float* f0;
  const float* bias;
  float scale;
  int ldc;
  long bstride;
};

// async global->LDS, 16B per lane; dst must be wave-uniform base + lane*16.
__device__ __forceinline__ void gld_lds16(const half_t* g, half_t* l) {
  __builtin_amdgcn_global_load_lds(
      (const __attribute__((address_space(1))) void*)g,
      (__attribute__((address_space(3))) void*)l, 16, 0, 0);
}

// pack 2 f32 -> 2 f16 (RTZ) as one u32
__device__ __forceinline__ int pkrtz(float a, float b) {
  return __builtin_bit_cast(int, __builtin_amdgcn_cvt_pkrtz(a, b));
}
// v_permlane16_swap: a.row1<->b.row0, a.row3<->b.row2 (rows = 16-lane groups)
__device__ __forceinline__ void pl16(int& a, int& b) {
  asm volatile("v_permlane16_swap_b32 %0, %1" : "+v"(a), "+v"(b));
}
// v_permlane32_swap: a.rows{2,3} <-> b.rows{0,1}
__device__ __forceinline__ void pl32(int& a, int& b) {
  asm volatile("v_permlane32_swap_b32 %0, %1" : "+v"(a), "+v"(b));
}

// ---------------------------------------------------------------- GEMM (NT)
// C[r,c] = sum_k A[r,k]*Bt[c,k]. BK=64 double-buffered async staging with
// counted vmcnt, swizzled chunks (conflict-free ds_read_b128).
template <int BM, int BN, int WMG, int WNG, int EPI>
__global__ __launch_bounds__(256) void gemm_nt(
    const half_t* __restrict__ A, const half_t* __restrict__ Bt,
    int K, int lda, int ldb, long bsA, long bsB, EpiParams ep)
{
  constexpr int BK = 64;
  constexpr int WTM = BM / WMG, WTN = BN / WNG;
  constexpr int MI = WTM / 16, NI = WTN / 16;
  constexpr int AIT = BM * BK / 8 / 256;
  constexpr int BIT = BN * BK / 8 / 256;
  constexpr int NLD = AIT + BIT;
  __shared__ __align__(16) half_t As[2][BM * BK];
  __shared__ __align__(16) half_t Bs[2][BN * BK];

  const int tid = threadIdx.x;
  const int lane = tid & 63;
  const int wave = tid >> 6;
  const int wm = wave / WNG, wn = wave % WNG;
  const int r16 = lane & 15, g = lane >> 4;
  const int z = blockIdx.z;
  const long m0 = (long)blockIdx.y * BM;
  const long n0 = (long)blockIdx.x * BN;
  const half_t* Abase = A + (long)z * bsA + m0 * (long)lda;
  const half_t* Bbase = Bt + (long)z * bsB + n0 * (long)ldb;

  const int rA = wm * WTM + r16;
  const int rB = wn * WTN + r16;

  floatx4 acc[MI][NI];
#pragma unroll
  for (int mi = 0; mi < MI; ++mi)
#pragma unroll
    for (int ni = 0; ni < NI; ++ni)
      acc[mi][ni] = floatx4{0.f, 0.f, 0.f, 0.f};

  auto stage = [&](int kt, int buf) {
#pragma unroll
    for (int i = 0; i < AIT; ++i) {
      const int c = tid + i * 256;
      const int row = c >> 3, js = c & 7;
      const int jg = js ^ (row & 7);
      gld_lds16(Abase + (long)row * lda + kt + jg * 8, &As[buf][c * 8]);
    }
#pragma unroll
    for (int i = 0; i < BIT; ++i) {
      const int c = tid + i * 256;
      const int row = c >> 3, js = c & 7;
      const int jg = js ^ (row & 7);
      gld_lds16(Bbase + (long)row * ldb + kt + jg * 8, &Bs[buf][c * 8]);
    }
  };

  const int NIT = K / BK;
  stage(0, 0);
  asm volatile("" ::: "memory");

  for (int it = 0; it < NIT; ++it) {
    const bool hn = (it + 1 < NIT);
    if (hn) stage((it + 1) * BK, (it + 1) & 1);
    asm volatile("" ::: "memory");
    if (hn) {
      if constexpr (NLD == 6) asm volatile("s_waitcnt vmcnt(6)" ::: "memory");
      else if constexpr (NLD == 4) asm volatile("s_waitcnt vmcnt(4)" ::: "memory");
      else if constexpr (NLD == 8) asm volatile("s_waitcnt vmcnt(8)" ::: "memory");
      else asm volatile("s_waitcnt vmcnt(0)" ::: "memory");
    } else {
      asm volatile("s_waitcnt vmcnt(0)" ::: "memory");
    }
    __builtin_amdgcn_s_barrier();
    asm volatile("" ::: "memory");

    const half_t* Ab = As[it & 1];
    const half_t* Bb = Bs[it & 1];
    half8 aF[MI][2], bF[NI][2];
#pragma unroll
    for (int mi = 0; mi < MI; ++mi)
#pragma unroll
      for (int k2 = 0; k2 < 2; ++k2)
        aF[mi][k2] = *reinterpret_cast<const half8*>(
            &Ab[(rA + mi * 16) * BK + ((k2 * 4 + g) ^ (r16 & 7)) * 8]);
#pragma unroll
    for (int ni = 0; ni < NI; ++ni)
#pragma unroll
      for (int k2 = 0; k2 < 2; ++k2)
        bF[ni][k2] = *reinterpret_cast<const half8*>(
            &Bb[(rB + ni * 16) * BK + ((k2 * 4 + g) ^ (r16 & 7)) * 8]);
    __builtin_amdgcn_s_setprio(1);
#pragma unroll
    for (int k2 = 0; k2 < 2; ++k2)
#pragma unroll
      for (int mi = 0; mi < MI; ++mi)
#pragma unroll
        for (int ni = 0; ni < NI; ++ni)
          acc[mi][ni] = __builtin_amdgcn_mfma_f32_16x16x32_f16(
              aF[mi][k2], bF[ni][k2], acc[mi][ni], 0, 0, 0);
    __builtin_amdgcn_s_setprio(0);
    asm volatile("s_waitcnt lgkmcnt(0)" ::: "memory");
    __builtin_amdgcn_s_barrier();
    asm volatile("" ::: "memory");
  }

  // epilogue: C/D layout col=lane&15, row=(lane>>4)*4+reg  [m89-verified]
#pragma unroll
  for (int mi = 0; mi < MI; ++mi) {
#pragma unroll
    for (int ni = 0; ni < NI; ++ni) {
#pragma unroll
      for (int reg = 0; reg < 4; ++reg) {
        const int r = (int)m0 + wm * WTM + mi * 16 + g * 4 + reg;
        const int c = (int)n0 + wn * WTN + ni * 16 + r16;
        const float v = acc[mi][ni][reg];
        if constexpr (EPI == EPI_F16STORE) {
          ep.h0[(long)z * ep.bstride + (long)r * ep.ldc + c] = (half_t)(v * ep.scale);
        } else if constexpr (EPI == EPI_QKV_XY) {
          const float val = v + ep.bias[c];
          const int which = c >> 9;     // 0=q 1=k 2=v
          const int cc2 = c & 511;
          const int h = cc2 >> 6, d = cc2 & 63;
          if (r < Bc * Tc) {            // x rows
            const int b = r >> 11, t = r & (Tc - 1);
            const long bh = (long)(b * Hc + h);
            if (which == 0)      ep.h0[(bh * Tc + t) * Dc + d] = (half_t)(val * S1);  // QXs (log2e folded)
            else if (which == 1) ep.h1[(bh * Tc + t) * Dc + d] = (half_t)val;         // KX
            else                 ep.h2[(bh * Dc + d) * Tc + t] = (half_t)val;         // VXT
          } else {                      // y rows
            const int r2 = r - Bc * Tc;
            const int b = r2 >> 10, t = r2 & (Mc - 1);
            const long bh = (long)(b * Hc + h);
            if (which == 0)      ep.h3[(bh * Dc + d) * Mc + t] = (half_t)(val * 0.125f); // QYTs
            else if (which == 1) { ep.h4[(bh * Mc + t) * Dc + d] = (half_t)val;          // KY
                                   ep.h5[(bh * Dc + d) * Mc + t] = (half_t)val; }        // KYT
            else                 ep.h6[(bh * Dc + d) * Mc + t] = (half_t)val;            // VYT
          }
        } else {  // EPI_PROJ
          ep.f0[(long)r * Cc + c] = v + ep.bias[c];
        }
      }
    }
  }
}

// --------------------------------------------- fused WT+Q2 kernel
// grid (16 t-chunks, 16 z). Phase 1: WT[64][64] = 0.125 * QYTs[z] KYT[z]^T
// (K=1024, pipelined dbuf) -> LDS in phase-2 fragment layout. Phase 2:
// Q2[z, t0..t0+127, :] = QXs * WT^T (K=64, single tile, A staged async).
__global__ __launch_bounds__(256) void wtq2(
    const half_t* __restrict__ QYT, const half_t* __restrict__ KYT,
    const half_t* __restrict__ QX, half_t* __restrict__ Q2)
{
  __shared__ __align__(16) half_t As[2][4096];
  __shared__ __align__(16) half_t Bs[2][4096];
  __shared__ __align__(16) half_t WTs[4096];
  const int tid = threadIdx.x, lane = tid & 63, wave = tid >> 6;
  const int wm = wave >> 1, wn = wave & 1;
  const int r16 = lane & 15, g = lane >> 4;
  const int z = blockIdx.y;
  const int t0 = blockIdx.x * 128;
  const half_t* Aq = QYT + (long)z * Dc * Mc;
  const half_t* Bk = KYT + (long)z * Dc * Mc;

  auto stage1 = [&](int kt, int buf) {
#pragma unroll
    for (int i = 0; i < 2; ++i) {
      const int c = tid + i * 256;
      const int row = c >> 3, js = c & 7, jg = js ^ (row & 7);
      gld_lds16(Aq + (long)row * Mc + kt + jg * 8, &As[buf][c * 8]);
    }
#pragma unroll
    for (int i = 0; i < 2; ++i) {
      const int c = tid + i * 256;
      const int row = c >> 3, js = c & 7, jg = js ^ (row & 7);
      gld_lds16(Bk + (long)row * Mc + kt + jg * 8, &Bs[buf][c * 8]);
    }
  };

  floatx4 acc[2][2];
#pragma unroll
  for (int mi = 0; mi < 2; ++mi)
#pragma unroll
    for (int ni = 0; ni < 2; ++ni) acc[mi][ni] = floatx4{0.f, 0.f, 0.f, 0.f};

  const int rA = wm * 32 + r16, rB = wn * 32 + r16;
  stage1(0, 0);
  asm volatile("" ::: "memory");
  for (int it = 0; it < 16; ++it) {
    const bool hn = (it < 15);
    if (hn) stage1((it + 1) * 64, (it + 1) & 1);
    asm volatile("" ::: "memory");
    if (hn) asm volatile("s_waitcnt vmcnt(4)" ::: "memory");
    else    asm volatile("s_waitcnt vmcnt(0)" ::: "memory");
    __builtin_amdgcn_s_barrier();
    asm volatile("" ::: "memory");
    const half_t* Ab = As[it & 1];
    const half_t* Bb = Bs[it & 1];
    half8 aF[2][2], bF[2][2];
#pragma unroll
    for (int mi = 0; mi < 2; ++mi)
#pragma unroll
      for (int k2 = 0; k2 < 2; ++k2)
        aF[mi][k2] = *reinterpret_cast<const half8*>(
            &Ab[(rA + mi * 16) * 64 + ((k2 * 4 + g) ^ (r16 & 7)) * 8]);
#pragma unroll
    for (int ni = 0; ni < 2; ++ni)
#pragma unroll
      for (int k2 = 0; k2 < 2; ++k2)
        bF[ni][k2] = *reinterpret_cast<const half8*>(
            &Bb[(rB + ni * 16) * 64 + ((k2 * 4 + g) ^ (r16 & 7)) * 8]);
    __builtin_amdgcn_s_setprio(1);
#pragma unroll
    for (int k2 = 0; k2 < 2; ++k2)
#pragma unroll
      for (int mi = 0; mi < 2; ++mi)
#pragma unroll
        for (int ni = 0; ni < 2; ++ni)
          acc[mi][ni] = __builtin_amdgcn_mfma_f32_16x16x32_f16(
              aF[mi][k2], bF[ni][k2], acc[mi][ni], 0, 0, 0);
    __builtin_amdgcn_s_setprio(0);
    asm volatile("s_waitcnt lgkmcnt(0)" ::: "memory");
    __builtin_amdgcn_s_barrier();
    asm volatile("" ::: "memory");
  }

  // phase-2 A stage (As fully free after final barrier): QX rows t0..t0+127
  half_t* P2 = &As[0][0];
#pragma unroll
  for (int i = 0; i < 4; ++i) {
    const int c = tid + i * 256;
    const int row = c >> 3, js = c & 7, jg = js ^ (row & 7);
    gld_lds16(QX + ((long)z * Tc + t0 + row) * 64 + jg * 8, P2 + c * 8);
  }
  // WT -> LDS f16 in phase-2 fragment layout (chunk swizzle js^(row&7))
#pragma unroll
  for (int mi = 0; mi < 2; ++mi)
#pragma unroll
    for (int ni = 0; ni < 2; ++ni)
#pragma unroll
      for (int reg = 0; reg < 4; ++reg) {
        const int r = wm * 32 + mi * 16 + g * 4 + reg;   // d2
        const int c = wn * 32 + ni * 16 + r16;           // d1
        WTs[r * 64 + (((c >> 3) ^ (r & 7)) << 3) + (c & 7)] =
            (half_t)(acc[mi][ni][reg] * 0.125f);
      }
  __syncthreads();   // drains vmcnt (QX stage) + lgkm (WTs writes)

  // phase 2: per wave 32 t-rows, full 64 d2 cols, K=64
  floatx4 a2[2][4];
#pragma unroll
  for (int mi = 0; mi < 2; ++mi)
#pragma unroll
    for (int ni = 0; ni < 4; ++ni) a2[mi][ni] = floatx4{0.f, 0.f, 0.f, 0.f};
  const int rA2 = wave * 32 + r16;
  half8 aF2[2][2], bF2[4][2];
#pragma unroll
  for (int mi = 0; mi < 2; ++mi)
#pragma unroll
    for (int k2 = 0; k2 < 2; ++k2)
      aF2[mi][k2] = *reinterpret_cast<const half8*>(
          &P2[(rA2 + mi * 16) * 64 + ((k2 * 4 + g) ^ (r16 & 7)) * 8]);
#pragma unroll
  for (int ni = 0; ni < 4; ++ni)
#pragma unroll
    for (int k2 = 0; k2 < 2; ++k2)
      bF2[ni][k2] = *reinterpret_cast<const half8*>(
          &WTs[(ni * 16 + r16) * 64 + ((k2 * 4 + g) ^ (r16 & 7)) * 8]);
#pragma unroll
  for (int k2 = 0; k2 < 2; ++k2)
#pragma unroll
    for (int mi = 0; mi < 2; ++mi)
#pragma unroll
      for (int ni = 0; ni < 4; ++ni)
        a2[mi][ni] = __builtin_amdgcn_mfma_f32_16x16x32_f16(
            aF2[mi][k2], bF2[ni][k2], a2[mi][ni], 0, 0, 0);
#pragma unroll
  for (int mi = 0; mi < 2; ++mi)
#pragma unroll
    for (int ni = 0; ni < 4; ++ni)
#pragma unroll
      for (int reg = 0; reg < 4; ++reg) {
        const int t = t0 + wave * 32 + mi * 16 + g * 4 + reg;
        const int c = ni * 16 + r16;
        Q2[((long)z * Tc + t) * 64 + c] = (half_t)a2[mi][ni][reg];
      }
}

// ------------------------------------------------------------ flash staging
__device__ __forceinline__ void stageK128(const half_t* Kz, int s0, half_t* dst, int tid) {
#pragma unroll
  for (int i = 0; i < 4; ++i) {
    const int c = tid + i * 256;
    const int row = c >> 3, js = c & 7;
    const int jg = js ^ (row & 7);
    gld_lds16(Kz + (long)(s0 + row) * 64 + jg * 8, dst + c * 8);
  }
}
__device__ __forceinline__ void stageV128(const half_t* Vz, int s0, int Slen, half_t* dst, int tid) {
#pragma unroll
  for (int i = 0; i < 4; ++i) {
    const int c = tid + i * 256;
    const int row = c >> 4, js = c & 15;
    const int jg = js ^ (row & 15);
    gld_lds16(Vz + (long)row * Slen + s0 + jg * 8, dst + c * 8);
  }
}

// --------------------------------------------------------- flash body (MI=2)
// 128 q-rows/block, 8 s-tiles of 128 over [sbeg, sbeg+scount). Scores in
// log2 domain (log2e folded into Q), no-max softmax. R15 schedule:
//  vmcnt(4)+barrier [K(t) ready, V(t) flying] ; QK with per-ni interleaved
//  softmax (pipelined by 1 ni: matrix pipe ni overlaps VALU ni-1) ; issue
//  K(t+1) ; tail softmax ; vmcnt(4)+barrier [V(t) ready] ; PV ; barrier ;
//  issue V(t+1) [hidden under next tile's QK+softmax].
// PARTIAL: unnormalized O f32 -> PO + row-sum -> Lp. else normalized f16.
template <bool MASKED, bool PARTIAL>
__device__ __forceinline__ void flash_body(
    const half_t* __restrict__ Qp, const half_t* __restrict__ Kp,
    const half_t* __restrict__ Vp, const unsigned char* __restrict__ mpk,
    float* __restrict__ PO, float* __restrict__ Lp, half_t* __restrict__ outF,
    int Slen, int sbeg, int scount, int z, int q0,
    half_t* Kb0, half_t* Kb1, half_t* Vb)
{
  const int tid = threadIdx.x, lane = tid & 63, w = tid >> 6;
  const int r16 = lane & 15, g = lane >> 4;
  const int b = z >> 3, h = z & 7;
  const int NT = Slen >> 7;
  const half_t* Qz = Qp + ((long)z * Tc + q0) * 64;
  const half_t* Kz = Kp + (long)z * Slen * 64;
  const half_t* Vz = Vp + (long)z * 64 * Slen;

  // prologue staging: K(0), V(0) (oldest 8 vmem ops, in this order)
  stageK128(Kz, sbeg, Kb0, tid);
  asm volatile("" ::: "memory");
  stageV128(Vz, sbeg, Slen, Vb, tid);
  asm volatile("" ::: "memory");

  half8 aQ[2][2];
#pragma unroll
  for (int mi = 0; mi < 2; ++mi)
#pragma unroll
    for (int k2 = 0; k2 < 2; ++k2)
      aQ[mi][k2] = *reinterpret_cast<const half8*>(
          Qz + (w * 32 + mi * 16 + r16) * 64 + k2 * 32 + g * 8);

  floatx4 oaccT[2][4];
  float lacc[2];
#pragma unroll
  for (int mi = 0; mi < 2; ++mi) {
    lacc[mi] = 0.f;
#pragma unroll
    for (int no = 0; no < 4; ++no) oaccT[mi][no] = floatx4{0.f, 0.f, 0.f, 0.f};
  }

  const int send = sbeg + scount;
  int cur = 0;
  for (int s0 = sbeg; s0 < send; s0 += 128) {
    const bool hn = (s0 + 128 < send);
    // K(t) ready (V(t) may still fly; K is the oldest outstanding group)
    asm volatile("s_waitcnt vmcnt(4)" ::: "memory");
    __builtin_amdgcn_s_barrier();
    asm volatile("" ::: "memory");

    unsigned int mb32[2];
    if constexpr (MASKED) {
      const int tile = s0 >> 7;
#pragma unroll
      for (int mi = 0; mi < 2; ++mi) {
        const int q = q0 + w * 32 + mi * 16 + r16;
        mb32[mi] = *reinterpret_cast<const unsigned int*>(
            mpk + ((long)q * NT + tile) * 16 + 4 * g);
      }
    }

    // S^T = K Q^T with softmax(ni-1) interleaved between ni's MFMAs:
    // matrix pipe (4 MFMAs) overlaps VALU (mask+exp2+sum of previous ni).
    floatx4 sacc[2][8];
#pragma unroll
    for (int mi = 0; mi < 2; ++mi)
#pragma unroll
      for (int ni = 0; ni < 8; ++ni) sacc[mi][ni] = floatx4{0.f, 0.f, 0.f, 0.f};
    const half_t* Kc = cur ? Kb1 : Kb0;

#define SMAX_NI(j)                                                          \
  {                                                                         \
    _Pragma("unroll")                                                       \
    for (int mi = 0; mi < 2; ++mi) {                                        \
      if constexpr (MASKED) {                                               \
        if (mb32[mi] != 0xffffffffu) {                                      \
          _Pragma("unroll")                                                 \
          for (int reg = 0; reg < 4; ++reg)                                 \
            if (!((mb32[mi] >> (reg * 8 + (j))) & 1))                       \
              sacc[mi][j][reg] = -__builtin_inff();                         \
        }                                                                   \
      }                                                                     \
      _Pragma("unroll")                                                     \
      for (int reg = 0; reg < 4; ++reg) {                                   \
        const float e = __builtin_amdgcn_exp2f(sacc[mi][j][reg]);           \
        sacc[mi][j][reg] = e;                                               \
        lacc[mi] += e;                                                      \
      }                                                                     \
    }                                                                       \
  }

    __builtin_amdgcn_s_setprio(1);
#pragma unroll
    for (int ni = 0; ni < 8; ++ni) {
      const int rB = ni * 16 + r16;
      const half8 b0 = *reinterpret_cast<const half8*>(&Kc[rB * 64 + (g ^ (rB & 7)) * 8]);
      const half8 b1 = *reinterpret_cast<const half8*>(&Kc[rB * 64 + ((4 + g) ^ (rB & 7)) * 8]);
#pragma unroll
      for (int mi = 0; mi < 2; ++mi) {
        sacc[mi][ni] = __builtin_amdgcn_mfma_f32_16x16x32_f16(b0, aQ[mi][0], sacc[mi][ni], 0, 0, 0);
        sacc[mi][ni] = __builtin_amdgcn_mfma_f32_16x16x32_f16(b1, aQ[mi][1], sacc[mi][ni], 0, 0, 0);
      }
      if (ni > 0) SMAX_NI(ni - 1);
    }
    __builtin_amdgcn_s_setprio(0);
    // prefetch K(t+1) into the other buffer; lands under tail softmax + PV
    if (hn) stageK128(Kz, s0 + 128, cur ? Kb0 : Kb1, tid);
    asm volatile("" ::: "memory");
    SMAX_NI(7);
#undef SMAX_NI

    // V(t) ready (K(t+1) = newest 4 still in flight when hn)
    if (hn) { asm volatile("s_waitcnt vmcnt(4)" ::: "memory"); }
    else    { asm volatile("s_waitcnt vmcnt(0)" ::: "memory"); }
    __builtin_amdgcn_s_barrier();
    asm volatile("" ::: "memory");

    // O^T += V^T P^T : P-fragment built in-register via pkrtz + permlane
#pragma unroll
    for (int c = 0; c < 4; ++c) {
      half8 bVv[4];
#pragma unroll
      for (int no = 0; no < 4; ++no) {
        const int rV = no * 16 + r16;
        bVv[no] = *reinterpret_cast<const half8*>(
            &Vb[rV * 128 + ((c * 4 + g) ^ (rV & 15)) * 8]);
      }
#pragma unroll
      for (int mi = 0; mi < 2; ++mi) {
        // butterfly P^T frag: target word p_t at lane g <-
        // pk[2c+(g>>1)][p_t&1] of lane 2(g&1)+(p_t>>1)
        int x0 = pkrtz(sacc[mi][2 * c][0],     sacc[mi][2 * c][1]);
        int x1 = pkrtz(sacc[mi][2 * c][2],     sacc[mi][2 * c][3]);
        int x2 = pkrtz(sacc[mi][2 * c + 1][0], sacc[mi][2 * c + 1][1]);
        int x3 = pkrtz(sacc[mi][2 * c + 1][2], sacc[mi][2 * c + 1][3]);
        pl32(x0, x2); pl32(x1, x3);   // resolve g1 <-> ni bit
        pl16(x0, x2); pl16(x1, x3);   // resolve g0 <-> word bit
        int4v wv; wv[0] = x0; wv[1] = x1; wv[2] = x2; wv[3] = x3;
        const half8 aP = __builtin_bit_cast(half8, wv);
        __builtin_amdgcn_s_setprio(1);
#pragma unroll
        for (int no = 0; no < 4; ++no)
          oaccT[mi][no] = __builtin_amdgcn_mfma_f32_16x16x32_f16(bVv[no], aP, oaccT[mi][no], 0, 0, 0);
        __builtin_amdgcn_s_setprio(0);
      }
    }
    __builtin_amdgcn_s_barrier();
    asm volatile("" ::: "memory");
    // prefetch V(t+1); lands under next tile's QK^T + softmax
    if (hn) stageV128(Vz, s0 + 128, Slen, Vb, tid);
    asm volatile("" ::: "memory");
    cur ^= 1;
  }

  // epilogue: cross-lane l reduce (deferred from the loop), then transpose
  // O^T -> O via per-wave 4KB slab in Vb (last iter drained + barriered).
  float ls2[2];
#pragma unroll
  for (int mi = 0; mi < 2; ++mi) {
    float ls = lacc[mi];
    ls += __shfl_xor(ls, 16);
    ls += __shfl_xor(ls, 32);
    ls2[mi] = ls;
  }
  float* slab = reinterpret_cast<float*>(Vb) + w * 1024;
#pragma unroll
  for (int mi = 0; mi < 2; ++mi) {
    const int tq = q0 + w * 32 + mi * 16;
    if constexpr (PARTIAL) {
      if (lane < 16) Lp[(long)z * Tc + tq + r16] = ls2[mi];
    }
    const float sc = PARTIAL ? 1.f : (1.f / ls2[mi]);
#pragma unroll
    for (int no = 0; no < 4; ++no) {
      floatx4 v = oaccT[mi][no];
      if constexpr (!PARTIAL) v *= sc;
      *reinterpret_cast<floatx4*>(&slab[r16 * 64 + no * 16 + (g ^ (r16 & 3)) * 4]) = v;
    }
#pragma unroll
    for (int it = 0; it < 4; ++it) {
      const int q2 = it * 4 + g;
      const int d4 = r16;
      const floatx4 v = *reinterpret_cast<const floatx4*>(
          &slab[q2 * 64 + (d4 >> 2) * 16 + ((d4 & 3) ^ (q2 & 3)) * 4]);
      const long off = ((long)(b * Tc + tq + q2)) * Cc + h * 64 + d4 * 4;
      if constexpr (PARTIAL) {
        *reinterpret_cast<floatx4*>(&PO[off]) = v;
      } else {
        half4v hh; hh[0] = (half_t)v[0]; hh[1] = (half_t)v[1];
        hh[2] = (half_t)v[2]; hh[3] = (half_t)v[3];
        *reinterpret_cast<half4v*>(&outF[off]) = hh;
      }
    }
  }
}

// 768 blocks, each exactly 8 s-tiles (= 3 blocks/CU, one balanced round):
//  bx < 512:  att0 (chained, masked), s-half sh=(bx>>4)&1, unnormalized f32+L
//  bx >= 512: att1 (first), full s-range, normalized f16 -> DH2
__global__ __launch_bounds__(256, 3) void flash_both(
    const half_t* __restrict__ Q2, const half_t* __restrict__ KX,
    const half_t* __restrict__ VXT, const unsigned char* __restrict__ mpk,
    const half_t* __restrict__ QX, const half_t* __restrict__ KY,
    const half_t* __restrict__ VYT,
    float* __restrict__ PO, float* __restrict__ Lp, half_t* __restrict__ DH2)
{
  __shared__ __align__(16) half_t Kb0[8192];
  __shared__ __align__(16) half_t Kb1[8192];
  __shared__ __align__(16) half_t Vb[8192];
  const int bx = blockIdx.x;
  if (bx < 512) {
    const int z  = ((bx & 7) << 1) | ((bx >> 3) & 1);   // z-local per XCD
    const int sh = (bx >> 4) & 1;
    const int q0 = (bx >> 5) * 128;
    flash_body<true, true>(Q2, KX, VXT, mpk,
                           PO + (long)sh * BTC, Lp + (long)sh * ZT, nullptr,
                           Tc, sh * 1024, 1024, z, q0, Kb0, Kb1, Vb);
  } else {
    const int b2 = bx - 512;
    const int z  = ((b2 & 7) << 1) | ((b2 >> 3) & 1);
    const int q0 = (b2 >> 4) * 128;
    flash_body<false, false>(QX, KY, VYT, nullptr,
                             nullptr, nullptr, DH2,
                             Mc, 0, Mc, z, q0, Kb0, Kb1, Vb);
  }
}

// --------------------------- combine att0 s-halves + diff with DH2 -> DH
__global__ __launch_bounds__(256) void combine_k(
    const float* __restrict__ PO, const float* __restrict__ Lp,
    const half_t* __restrict__ DH2, half_t* __restrict__ DH)
{
  const long idx = (long)blockIdx.x * 256 + threadIdx.x;   // over BTC/4
  const long c4 = idx * 4;
  const int c = (int)(c4 & (Cc - 1));
  const long bt = c4 >> 9;
  const int h = c >> 6;
  const int b = (int)(bt >> 11), t = (int)(bt & (Tc - 1));
  const long zt = (long)(b * Hc + h) * Tc + t;
  const float ainv = 1.f / (Lp[zt] + Lp[ZT + zt]);
  const float4* PO4 = reinterpret_cast<const float4*>(PO);
  const float4 oa0 = PO4[idx];
  const float4 oa1 = PO4[BTC / 4 + idx];
  const half4v dv = reinterpret_cast<const half4v*>(DH2)[idx];
  half4v r;
  r[0] = (half_t)((float)dv[0] - (oa0.x + oa1.x) * ainv);
  r[1] = (half_t)((float)dv[1] - (oa0.y + oa1.y) * ainv);
  r[2] = (half_t)((float)dv[2] - (oa0.z + oa1.z) * ainv);
  r[3] = (half_t)((float)dv[3] - (oa0.w + oa1.w) * ainv);
  reinterpret_cast<half4v*>(DH)[idx] = r;
}

// ----------------------------------------------- prep: converts + mask pack
__device__ __forceinline__ void cvt4(const float* in, half_t* out, long i) {
  const float4 f = reinterpret_cast<const float4*>(in)[i];
  half4v h; h[0] = (half_t)f.x; h[1] = (half_t)f.y; h[2] = (half_t)f.z; h[3] = (half_t)f.w;
  reinterpret_cast<half4v*>(out)[i] = h;
}

__global__ __launch_bounds__(256) void prep(
    const float* __restrict__ x, const float* __restrict__ y,
    const float* __restrict__ qw, const float* __restrict__ pw,
    const int* __restrict__ mask,
    half_t* __restrict__ XH, half_t* __restrict__ YH,
    half_t* __restrict__ WQ, half_t* __restrict__ WP,
    unsigned char* __restrict__ mpk)
{
  const long i = (long)blockIdx.x * 256 + threadIdx.x;
  constexpr long n0 = 524288;            // x/4
  constexpr long n1 = n0 + 262144;       // y/4
  constexpr long n2 = n1 + 196608;       // qkv_w/4
  constexpr long n3 = n2 + 65536;        // proj_w/4
  if (i < n0) cvt4(x, XH, i);
  else if (i < n1) cvt4(y, YH, i - n0);
  else if (i < n2) cvt4(qw, WQ, i - n1);
  else if (i < n3) cvt4(pw, WP, i - n2);
  else {
    const long idx = i - n3;             // [0, Tc*256)
    const int t = (int)(idx >> 8), tile = (int)((idx >> 4) & 15), r16 = (int)(idx & 15);
    const int* row = mask + (long)t * Tc + tile * 128 + r16;
    unsigned int bbits = 0;
#pragma unroll
    for (int ni = 0; ni < 8; ++ni)
      bbits |= (row[ni * 16] != 0 ? 1u : 0u) << ni;
    mpk[idx] = (unsigned char)bbits;
  }
}

// ------------------------------------------------------------- workspace map
constexpr size_t OFF_XH   = 0;                                   // [B*T,C] f16 (YH must follow!)
constexpr size_t OFF_YH   = OFF_XH   + (size_t)Bc*Tc*Cc*2;       // contiguous rows after XH
constexpr size_t OFF_WQ   = OFF_YH   + (size_t)Bc*Mc*Cc*2;
constexpr size_t OFF_WP   = OFF_WQ   + (size_t)3*Cc*Cc*2;
constexpr size_t OFF_QX   = OFF_WP   + (size_t)Cc*Cc*2;          // [z,T,D] *0.125*log2e
constexpr size_t OFF_KX   = OFF_QX   + (size_t)Bc*Hc*Tc*Dc*2;    // [z,T,D]
constexpr size_t OFF_VXT  = OFF_KX   + (size_t)Bc*Hc*Tc*Dc*2;    // [z,D,T]
constexpr size_t OFF_QYT  = OFF_VXT  + (size_t)Bc*Hc*Tc*Dc*2;    // [z,D,M] *0.125
constexpr size_t OFF_KY   = OFF_QYT  + (size_t)Bc*Hc*Mc*Dc*2;    // [z,M,D]
constexpr size_t OFF_KYT  = OFF_KY   + (size_t)Bc*Hc*Mc*Dc*2;    // [z,D,M]
constexpr size_t OFF_VYT  = OFF_KYT  + (size_t)Bc*Hc*Mc*Dc*2;    // [z,D,M]
constexpr size_t OFF_Q2   = OFF_VYT  + (size_t)Bc*Hc*Mc*Dc*2;    // [z,T,D]
constexpr size_t OFF_DH   = OFF_Q2   + (size_t)Bc*Hc*Tc*Dc*2;    // [B,T,C] diff f16
constexpr size_t OFF_DH2  = OFF_DH   + (size_t)Bc*Tc*Cc*2;       // [B,T,C] cval_x2y f16
constexpr size_t OFF_MPK  = OFF_DH2  + (size_t)Bc*Tc*Cc*2;       // [T,16,16] u8
constexpr size_t OFF_PO   = OFF_MPK  + (size_t)Tc*256;           // [2][B,T,C] f32 unnormalized
constexpr size_t OFF_L    = OFF_PO   + (size_t)2*BTC*4;          // [2][ZT] f32 row sums
// total ~55 MB

extern "C" void kernel_launch(void* const* d_in, const int* in_sizes, int n_in,
                              void* d_out, int out_size, void* d_ws, size_t ws_size,
                              hipStream_t stream) {
  const float* x      = (const float*)d_in[0];
  const float* y      = (const float*)d_in[1];
  const int*   mask   = (const int*)  d_in[2];
  const float* qkv_b  = (const float*)d_in[4];
  const float* proj_b = (const float*)d_in[6];
  float* out = (float*)d_out;
  char* ws = (char*)d_ws;

  half_t* XH   = (half_t*)(ws + OFF_XH);
  half_t* YH   = (half_t*)(ws + OFF_YH);
  half_t* WQ   = (half_t*)(ws + OFF_WQ);
  half_t* WP   = (half_t*)(ws + OFF_WP);
  half_t* QX   = (half_t*)(ws + OFF_QX);
  half_t* KX   = (half_t*)(ws + OFF_KX);
  half_t* VXT  = (half_t*)(ws + OFF_VXT);
  half_t* QYT  = (half_t*)(ws + OFF_QYT);
  half_t* KY   = (half_t*)(ws + OFF_KY);
  half_t* KYT  = (half_t*)(ws + OFF_KYT);
  half_t* VYT  = (half_t*)(ws + OFF_VYT);
  half_t* Q2   = (half_t*)(ws + OFF_Q2);
  half_t* DH   = (half_t*)(ws + OFF_DH);
  half_t* DH2  = (half_t*)(ws + OFF_DH2);
  unsigned char* MPK = (unsigned char*)(ws + OFF_MPK);
  float*  PO   = (float*) (ws + OFF_PO);
  float*  Lp   = (float*) (ws + OFF_L);

  // converts + mask packing (one launch)
  prep<<<6144, 256, 0, stream>>>(x, y, (const float*)d_in[3], (const float*)d_in[5],
                                 mask, XH, YH, WQ, WP, MPK);

  // fused qkv projection for x and y (XH||YH contiguous: 6144 rows)
  {
    EpiParams ep{};
    ep.h0 = QX; ep.h1 = KX; ep.h2 = VXT; ep.h3 = QYT;
    ep.h4 = KY; ep.h5 = KYT; ep.h6 = VYT; ep.bias = qkv_b;
    gemm_nt<128,64,2,2,EPI_QKV_XY><<<dim3(24, 48, 1), 256, 0, stream>>>(
        XH, WQ, Cc, Cc, Cc, 0, 0, ep);
  }

  // fused WT+Q2: 16 t-chunks x 16 z = 256 blocks
  wtq2<<<dim3(16, 16), 256, 0, stream>>>(QYT, KYT, QX, Q2);

  // balanced flash: 512 att0-half blocks + 256 att1 blocks = 768 (3/CU)
  flash_both<<<dim3(768), 256, 0, stream>>>(
      Q2, KX, VXT, MPK, QX, KY, VYT, PO, Lp, DH2);

  // combine att0 halves + diff with DH2 -> DH
  combine_k<<<(int)(BTC/4/256), 256, 0, stream>>>(PO, Lp, DH2, DH);

  // out = DH @ proj_w^T + proj_b
  {
    EpiParams ep{}; ep.f0 = out; ep.bias = proj_b;
    gemm_nt<64,64,2,2,EPI_PROJ><<<dim3(8, 64, 1), 256, 0, stream>>>(
        DH, WP, Cc, Cc, Cc, 0, 0, ep);
  }
}

// Round 7
// 178.741 us; speedup vs baseline: 1.0873x; 1.0026x over previous
//
#include <hip/hip_runtime.h>

// CrossAttentionPro on MI355X — Round 19:
//  R15 flash schedule (measured best): 48 KB LDS (K dbuf + V single, 3
//  blk/CU), 768 blocks x 8 tiles, 3 barriers/tile, V(t+1) prefetched at
//  END of tile t, SEPARATED softmax phase (R18 lesson: interleaving VALU
//  into the MFMA cluster regressed ~4us).
//  NEW: ones-MFMA row-sum — lacc4[mi] = mfma(vones, aP, lacc4[mi]) in the
//  PV loop. A=ones => D[row,q] = sum_k P^T[k,q] = l_q at every lane
//  (col=lane&15): replaces 64 VALU adds/tile/wave with 8 matrix-pipe MFMAs
//  and kills the epilogue cross-lane shuffles. l is now the sum of the
//  exact f16 P used in PV (self-consistent normalization).
//  Kept: swapped-operand S^T=mfma(K,Q), no-max exp2 softmax (log2-domain,
//  std~0.25), pkrtz+permlane P-frag butterfly, BK=64 dbuf counted-vmcnt
//  GEMMs, fused qkv epilogue, wtq2 fusion, bit-packed mask, XCD z-locality,
//  s_setprio on MFMA clusters, separate combine_k + f16-A proj (R17
//  lesson: combine-in-proj = +100MB HBM).

typedef _Float16 half_t;
typedef _Float16 half8 __attribute__((ext_vector_type(8)));
typedef _Float16 half4v __attribute__((ext_vector_type(4)));
typedef float floatx4 __attribute__((ext_vector_type(4)));
typedef int int4v __attribute__((ext_vector_type(4)));

constexpr int Bc = 2, Tc = 2048, Mc = 1024, Cc = 512, Hc = 8, Dc = 64;
constexpr long BTC = (long)Bc * Tc * Cc;
constexpr long ZT  = (long)Bc * Hc * Tc;
constexpr float S1 = 0.18033688f;                 // 0.125 * log2(e)

enum { EPI_F16STORE = 0, EPI_QKV_XY = 1, EPI_PROJ = 2 };

struct EpiParams {
  half_t* h0;        // QXs  / f16 dest
  half_t* h1;        // KX
  half_t* h2;        // VXT
  half_t* h3;        // QYT
  half_t* h4;        // KY
  half_t* h5;        // KYT
  half_t* h6;        // VYT
  float* f0;
  const float* bias;
  float scale;
  int ldc;
  long bstride;
};

// async global->LDS, 16B per lane; dst must be wave-uniform base + lane*16.
__device__ __forceinline__ void gld_lds16(const half_t* g, half_t* l) {
  __builtin_amdgcn_global_load_lds(
      (const __attribute__((address_space(1))) void*)g,
      (__attribute__((address_space(3))) void*)l, 16, 0, 0);
}

// pack 2 f32 -> 2 f16 (RTZ) as one u32
__device__ __forceinline__ int pkrtz(float a, float b) {
  return __builtin_bit_cast(int, __builtin_amdgcn_cvt_pkrtz(a, b));
}
// v_permlane16_swap: a.row1<->b.row0, a.row3<->b.row2 (rows = 16-lane groups)
__device__ __forceinline__ void pl16(int& a, int& b) {
  asm volatile("v_permlane16_swap_b32 %0, %1" : "+v"(a), "+v"(b));
}
// v_permlane32_swap: a.rows{2,3} <-> b.rows{0,1}
__device__ __forceinline__ void pl32(int& a, int& b) {
  asm volatile("v_permlane32_swap_b32 %0, %1" : "+v"(a), "+v"(b));
}

// ---------------------------------------------------------------- GEMM (NT)
// C[r,c] = sum_k A[r,k]*Bt[c,k]. BK=64 double-buffered async staging with
// counted vmcnt, swizzled chunks (conflict-free ds_read_b128).
template <int BM, int BN, int WMG, int WNG, int EPI>
__global__ __launch_bounds__(256) void gemm_nt(
    const half_t* __restrict__ A, const half_t* __restrict__ Bt,
    int K, int lda, int ldb, long bsA, long bsB, EpiParams ep)
{
  constexpr int BK = 64;
  constexpr int WTM = BM / WMG, WTN = BN / WNG;
  constexpr int MI = WTM / 16, NI = WTN / 16;
  constexpr int AIT = BM * BK / 8 / 256;
  constexpr int BIT = BN * BK / 8 / 256;
  constexpr int NLD = AIT + BIT;
  __shared__ __align__(16) half_t As[2][BM * BK];
  __shared__ __align__(16) half_t Bs[2][BN * BK];

  const int tid = threadIdx.x;
  const int lane = tid & 63;
  const int wave = tid >> 6;
  const int wm = wave / WNG, wn = wave % WNG;
  const int r16 = lane & 15, g = lane >> 4;
  const int z = blockIdx.z;
  const long m0 = (long)blockIdx.y * BM;
  const long n0 = (long)blockIdx.x * BN;
  const half_t* Abase = A + (long)z * bsA + m0 * (long)lda;
  const half_t* Bbase = Bt + (long)z * bsB + n0 * (long)ldb;

  const int rA = wm * WTM + r16;
  const int rB = wn * WTN + r16;

  floatx4 acc[MI][NI];
#pragma unroll
  for (int mi = 0; mi < MI; ++mi)
#pragma unroll
    for (int ni = 0; ni < NI; ++ni)
      acc[mi][ni] = floatx4{0.f, 0.f, 0.f, 0.f};

  auto stage = [&](int kt, int buf) {
#pragma unroll
    for (int i = 0; i < AIT; ++i) {
      const int c = tid + i * 256;
      const int row = c >> 3, js = c & 7;
      const int jg = js ^ (row & 7);
      gld_lds16(Abase + (long)row * lda + kt + jg * 8, &As[buf][c * 8]);
    }
#pragma unroll
    for (int i = 0; i < BIT; ++i) {
      const int c = tid + i * 256;
      const int row = c >> 3, js = c & 7;
      const int jg = js ^ (row & 7);
      gld_lds16(Bbase + (long)row * ldb + kt + jg * 8, &Bs[buf][c * 8]);
    }
  };

  const int NIT = K / BK;
  stage(0, 0);
  asm volatile("" ::: "memory");

  for (int it = 0; it < NIT; ++it) {
    const bool hn = (it + 1 < NIT);
    if (hn) stage((it + 1) * BK, (it + 1) & 1);
    asm volatile("" ::: "memory");
    if (hn) {
      if constexpr (NLD == 6) asm volatile("s_waitcnt vmcnt(6)" ::: "memory");
      else if constexpr (NLD == 4) asm volatile("s_waitcnt vmcnt(4)" ::: "memory");
      else if constexpr (NLD == 8) asm volatile("s_waitcnt vmcnt(8)" ::: "memory");
      else asm volatile("s_waitcnt vmcnt(0)" ::: "memory");
    } else {
      asm volatile("s_waitcnt vmcnt(0)" ::: "memory");
    }
    __builtin_amdgcn_s_barrier();
    asm volatile("" ::: "memory");

    const half_t* Ab = As[it & 1];
    const half_t* Bb = Bs[it & 1];
    half8 aF[MI][2], bF[NI][2];
#pragma unroll
    for (int mi = 0; mi < MI; ++mi)
#pragma unroll
      for (int k2 = 0; k2 < 2; ++k2)
        aF[mi][k2] = *reinterpret_cast<const half8*>(
            &Ab[(rA + mi * 16) * BK + ((k2 * 4 + g) ^ (r16 & 7)) * 8]);
#pragma unroll
    for (int ni = 0; ni < NI; ++ni)
#pragma unroll
      for (int k2 = 0; k2 < 2; ++k2)
        bF[ni][k2] = *reinterpret_cast<const half8*>(
            &Bb[(rB + ni * 16) * BK + ((k2 * 4 + g) ^ (r16 & 7)) * 8]);
    __builtin_amdgcn_s_setprio(1);
#pragma unroll
    for (int k2 = 0; k2 < 2; ++k2)
#pragma unroll
      for (int mi = 0; mi < MI; ++mi)
#pragma unroll
        for (int ni = 0; ni < NI; ++ni)
          acc[mi][ni] = __builtin_amdgcn_mfma_f32_16x16x32_f16(
              aF[mi][k2], bF[ni][k2], acc[mi][ni], 0, 0, 0);
    __builtin_amdgcn_s_setprio(0);
    asm volatile("s_waitcnt lgkmcnt(0)" ::: "memory");
    __builtin_amdgcn_s_barrier();
    asm volatile("" ::: "memory");
  }

  // epilogue: C/D layout col=lane&15, row=(lane>>4)*4+reg  [m89-verified]
#pragma unroll
  for (int mi = 0; mi < MI; ++mi) {
#pragma unroll
    for (int ni = 0; ni < NI; ++ni) {
#pragma unroll
      for (int reg = 0; reg < 4; ++reg) {
        const int r = (int)m0 + wm * WTM + mi * 16 + g * 4 + reg;
        const int c = (int)n0 + wn * WTN + ni * 16 + r16;
        const float v = acc[mi][ni][reg];
        if constexpr (EPI == EPI_F16STORE) {
          ep.h0[(long)z * ep.bstride + (long)r * ep.ldc + c] = (half_t)(v * ep.scale);
        } else if constexpr (EPI == EPI_QKV_XY) {
          const float val = v + ep.bias[c];
          const int which = c >> 9;     // 0=q 1=k 2=v
          const int cc2 = c & 511;
          const int h = cc2 >> 6, d = cc2 & 63;
          if (r < Bc * Tc) {            // x rows
            const int b = r >> 11, t = r & (Tc - 1);
            const long bh = (long)(b * Hc + h);
            if (which == 0)      ep.h0[(bh * Tc + t) * Dc + d] = (half_t)(val * S1);  // QXs (log2e folded)
            else if (which == 1) ep.h1[(bh * Tc + t) * Dc + d] = (half_t)val;         // KX
            else                 ep.h2[(bh * Dc + d) * Tc + t] = (half_t)val;         // VXT
          } else {                      // y rows
            const int r2 = r - Bc * Tc;
            const int b = r2 >> 10, t = r2 & (Mc - 1);
            const long bh = (long)(b * Hc + h);
            if (which == 0)      ep.h3[(bh * Dc + d) * Mc + t] = (half_t)(val * 0.125f); // QYTs
            else if (which == 1) { ep.h4[(bh * Mc + t) * Dc + d] = (half_t)val;          // KY
                                   ep.h5[(bh * Dc + d) * Mc + t] = (half_t)val; }        // KYT
            else                 ep.h6[(bh * Dc + d) * Mc + t] = (half_t)val;            // VYT
          }
        } else {  // EPI_PROJ
          ep.f0[(long)r * Cc + c] = v + ep.bias[c];
        }
      }
    }
  }
}

// --------------------------------------------- fused WT+Q2 kernel
// grid (16 t-chunks, 16 z). Phase 1: WT[64][64] = 0.125 * QYTs[z] KYT[z]^T
// (K=1024, pipelined dbuf) -> LDS in phase-2 fragment layout. Phase 2:
// Q2[z, t0..t0+127, :] = QXs * WT^T (K=64, single tile, A staged async).
__global__ __launch_bounds__(256) void wtq2(
    const half_t* __restrict__ QYT, const half_t* __restrict__ KYT,
    const half_t* __restrict__ QX, half_t* __restrict__ Q2)
{
  __shared__ __align__(16) half_t As[2][4096];
  __shared__ __align__(16) half_t Bs[2][4096];
  __shared__ __align__(16) half_t WTs[4096];
  const int tid = threadIdx.x, lane = tid & 63, wave = tid >> 6;
  const int wm = wave >> 1, wn = wave & 1;
  const int r16 = lane & 15, g = lane >> 4;
  const int z = blockIdx.y;
  const int t0 = blockIdx.x * 128;
  const half_t* Aq = QYT + (long)z * Dc * Mc;
  const half_t* Bk = KYT + (long)z * Dc * Mc;

  auto stage1 = [&](int kt, int buf) {
#pragma unroll
    for (int i = 0; i < 2; ++i) {
      const int c = tid + i * 256;
      const int row = c >> 3, js = c & 7, jg = js ^ (row & 7);
      gld_lds16(Aq + (long)row * Mc + kt + jg * 8, &As[buf][c * 8]);
    }
#pragma unroll
    for (int i = 0; i < 2; ++i) {
      const int c = tid + i * 256;
      const int row = c >> 3, js = c & 7, jg = js ^ (row & 7);
      gld_lds16(Bk + (long)row * Mc + kt + jg * 8, &Bs[buf][c * 8]);
    }
  };

  floatx4 acc[2][2];
#pragma unroll
  for (int mi = 0; mi < 2; ++mi)
#pragma unroll
    for (int ni = 0; ni < 2; ++ni) acc[mi][ni] = floatx4{0.f, 0.f, 0.f, 0.f};

  const int rA = wm * 32 + r16, rB = wn * 32 + r16;
  stage1(0, 0);
  asm volatile("" ::: "memory");
  for (int it = 0; it < 16; ++it) {
    const bool hn = (it < 15);
    if (hn) stage1((it + 1) * 64, (it + 1) & 1);
    asm volatile("" ::: "memory");
    if (hn) asm volatile("s_waitcnt vmcnt(4)" ::: "memory");
    else    asm volatile("s_waitcnt vmcnt(0)" ::: "memory");
    __builtin_amdgcn_s_barrier();
    asm volatile("" ::: "memory");
    const half_t* Ab = As[it & 1];
    const half_t* Bb = Bs[it & 1];
    half8 aF[2][2], bF[2][2];
#pragma unroll
    for (int mi = 0; mi < 2; ++mi)
#pragma unroll
      for (int k2 = 0; k2 < 2; ++k2)
        aF[mi][k2] = *reinterpret_cast<const half8*>(
            &Ab[(rA + mi * 16) * 64 + ((k2 * 4 + g) ^ (r16 & 7)) * 8]);
#pragma unroll
    for (int ni = 0; ni < 2; ++ni)
#pragma unroll
      for (int k2 = 0; k2 < 2; ++k2)
        bF[ni][k2] = *reinterpret_cast<const half8*>(
            &Bb[(rB + ni * 16) * 64 + ((k2 * 4 + g) ^ (r16 & 7)) * 8]);
    __builtin_amdgcn_s_setprio(1);
#pragma unroll
    for (int k2 = 0; k2 < 2; ++k2)
#pragma unroll
      for (int mi = 0; mi < 2; ++mi)
#pragma unroll
        for (int ni = 0; ni < 2; ++ni)
          acc[mi][ni] = __builtin_amdgcn_mfma_f32_16x16x32_f16(
              aF[mi][k2], bF[ni][k2], acc[mi][ni], 0, 0, 0);
    __builtin_amdgcn_s_setprio(0);
    asm volatile("s_waitcnt lgkmcnt(0)" ::: "memory");
    __builtin_amdgcn_s_barrier();
    asm volatile("" ::: "memory");
  }

  // phase-2 A stage (As fully free after final barrier): QX rows t0..t0+127
  half_t* P2 = &As[0][0];
#pragma unroll
  for (int i = 0; i < 4; ++i) {
    const int c = tid + i * 256;
    const int row = c >> 3, js = c & 7, jg = js ^ (row & 7);
    gld_lds16(QX + ((long)z * Tc + t0 + row) * 64 + jg * 8, P2 + c * 8);
  }
  // WT -> LDS f16 in phase-2 fragment layout (chunk swizzle js^(row&7))
#pragma unroll
  for (int mi = 0; mi < 2; ++mi)
#pragma unroll
    for (int ni = 0; ni < 2; ++ni)
#pragma unroll
      for (int reg = 0; reg < 4; ++reg) {
        const int r = wm * 32 + mi * 16 + g * 4 + reg;   // d2
        const int c = wn * 32 + ni * 16 + r16;           // d1
        WTs[r * 64 + (((c >> 3) ^ (r & 7)) << 3) + (c & 7)] =
            (half_t)(acc[mi][ni][reg] * 0.125f);
      }
  __syncthreads();   // drains vmcnt (QX stage) + lgkm (WTs writes)

  // phase 2: per wave 32 t-rows, full 64 d2 cols, K=64
  floatx4 a2[2][4];
#pragma unroll
  for (int mi = 0; mi < 2; ++mi)
#pragma unroll
    for (int ni = 0; ni < 4; ++ni) a2[mi][ni] = floatx4{0.f, 0.f, 0.f, 0.f};
  const int rA2 = wave * 32 + r16;
  half8 aF2[2][2], bF2[4][2];
#pragma unroll
  for (int mi = 0; mi < 2; ++mi)
#pragma unroll
    for (int k2 = 0; k2 < 2; ++k2)
      aF2[mi][k2] = *reinterpret_cast<const half8*>(
          &P2[(rA2 + mi * 16) * 64 + ((k2 * 4 + g) ^ (r16 & 7)) * 8]);
#pragma unroll
  for (int ni = 0; ni < 4; ++ni)
#pragma unroll
    for (int k2 = 0; k2 < 2; ++k2)
      bF2[ni][k2] = *reinterpret_cast<const half8*>(
          &WTs[(ni * 16 + r16) * 64 + ((k2 * 4 + g) ^ (r16 & 7)) * 8]);
#pragma unroll
  for (int k2 = 0; k2 < 2; ++k2)
#pragma unroll
    for (int mi = 0; mi < 2; ++mi)
#pragma unroll
      for (int ni = 0; ni < 4; ++ni)
        a2[mi][ni] = __builtin_amdgcn_mfma_f32_16x16x32_f16(
            aF2[mi][k2], bF2[ni][k2], a2[mi][ni], 0, 0, 0);
#pragma unroll
  for (int mi = 0; mi < 2; ++mi)
#pragma unroll
    for (int ni = 0; ni < 4; ++ni)
#pragma unroll
      for (int reg = 0; reg < 4; ++reg) {
        const int t = t0 + wave * 32 + mi * 16 + g * 4 + reg;
        const int c = ni * 16 + r16;
        Q2[((long)z * Tc + t) * 64 + c] = (half_t)a2[mi][ni][reg];
      }
}

// ------------------------------------------------------------ flash staging
__device__ __forceinline__ void stageK128(const half_t* Kz, int s0, half_t* dst, int tid) {
#pragma unroll
  for (int i = 0; i < 4; ++i) {
    const int c = tid + i * 256;
    const int row = c >> 3, js = c & 7;
    const int jg = js ^ (row & 7);
    gld_lds16(Kz + (long)(s0 + row) * 64 + jg * 8, dst + c * 8);
  }
}
__device__ __forceinline__ void stageV128(const half_t* Vz, int s0, int Slen, half_t* dst, int tid) {
#pragma unroll
  for (int i = 0; i < 4; ++i) {
    const int c = tid + i * 256;
    const int row = c >> 4, js = c & 15;
    const int jg = js ^ (row & 15);
    gld_lds16(Vz + (long)row * Slen + s0 + jg * 8, dst + c * 8);
  }
}

// --------------------------------------------------------- flash body (MI=2)
// 128 q-rows/block, 8 s-tiles of 128 over [sbeg, sbeg+scount). Scores in
// log2 domain (log2e folded into Q), no-max softmax. R15 schedule:
//  vmcnt(4)+barrier [K(t) ready, V(t) flying] ; QK MFMA cluster ; issue
//  K(t+1) ; softmax (mask+exp2, separated phase) ; vmcnt(4)+barrier [V(t)
//  ready] ; PV (+ones-MFMA row-sum) ; barrier ; issue V(t+1).
// PARTIAL: unnormalized O f32 -> PO + row-sum -> Lp. else normalized f16.
template <bool MASKED, bool PARTIAL>
__device__ __forceinline__ void flash_body(
    const half_t* __restrict__ Qp, const half_t* __restrict__ Kp,
    const half_t* __restrict__ Vp, const unsigned char* __restrict__ mpk,
    float* __restrict__ PO, float* __restrict__ Lp, half_t* __restrict__ outF,
    int Slen, int sbeg, int scount, int z, int q0,
    half_t* Kb0, half_t* Kb1, half_t* Vb)
{
  const int tid = threadIdx.x, lane = tid & 63, w = tid >> 6;
  const int r16 = lane & 15, g = lane >> 4;
  const int b = z >> 3, h = z & 7;
  const int NT = Slen >> 7;
  const half_t* Qz = Qp + ((long)z * Tc + q0) * 64;
  const half_t* Kz = Kp + (long)z * Slen * 64;
  const half_t* Vz = Vp + (long)z * 64 * Slen;

  // prologue staging: K(0), V(0) (oldest 8 vmem ops, in this order)
  stageK128(Kz, sbeg, Kb0, tid);
  asm volatile("" ::: "memory");
  stageV128(Vz, sbeg, Slen, Vb, tid);
  asm volatile("" ::: "memory");

  half8 aQ[2][2];
#pragma unroll
  for (int mi = 0; mi < 2; ++mi)
#pragma unroll
    for (int k2 = 0; k2 < 2; ++k2)
      aQ[mi][k2] = *reinterpret_cast<const half8*>(
          Qz + (w * 32 + mi * 16 + r16) * 64 + k2 * 32 + g * 8);

  half8 vones;
#pragma unroll
  for (int j = 0; j < 8; ++j) vones[j] = (half_t)1.f;

  floatx4 oaccT[2][4];
  floatx4 lacc4[2];
#pragma unroll
  for (int mi = 0; mi < 2; ++mi) {
    lacc4[mi] = floatx4{0.f, 0.f, 0.f, 0.f};
#pragma unroll
    for (int no = 0; no < 4; ++no) oaccT[mi][no] = floatx4{0.f, 0.f, 0.f, 0.f};
  }

  const int send = sbeg + scount;
  int cur = 0;
  for (int s0 = sbeg; s0 < send; s0 += 128) {
    const bool hn = (s0 + 128 < send);
    // K(t) ready (V(t) may still fly; K is the oldest outstanding group)
    asm volatile("s_waitcnt vmcnt(4)" ::: "memory");
    __builtin_amdgcn_s_barrier();
    asm volatile("" ::: "memory");

    unsigned int mb32[2];
    if constexpr (MASKED) {
      const int tile = s0 >> 7;
#pragma unroll
      for (int mi = 0; mi < 2; ++mi) {
        const int q = q0 + w * 32 + mi * 16 + r16;
        mb32[mi] = *reinterpret_cast<const unsigned int*>(
            mpk + ((long)q * NT + tile) * 16 + 4 * g);
      }
    }

    // S^T = K Q^T : 16 b128 reads feed 32 MFMAs
    floatx4 sacc[2][8];
#pragma unroll
    for (int mi = 0; mi < 2; ++mi)
#pragma unroll
      for (int ni = 0; ni < 8; ++ni) sacc[mi][ni] = floatx4{0.f, 0.f, 0.f, 0.f};
    const half_t* Kc = cur ? Kb1 : Kb0;
    __builtin_amdgcn_s_setprio(1);
#pragma unroll
    for (int ni = 0; ni < 8; ++ni) {
      const int rB = ni * 16 + r16;
      const half8 b0 = *reinterpret_cast<const half8*>(&Kc[rB * 64 + (g ^ (rB & 7)) * 8]);
      const half8 b1 = *reinterpret_cast<const half8*>(&Kc[rB * 64 + ((4 + g) ^ (rB & 7)) * 8]);
#pragma unroll
      for (int mi = 0; mi < 2; ++mi) {
        sacc[mi][ni] = __builtin_amdgcn_mfma_f32_16x16x32_f16(b0, aQ[mi][0], sacc[mi][ni], 0, 0, 0);
        sacc[mi][ni] = __builtin_amdgcn_mfma_f32_16x16x32_f16(b1, aQ[mi][1], sacc[mi][ni], 0, 0, 0);
      }
    }
    __builtin_amdgcn_s_setprio(0);
    // prefetch K(t+1) into the other buffer; lands under softmax+PV
    if (hn) stageK128(Kz, s0 + 128, cur ? Kb0 : Kb1, tid);
    asm volatile("" ::: "memory");

    // in-register softmax (separated phase): mask + exp2 only; row-sum
    // rides the PV ones-MFMA.
#pragma unroll
    for (int mi = 0; mi < 2; ++mi) {
      if constexpr (MASKED) {
        if (mb32[mi] != 0xffffffffu) {
#pragma unroll
          for (int reg = 0; reg < 4; ++reg)
#pragma unroll
            for (int ni = 0; ni < 8; ++ni)
              if (!((mb32[mi] >> (reg * 8 + ni)) & 1)) sacc[mi][ni][reg] = -__builtin_inff();
        }
      }
#pragma unroll
      for (int ni = 0; ni < 8; ++ni)
#pragma unroll
        for (int reg = 0; reg < 4; ++reg)
          sacc[mi][ni][reg] = __builtin_amdgcn_exp2f(sacc[mi][ni][reg]);
    }

    // V(t) ready (K(t+1) = newest 4 still in flight when hn)
    if (hn) { asm volatile("s_waitcnt vmcnt(4)" ::: "memory"); }
    else    { asm volatile("s_waitcnt vmcnt(0)" ::: "memory"); }
    __builtin_amdgcn_s_barrier();
    asm volatile("" ::: "memory");

    // O^T += V^T P^T ; l += ones·P^T (row-sum via matrix pipe)
#pragma unroll
    for (int c = 0; c < 4; ++c) {
      half8 bVv[4];
#pragma unroll
      for (int no = 0; no < 4; ++no) {
        const int rV = no * 16 + r16;
        bVv[no] = *reinterpret_cast<const half8*>(
            &Vb[rV * 128 + ((c * 4 + g) ^ (rV & 15)) * 8]);
      }
#pragma unroll
      for (int mi = 0; mi < 2; ++mi) {
        // butterfly P^T frag: target word p_t at lane g <-
        // pk[2c+(g>>1)][p_t&1] of lane 2(g&1)+(p_t>>1)
        int x0 = pkrtz(sacc[mi][2 * c][0],     sacc[mi][2 * c][1]);
        int x1 = pkrtz(sacc[mi][2 * c][2],     sacc[mi][2 * c][3]);
        int x2 = pkrtz(sacc[mi][2 * c + 1][0], sacc[mi][2 * c + 1][1]);
        int x3 = pkrtz(sacc[mi][2 * c + 1][2], sacc[mi][2 * c + 1][3]);
        pl32(x0, x2); pl32(x1, x3);   // resolve g1 <-> ni bit
        pl16(x0, x2); pl16(x1, x3);   // resolve g0 <-> word bit
        int4v wv; wv[0] = x0; wv[1] = x1; wv[2] = x2; wv[3] = x3;
        const half8 aP = __builtin_bit_cast(half8, wv);
        __builtin_amdgcn_s_setprio(1);
#pragma unroll
        for (int no = 0; no < 4; ++no)
          oaccT[mi][no] = __builtin_amdgcn_mfma_f32_16x16x32_f16(bVv[no], aP, oaccT[mi][no], 0, 0, 0);
        lacc4[mi] = __builtin_amdgcn_mfma_f32_16x16x32_f16(vones, aP, lacc4[mi], 0, 0, 0);
        __builtin_amdgcn_s_setprio(0);
      }
    }
    __builtin_amdgcn_s_barrier();
    asm volatile("" ::: "memory");
    // prefetch V(t+1); lands under next tile's QK^T + softmax
    if (hn) stageV128(Vz, s0 + 128, Slen, Vb, tid);
    asm volatile("" ::: "memory");
    cur ^= 1;
  }

  // epilogue: l_q sits in every lane's lacc4[mi][0] (all rows of the ones-
  // MFMA D are identical; col=lane&15=q). No cross-lane reduce needed.
  float ls2[2];
#pragma unroll
  for (int mi = 0; mi < 2; ++mi) ls2[mi] = lacc4[mi][0];

  float* slab = reinterpret_cast<float*>(Vb) + w * 1024;
#pragma unroll
  for (int mi = 0; mi < 2; ++mi) {
    const int tq = q0 + w * 32 + mi * 16;
    if constexpr (PARTIAL) {
      if (lane < 16) Lp[(long)z * Tc + tq + r16] = ls2[mi];
    }
    const float sc = PARTIAL ? 1.f : (1.f / ls2[mi]);
#pragma unroll
    for (int no = 0; no < 4; ++no) {
      floatx4 v = oaccT[mi][no];
      if constexpr (!PARTIAL) v *= sc;
      *reinterpret_cast<floatx4*>(&slab[r16 * 64 + no * 16 + (g ^ (r16 & 3)) * 4]) = v;
    }
#pragma unroll
    for (int it = 0; it < 4; ++it) {
      const int q2 = it * 4 + g;
      const int d4 = r16;
      const floatx4 v = *reinterpret_cast<const floatx4*>(
          &slab[q2 * 64 + (d4 >> 2) * 16 + ((d4 & 3) ^ (q2 & 3)) * 4]);
      const long off = ((long)(b * Tc + tq + q2)) * Cc + h * 64 + d4 * 4;
      if constexpr (PARTIAL) {
        *reinterpret_cast<floatx4*>(&PO[off]) = v;
      } else {
        half4v hh; hh[0] = (half_t)v[0]; hh[1] = (half_t)v[1];
        hh[2] = (half_t)v[2]; hh[3] = (half_t)v[3];
        *reinterpret_cast<half4v*>(&outF[off]) = hh;
      }
    }
  }
}

// 768 blocks, each exactly 8 s-tiles (= 3 blocks/CU, one balanced round):
//  bx < 512:  att0 (chained, masked), s-half sh=(bx>>4)&1, unnormalized f32+L
//  bx >= 512: att1 (first), full s-range, normalized f16 -> DH2
__global__ __launch_bounds__(256, 3) void flash_both(
    const half_t* __restrict__ Q2, const half_t* __restrict__ KX,
    const half_t* __restrict__ VXT, const unsigned char* __restrict__ mpk,
    const half_t* __restrict__ QX, const half_t* __restrict__ KY,
    const half_t* __restrict__ VYT,
    float* __restrict__ PO, float* __restrict__ Lp, half_t* __restrict__ DH2)
{
  __shared__ __align__(16) half_t Kb0[8192];
  __shared__ __align__(16) half_t Kb1[8192];
  __shared__ __align__(16) half_t Vb[8192];
  const int bx = blockIdx.x;
  if (bx < 512) {
    const int z  = ((bx & 7) << 1) | ((bx >> 3) & 1);   // z-local per XCD
    const int sh = (bx >> 4) & 1;
    const int q0 = (bx >> 5) * 128;
    flash_body<true, true>(Q2, KX, VXT, mpk,
                           PO + (long)sh * BTC, Lp + (long)sh * ZT, nullptr,
                           Tc, sh * 1024, 1024, z, q0, Kb0, Kb1, Vb);
  } else {
    const int b2 = bx - 512;
    const int z  = ((b2 & 7) << 1) | ((b2 >> 3) & 1);
    const int q0 = (b2 >> 4) * 128;
    flash_body<false, false>(QX, KY, VYT, nullptr,
                             nullptr, nullptr, DH2,
                             Mc, 0, Mc, z, q0, Kb0, Kb1, Vb);
  }
}

// --------------------------- combine att0 s-halves + diff with DH2 -> DH
__global__ __launch_bounds__(256) void combine_k(
    const float* __restrict__ PO, const float* __restrict__ Lp,
    const half_t* __restrict__ DH2, half_t* __restrict__ DH)
{
  const long idx = (long)blockIdx.x * 256 + threadIdx.x;   // over BTC/4
  const long c4 = idx * 4;
  const int c = (int)(c4 & (Cc - 1));
  const long bt = c4 >> 9;
  const int h = c >> 6;
  const int b = (int)(bt >> 11), t = (int)(bt & (Tc - 1));
  const long zt = (long)(b * Hc + h) * Tc + t;
  const float ainv = 1.f / (Lp[zt] + Lp[ZT + zt]);
  const float4* PO4 = reinterpret_cast<const float4*>(PO);
  const float4 oa0 = PO4[idx];
  const float4 oa1 = PO4[BTC / 4 + idx];
  const half4v dv = reinterpret_cast<const half4v*>(DH2)[idx];
  half4v r;
  r[0] = (half_t)((float)dv[0] - (oa0.x + oa1.x) * ainv);
  r[1] = (half_t)((float)dv[1] - (oa0.y + oa1.y) * ainv);
  r[2] = (half_t)((float)dv[2] - (oa0.z + oa1.z) * ainv);
  r[3] = (half_t)((float)dv[3] - (oa0.w + oa1.w) * ainv);
  reinterpret_cast<half4v*>(DH)[idx] = r;
}

// ----------------------------------------------- prep: converts + mask pack
__device__ __forceinline__ void cvt4(const float* in, half_t* out, long i) {
  const float4 f = reinterpret_cast<const float4*>(in)[i];
  half4v h; h[0] = (half_t)f.x; h[1] = (half_t)f.y; h[2] = (half_t)f.z; h[3] = (half_t)f.w;
  reinterpret_cast<half4v*>(out)[i] = h;
}

__global__ __launch_bounds__(256) void prep(
    const float* __restrict__ x, const float* __restrict__ y,
    const float* __restrict__ qw, const float* __restrict__ pw,
    const int* __restrict__ mask,
    half_t* __restrict__ XH, half_t* __restrict__ YH,
    half_t* __restrict__ WQ, half_t* __restrict__ WP,
    unsigned char* __restrict__ mpk)
{
  const long i = (long)blockIdx.x * 256 + threadIdx.x;
  constexpr long n0 = 524288;            // x/4
  constexpr long n1 = n0 + 262144;       // y/4
  constexpr long n2 = n1 + 196608;       // qkv_w/4
  constexpr long n3 = n2 + 65536;        // proj_w/4
  if (i < n0) cvt4(x, XH, i);
  else if (i < n1) cvt4(y, YH, i - n0);
  else if (i < n2) cvt4(qw, WQ, i - n1);
  else if (i < n3) cvt4(pw, WP, i - n2);
  else {
    const long idx = i - n3;             // [0, Tc*256)
    const int t = (int)(idx >> 8), tile = (int)((idx >> 4) & 15), r16 = (int)(idx & 15);
    const int* row = mask + (long)t * Tc + tile * 128 + r16;
    unsigned int bbits = 0;
#pragma unroll
    for (int ni = 0; ni < 8; ++ni)
      bbits |= (row[ni * 16] != 0 ? 1u : 0u) << ni;
    mpk[idx] = (unsigned char)bbits;
  }
}

// ------------------------------------------------------------- workspace map
constexpr size_t OFF_XH   = 0;                                   // [B*T,C] f16 (YH must follow!)
constexpr size_t OFF_YH   = OFF_XH   + (size_t)Bc*Tc*Cc*2;       // contiguous rows after XH
constexpr size_t OFF_WQ   = OFF_YH   + (size_t)Bc*Mc*Cc*2;
constexpr size_t OFF_WP   = OFF_WQ   + (size_t)3*Cc*Cc*2;
constexpr size_t OFF_QX   = OFF_WP   + (size_t)Cc*Cc*2;          // [z,T,D] *0.125*log2e
constexpr size_t OFF_KX   = OFF_QX   + (size_t)Bc*Hc*Tc*Dc*2;    // [z,T,D]
constexpr size_t OFF_VXT  = OFF_KX   + (size_t)Bc*Hc*Tc*Dc*2;    // [z,D,T]
constexpr size_t OFF_QYT  = OFF_VXT  + (size_t)Bc*Hc*Tc*Dc*2;    // [z,D,M] *0.125
constexpr size_t OFF_KY   = OFF_QYT  + (size_t)Bc*Hc*Mc*Dc*2;    // [z,M,D]
constexpr size_t OFF_KYT  = OFF_KY   + (size_t)Bc*Hc*Mc*Dc*2;    // [z,D,M]
constexpr size_t OFF_VYT  = OFF_KYT  + (size_t)Bc*Hc*Mc*Dc*2;    // [z,D,M]
constexpr size_t OFF_Q2   = OFF_VYT  + (size_t)Bc*Hc*Mc*Dc*2;    // [z,T,D]
constexpr size_t OFF_DH   = OFF_Q2   + (size_t)Bc*Hc*Tc*Dc*2;    // [B,T,C] diff f16
constexpr size_t OFF_DH2  = OFF_DH   + (size_t)Bc*Tc*Cc*2;       // [B,T,C] cval_x2y f16
constexpr size_t OFF_MPK  = OFF_DH2  + (size_t)Bc*Tc*Cc*2;       // [T,16,16] u8
constexpr size_t OFF_PO   = OFF_MPK  + (size_t)Tc*256;           // [2][B,T,C] f32 unnormalized
constexpr size_t OFF_L    = OFF_PO   + (size_t)2*BTC*4;          // [2][ZT] f32 row sums
// total ~55 MB

extern "C" void kernel_launch(void* const* d_in, const int* in_sizes, int n_in,
                              void* d_out, int out_size, void* d_ws, size_t ws_size,
                              hipStream_t stream) {
  const float* x      = (const float*)d_in[0];
  const float* y      = (const float*)d_in[1];
  const int*   mask   = (const int*)  d_in[2];
  const float* qkv_b  = (const float*)d_in[4];
  const float* proj_b = (const float*)d_in[6];
  float* out = (float*)d_out;
  char* ws = (char*)d_ws;

  half_t* XH   = (half_t*)(ws + OFF_XH);
  half_t* YH   = (half_t*)(ws + OFF_YH);
  half_t* WQ   = (half_t*)(ws + OFF_WQ);
  half_t* WP   = (half_t*)(ws + OFF_WP);
  half_t* QX   = (half_t*)(ws + OFF_QX);
  half_t* KX   = (half_t*)(ws + OFF_KX);
  half_t* VXT  = (half_t*)(ws + OFF_VXT);
  half_t* QYT  = (half_t*)(ws + OFF_QYT);
  half_t* KY   = (half_t*)(ws + OFF_KY);
  half_t* KYT  = (half_t*)(ws + OFF_KYT);
  half_t* VYT  = (half_t*)(ws + OFF_VYT);
  half_t* Q2   = (half_t*)(ws + OFF_Q2);
  half_t* DH   = (half_t*)(ws + OFF_DH);
  half_t* DH2  = (half_t*)(ws + OFF_DH2);
  unsigned char* MPK = (unsigned char*)(ws + OFF_MPK);
  float*  PO   = (float*) (ws + OFF_PO);
  float*  Lp   = (float*) (ws + OFF_L);

  // converts + mask packing (one launch)
  prep<<<6144, 256, 0, stream>>>(x, y, (const float*)d_in[3], (const float*)d_in[5],
                                 mask, XH, YH, WQ, WP, MPK);

  // fused qkv projection for x and y (XH||YH contiguous: 6144 rows)
  {
    EpiParams ep{};
    ep.h0 = QX; ep.h1 = KX; ep.h2 = VXT; ep.h3 = QYT;
    ep.h4 = KY; ep.h5 = KYT; ep.h6 = VYT; ep.bias = qkv_b;
    gemm_nt<128,64,2,2,EPI_QKV_XY><<<dim3(24, 48, 1), 256, 0, stream>>>(
        XH, WQ, Cc, Cc, Cc, 0, 0, ep);
  }

  // fused WT+Q2: 16 t-chunks x 16 z = 256 blocks
  wtq2<<<dim3(16, 16), 256, 0, stream>>>(QYT, KYT, QX, Q2);

  // balanced flash: 512 att0-half blocks + 256 att1 blocks = 768 (3/CU)
  flash_both<<<dim3(768), 256, 0, stream>>>(
      Q2, KX, VXT, MPK, QX, KY, VYT, PO, Lp, DH2);

  // combine att0 halves + diff with DH2 -> DH
  combine_k<<<(int)(BTC/4/256), 256, 0, stream>>>(PO, Lp, DH2, DH);

  // out = DH @ proj_w^T + proj_b
  {
    EpiParams ep{}; ep.f0 = out; ep.bias = proj_b;
    gemm_nt<64,64,2,2,EPI_PROJ><<<dim3(8, 64, 1), 256, 0, stream>>>(
        DH, WP, Cc, Cc, Cc, 0, 0, ep);
  }
}

// Round 8
// 174.494 us; speedup vs baseline: 1.1138x; 1.0243x over previous
//
#include <hip/hip_runtime.h>

// CrossAttentionPro on MI355X — Round 20:
//  (a) qkv epilogue coalescing: the 4 transposed outputs (VXT/QYT/KYT/VYT)
//      were scatter-stored (2B per lane at 2-4KB stride = 64 cache lines
//      per store). Each block owns one (tensor,head) 128x64 tile -> now
//      transposed through a 64x136 LDS slab (As reused after the K-loop's
//      final barrier) and stored as coalesced 16B row chunks.
//  (b) PO (att0 unnormalized O) f32 -> f16: halves att0 epilogue writes
//      and combine reads (|O|~32-200, rel err 1e-3 -> ~5e-5 after /l).
//  Flash unchanged from R19 (matched best; VALU 41->31, Mfma 24.8%):
//  R15 schedule + ones-MFMA row-sum, swapped-operand S^T=mfma(K,Q), no-max
//  exp2 softmax, pkrtz+permlane P-frag butterfly, K dbuf + counted vmcnt,
//  48KB LDS 3 blk/CU, 768-block balanced grid, XCD z-locality, setprio.

typedef _Float16 half_t;
typedef _Float16 half8 __attribute__((ext_vector_type(8)));
typedef _Float16 half4v __attribute__((ext_vector_type(4)));
typedef float floatx4 __attribute__((ext_vector_type(4)));
typedef int int4v __attribute__((ext_vector_type(4)));

constexpr int Bc = 2, Tc = 2048, Mc = 1024, Cc = 512, Hc = 8, Dc = 64;
constexpr long BTC = (long)Bc * Tc * Cc;
constexpr long ZT  = (long)Bc * Hc * Tc;
constexpr float S1 = 0.18033688f;                 // 0.125 * log2(e)

enum { EPI_F16STORE = 0, EPI_QKV_XY = 1, EPI_PROJ = 2 };

struct EpiParams {
  half_t* h0;        // QXs  / f16 dest
  half_t* h1;        // KX
  half_t* h2;        // VXT
  half_t* h3;        // QYT
  half_t* h4;        // KY
  half_t* h5;        // KYT
  half_t* h6;        // VYT
  float* f0;
  const float* bias;
  float scale;
  int ldc;
  long bstride;
};

// async global->LDS, 16B per lane; dst must be wave-uniform base + lane*16.
__device__ __forceinline__ void gld_lds16(const half_t* g, half_t* l) {
  __builtin_amdgcn_global_load_lds(
      (const __attribute__((address_space(1))) void*)g,
      (__attribute__((address_space(3))) void*)l, 16, 0, 0);
}

// pack 2 f32 -> 2 f16 (RTZ) as one u32
__device__ __forceinline__ int pkrtz(float a, float b) {
  return __builtin_bit_cast(int, __builtin_amdgcn_cvt_pkrtz(a, b));
}
// v_permlane16_swap: a.row1<->b.row0, a.row3<->b.row2 (rows = 16-lane groups)
__device__ __forceinline__ void pl16(int& a, int& b) {
  asm volatile("v_permlane16_swap_b32 %0, %1" : "+v"(a), "+v"(b));
}
// v_permlane32_swap: a.rows{2,3} <-> b.rows{0,1}
__device__ __forceinline__ void pl32(int& a, int& b) {
  asm volatile("v_permlane32_swap_b32 %0, %1" : "+v"(a), "+v"(b));
}

// ---------------------------------------------------------------- GEMM (NT)
// C[r,c] = sum_k A[r,k]*Bt[c,k]. BK=64 double-buffered async staging with
// counted vmcnt, swizzled chunks (conflict-free ds_read_b128).
// EPI_QKV_XY (BM=128,BN=64): each block = one (tensor,head) 128x64 tile;
// transposed outputs routed through a 64x136 LDS slab for coalesced stores.
template <int BM, int BN, int WMG, int WNG, int EPI>
__global__ __launch_bounds__(256) void gemm_nt(
    const half_t* __restrict__ A, const half_t* __restrict__ Bt,
    int K, int lda, int ldb, long bsA, long bsB, EpiParams ep)
{
  constexpr int BK = 64;
  constexpr int WTM = BM / WMG, WTN = BN / WNG;
  constexpr int MI = WTM / 16, NI = WTN / 16;
  constexpr int AIT = BM * BK / 8 / 256;
  constexpr int BIT = BN * BK / 8 / 256;
  constexpr int NLD = AIT + BIT;
  __shared__ __align__(16) half_t As[2][BM * BK];
  __shared__ __align__(16) half_t Bs[2][BN * BK];

  const int tid = threadIdx.x;
  const int lane = tid & 63;
  const int wave = tid >> 6;
  const int wm = wave / WNG, wn = wave % WNG;
  const int r16 = lane & 15, g = lane >> 4;
  const int z = blockIdx.z;
  const long m0 = (long)blockIdx.y * BM;
  const long n0 = (long)blockIdx.x * BN;
  const half_t* Abase = A + (long)z * bsA + m0 * (long)lda;
  const half_t* Bbase = Bt + (long)z * bsB + n0 * (long)ldb;

  const int rA = wm * WTM + r16;
  const int rB = wn * WTN + r16;

  floatx4 acc[MI][NI];
#pragma unroll
  for (int mi = 0; mi < MI; ++mi)
#pragma unroll
    for (int ni = 0; ni < NI; ++ni)
      acc[mi][ni] = floatx4{0.f, 0.f, 0.f, 0.f};

  auto stage = [&](int kt, int buf) {
#pragma unroll
    for (int i = 0; i < AIT; ++i) {
      const int c = tid + i * 256;
      const int row = c >> 3, js = c & 7;
      const int jg = js ^ (row & 7);
      gld_lds16(Abase + (long)row * lda + kt + jg * 8, &As[buf][c * 8]);
    }
#pragma unroll
    for (int i = 0; i < BIT; ++i) {
      const int c = tid + i * 256;
      const int row = c >> 3, js = c & 7;
      const int jg = js ^ (row & 7);
      gld_lds16(Bbase + (long)row * ldb + kt + jg * 8, &Bs[buf][c * 8]);
    }
  };

  const int NIT = K / BK;
  stage(0, 0);
  asm volatile("" ::: "memory");

  for (int it = 0; it < NIT; ++it) {
    const bool hn = (it + 1 < NIT);
    if (hn) stage((it + 1) * BK, (it + 1) & 1);
    asm volatile("" ::: "memory");
    if (hn) {
      if constexpr (NLD == 6) asm volatile("s_waitcnt vmcnt(6)" ::: "memory");
      else if constexpr (NLD == 4) asm volatile("s_waitcnt vmcnt(4)" ::: "memory");
      else if constexpr (NLD == 8) asm volatile("s_waitcnt vmcnt(8)" ::: "memory");
      else asm volatile("s_waitcnt vmcnt(0)" ::: "memory");
    } else {
      asm volatile("s_waitcnt vmcnt(0)" ::: "memory");
    }
    __builtin_amdgcn_s_barrier();
    asm volatile("" ::: "memory");

    const half_t* Ab = As[it & 1];
    const half_t* Bb = Bs[it & 1];
    half8 aF[MI][2], bF[NI][2];
#pragma unroll
    for (int mi = 0; mi < MI; ++mi)
#pragma unroll
      for (int k2 = 0; k2 < 2; ++k2)
        aF[mi][k2] = *reinterpret_cast<const half8*>(
            &Ab[(rA + mi * 16) * BK + ((k2 * 4 + g) ^ (r16 & 7)) * 8]);
#pragma unroll
    for (int ni = 0; ni < NI; ++ni)
#pragma unroll
      for (int k2 = 0; k2 < 2; ++k2)
        bF[ni][k2] = *reinterpret_cast<const half8*>(
            &Bb[(rB + ni * 16) * BK + ((k2 * 4 + g) ^ (r16 & 7)) * 8]);
    __builtin_amdgcn_s_setprio(1);
#pragma unroll
    for (int k2 = 0; k2 < 2; ++k2)
#pragma unroll
      for (int mi = 0; mi < MI; ++mi)
#pragma unroll
        for (int ni = 0; ni < NI; ++ni)
          acc[mi][ni] = __builtin_amdgcn_mfma_f32_16x16x32_f16(
              aF[mi][k2], bF[ni][k2], acc[mi][ni], 0, 0, 0);
    __builtin_amdgcn_s_setprio(0);
    asm volatile("s_waitcnt lgkmcnt(0)" ::: "memory");
    __builtin_amdgcn_s_barrier();
    asm volatile("" ::: "memory");
  }

  // epilogue: C/D layout col=lane&15, row=(lane>>4)*4+reg  [m89-verified]
  // transposed-output slab (reuses As, free after last barrier): [64][136]
  half_t* Txp = &As[0][0];
  const bool isx  = (m0 < (long)Bc * Tc);
  const int which = (int)(n0 >> 9);
  const int hh    = ((int)n0 & 511) >> 6;

#pragma unroll
  for (int mi = 0; mi < MI; ++mi) {
#pragma unroll
    for (int ni = 0; ni < NI; ++ni) {
#pragma unroll
      for (int reg = 0; reg < 4; ++reg) {
        const int r = (int)m0 + wm * WTM + mi * 16 + g * 4 + reg;
        const int c = (int)n0 + wn * WTN + ni * 16 + r16;
        const float v = acc[mi][ni][reg];
        if constexpr (EPI == EPI_F16STORE) {
          ep.h0[(long)z * ep.bstride + (long)r * ep.ldc + c] = (half_t)(v * ep.scale);
        } else if constexpr (EPI == EPI_QKV_XY) {
          const float val = v + ep.bias[c];
          const int d = c & 63;
          const int rloc = r - (int)m0;
          if (isx) {                    // x rows
            const int b = (int)(m0 >> 11);
            const int t = r & (Tc - 1);
            const long bh = (long)(b * Hc + hh);
            if (which == 0)      ep.h0[(bh * Tc + t) * Dc + d] = (half_t)(val * S1);  // QXs
            else if (which == 1) ep.h1[(bh * Tc + t) * Dc + d] = (half_t)val;         // KX
            else                 Txp[d * 136 + rloc] = (half_t)val;                   // VXT (LDS)
          } else {                      // y rows
            const long m2 = m0 - (long)Bc * Tc;
            const int b = (int)(m2 >> 10);
            const int t = (r - Bc * Tc) & (Mc - 1);
            const long bh = (long)(b * Hc + hh);
            if (which == 0)      Txp[d * 136 + rloc] = (half_t)(val * 0.125f);        // QYT (LDS)
            else if (which == 1) { ep.h4[(bh * Mc + t) * Dc + d] = (half_t)val;       // KY
                                   Txp[d * 136 + rloc] = (half_t)val; }               // KYT (LDS)
            else                 Txp[d * 136 + rloc] = (half_t)val;                   // VYT (LDS)
          }
        } else {  // EPI_PROJ
          ep.f0[(long)r * Cc + c] = v + ep.bias[c];
        }
      }
    }
  }

  if constexpr (EPI == EPI_QKV_XY && BM == 128) {
    const bool hasT = isx ? (which == 2) : true;
    if (hasT) {                     // block-uniform -> barrier is safe
      __syncthreads();
      half_t* dstT; int L; long tb; int b;
      if (isx) { dstT = ep.h2; L = Tc; tb = m0 & (Tc - 1); b = (int)(m0 >> 11); }
      else {
        const long m2 = m0 - (long)Bc * Tc;
        b = (int)(m2 >> 10); tb = m2 & (Mc - 1); L = Mc;
        dstT = (which == 0) ? ep.h3 : (which == 1) ? ep.h5 : ep.h6;
      }
      const long bh = (long)(b * Hc + hh);
      const int dr = tid >> 2, qd = tid & 3;       // 64 rows x 4 quarters
      half_t* gbase = dstT + (bh * 64 + dr) * L + tb + qd * 32;
#pragma unroll
      for (int j = 0; j < 4; ++j) {
        const half8 v8 = *reinterpret_cast<const half8*>(&Txp[dr * 136 + qd * 32 + j * 8]);
        *reinterpret_cast<half8*>(&gbase[j * 8]) = v8;
      }
    }
  }
}

// --------------------------------------------- fused WT+Q2 kernel
// grid (16 t-chunks, 16 z). Phase 1: WT[64][64] = 0.125 * QYTs[z] KYT[z]^T
// (K=1024, pipelined dbuf) -> LDS in phase-2 fragment layout. Phase 2:
// Q2[z, t0..t0+127, :] = QXs * WT^T (K=64, single tile, A staged async).
__global__ __launch_bounds__(256) void wtq2(
    const half_t* __restrict__ QYT, const half_t* __restrict__ KYT,
    const half_t* __restrict__ QX, half_t* __restrict__ Q2)
{
  __shared__ __align__(16) half_t As[2][4096];
  __shared__ __align__(16) half_t Bs[2][4096];
  __shared__ __align__(16) half_t WTs[4096];
  const int tid = threadIdx.x, lane = tid & 63, wave = tid >> 6;
  const int wm = wave >> 1, wn = wave & 1;
  const int r16 = lane & 15, g = lane >> 4;
  const int z = blockIdx.y;
  const int t0 = blockIdx.x * 128;
  const half_t* Aq = QYT + (long)z * Dc * Mc;
  const half_t* Bk = KYT + (long)z * Dc * Mc;

  auto stage1 = [&](int kt, int buf) {
#pragma unroll
    for (int i = 0; i < 2; ++i) {
      const int c = tid + i * 256;
      const int row = c >> 3, js = c & 7, jg = js ^ (row & 7);
      gld_lds16(Aq + (long)row * Mc + kt + jg * 8, &As[buf][c * 8]);
    }
#pragma unroll
    for (int i = 0; i < 2; ++i) {
      const int c = tid + i * 256;
      const int row = c >> 3, js = c & 7, jg = js ^ (row & 7);
      gld_lds16(Bk + (long)row * Mc + kt + jg * 8, &Bs[buf][c * 8]);
    }
  };

  floatx4 acc[2][2];
#pragma unroll
  for (int mi = 0; mi < 2; ++mi)
#pragma unroll
    for (int ni = 0; ni < 2; ++ni) acc[mi][ni] = floatx4{0.f, 0.f, 0.f, 0.f};

  const int rA = wm * 32 + r16, rB = wn * 32 + r16;
  stage1(0, 0);
  asm volatile("" ::: "memory");
  for (int it = 0; it < 16; ++it) {
    const bool hn = (it < 15);
    if (hn) stage1((it + 1) * 64, (it + 1) & 1);
    asm volatile("" ::: "memory");
    if (hn) asm volatile("s_waitcnt vmcnt(4)" ::: "memory");
    else    asm volatile("s_waitcnt vmcnt(0)" ::: "memory");
    __builtin_amdgcn_s_barrier();
    asm volatile("" ::: "memory");
    const half_t* Ab = As[it & 1];
    const half_t* Bb = Bs[it & 1];
    half8 aF[2][2], bF[2][2];
#pragma unroll
    for (int mi = 0; mi < 2; ++mi)
#pragma unroll
      for (int k2 = 0; k2 < 2; ++k2)
        aF[mi][k2] = *reinterpret_cast<const half8*>(
            &Ab[(rA + mi * 16) * 64 + ((k2 * 4 + g) ^ (r16 & 7)) * 8]);
#pragma unroll
    for (int ni = 0; ni < 2; ++ni)
#pragma unroll
      for (int k2 = 0; k2 < 2; ++k2)
        bF[ni][k2] = *reinterpret_cast<const half8*>(
            &Bb[(rB + ni * 16) * 64 + ((k2 * 4 + g) ^ (r16 & 7)) * 8]);
    __builtin_amdgcn_s_setprio(1);
#pragma unroll
    for (int k2 = 0; k2 < 2; ++k2)
#pragma unroll
      for (int mi = 0; mi < 2; ++mi)
#pragma unroll
        for (int ni = 0; ni < 2; ++ni)
          acc[mi][ni] = __builtin_amdgcn_mfma_f32_16x16x32_f16(
              aF[mi][k2], bF[ni][k2], acc[mi][ni], 0, 0, 0);
    __builtin_amdgcn_s_setprio(0);
    asm volatile("s_waitcnt lgkmcnt(0)" ::: "memory");
    __builtin_amdgcn_s_barrier();
    asm volatile("" ::: "memory");
  }

  // phase-2 A stage (As fully free after final barrier): QX rows t0..t0+127
  half_t* P2 = &As[0][0];
#pragma unroll
  for (int i = 0; i < 4; ++i) {
    const int c = tid + i * 256;
    const int row = c >> 3, js = c & 7, jg = js ^ (row & 7);
    gld_lds16(QX + ((long)z * Tc + t0 + row) * 64 + jg * 8, P2 + c * 8);
  }
  // WT -> LDS f16 in phase-2 fragment layout (chunk swizzle js^(row&7))
#pragma unroll
  for (int mi = 0; mi < 2; ++mi)
#pragma unroll
    for (int ni = 0; ni < 2; ++ni)
#pragma unroll
      for (int reg = 0; reg < 4; ++reg) {
        const int r = wm * 32 + mi * 16 + g * 4 + reg;   // d2
        const int c = wn * 32 + ni * 16 + r16;           // d1
        WTs[r * 64 + (((c >> 3) ^ (r & 7)) << 3) + (c & 7)] =
            (half_t)(acc[mi][ni][reg] * 0.125f);
      }
  __syncthreads();   // drains vmcnt (QX stage) + lgkm (WTs writes)

  // phase 2: per wave 32 t-rows, full 64 d2 cols, K=64
  floatx4 a2[2][4];
#pragma unroll
  for (int mi = 0; mi < 2; ++mi)
#pragma unroll
    for (int ni = 0; ni < 4; ++ni) a2[mi][ni] = floatx4{0.f, 0.f, 0.f, 0.f};
  const int rA2 = wave * 32 + r16;
  half8 aF2[2][2], bF2[4][2];
#pragma unroll
  for (int mi = 0; mi < 2; ++mi)
#pragma unroll
    for (int k2 = 0; k2 < 2; ++k2)
      aF2[mi][k2] = *reinterpret_cast<const half8*>(
          &P2[(rA2 + mi * 16) * 64 + ((k2 * 4 + g) ^ (r16 & 7)) * 8]);
#pragma unroll
  for (int ni = 0; ni < 4; ++ni)
#pragma unroll
    for (int k2 = 0; k2 < 2; ++k2)
      bF2[ni][k2] = *reinterpret_cast<const half8*>(
          &WTs[(ni * 16 + r16) * 64 + ((k2 * 4 + g) ^ (r16 & 7)) * 8]);
#pragma unroll
  for (int k2 = 0; k2 < 2; ++k2)
#pragma unroll
    for (int mi = 0; mi < 2; ++mi)
#pragma unroll
      for (int ni = 0; ni < 4; ++ni)
        a2[mi][ni] = __builtin_amdgcn_mfma_f32_16x16x32_f16(
            aF2[mi][k2], bF2[ni][k2], a2[mi][ni], 0, 0, 0);
#pragma unroll
  for (int mi = 0; mi < 2; ++mi)
#pragma unroll
    for (int ni = 0; ni < 4; ++ni)
#pragma unroll
      for (int reg = 0; reg < 4; ++reg) {
        const int t = t0 + wave * 32 + mi * 16 + g * 4 + reg;
        const int c = ni * 16 + r16;
        Q2[((long)z * Tc + t) * 64 + c] = (half_t)a2[mi][ni][reg];
      }
}

// ------------------------------------------------------------ flash staging
__device__ __forceinline__ void stageK128(const half_t* Kz, int s0, half_t* dst, int tid) {
#pragma unroll
  for (int i = 0; i < 4; ++i) {
    const int c = tid + i * 256;
    const int row = c >> 3, js = c & 7;
    const int jg = js ^ (row & 7);
    gld_lds16(Kz + (long)(s0 + row) * 64 + jg * 8, dst + c * 8);
  }
}
__device__ __forceinline__ void stageV128(const half_t* Vz, int s0, int Slen, half_t* dst, int tid) {
#pragma unroll
  for (int i = 0; i < 4; ++i) {
    const int c = tid + i * 256;
    const int row = c >> 4, js = c & 15;
    const int jg = js ^ (row & 15);
    gld_lds16(Vz + (long)row * Slen + s0 + jg * 8, dst + c * 8);
  }
}

// --------------------------------------------------------- flash body (MI=2)
// R19 schedule (unchanged): vmcnt(4)+barrier [K(t) ready] ; QK MFMA cluster ;
// issue K(t+1) ; softmax (mask+exp2) ; vmcnt(4)+barrier [V(t) ready] ; PV
// (+ones-MFMA row-sum) ; barrier ; issue V(t+1).
// PARTIAL: unnormalized O -> f16 POh + row-sum -> Lp. else normalized f16.
template <bool MASKED, bool PARTIAL>
__device__ __forceinline__ void flash_body(
    const half_t* __restrict__ Qp, const half_t* __restrict__ Kp,
    const half_t* __restrict__ Vp, const unsigned char* __restrict__ mpk,
    half_t* __restrict__ POh, float* __restrict__ Lp, half_t* __restrict__ outF,
    int Slen, int sbeg, int scount, int z, int q0,
    half_t* Kb0, half_t* Kb1, half_t* Vb)
{
  const int tid = threadIdx.x, lane = tid & 63, w = tid >> 6;
  const int r16 = lane & 15, g = lane >> 4;
  const int b = z >> 3, h = z & 7;
  const int NT = Slen >> 7;
  const half_t* Qz = Qp + ((long)z * Tc + q0) * 64;
  const half_t* Kz = Kp + (long)z * Slen * 64;
  const half_t* Vz = Vp + (long)z * 64 * Slen;

  // prologue staging: K(0), V(0) (oldest 8 vmem ops, in this order)
  stageK128(Kz, sbeg, Kb0, tid);
  asm volatile("" ::: "memory");
  stageV128(Vz, sbeg, Slen, Vb, tid);
  asm volatile("" ::: "memory");

  half8 aQ[2][2];
#pragma unroll
  for (int mi = 0; mi < 2; ++mi)
#pragma unroll
    for (int k2 = 0; k2 < 2; ++k2)
      aQ[mi][k2] = *reinterpret_cast<const half8*>(
          Qz + (w * 32 + mi * 16 + r16) * 64 + k2 * 32 + g * 8);

  half8 vones;
#pragma unroll
  for (int j = 0; j < 8; ++j) vones[j] = (half_t)1.f;

  floatx4 oaccT[2][4];
  floatx4 lacc4[2];
#pragma unroll
  for (int mi = 0; mi < 2; ++mi) {
    lacc4[mi] = floatx4{0.f, 0.f, 0.f, 0.f};
#pragma unroll
    for (int no = 0; no < 4; ++no) oaccT[mi][no] = floatx4{0.f, 0.f, 0.f, 0.f};
  }

  const int send = sbeg + scount;
  int cur = 0;
  for (int s0 = sbeg; s0 < send; s0 += 128) {
    const bool hn = (s0 + 128 < send);
    // K(t) ready (V(t) may still fly; K is the oldest outstanding group)
    asm volatile("s_waitcnt vmcnt(4)" ::: "memory");
    __builtin_amdgcn_s_barrier();
    asm volatile("" ::: "memory");

    unsigned int mb32[2];
    if constexpr (MASKED) {
      const int tile = s0 >> 7;
#pragma unroll
      for (int mi = 0; mi < 2; ++mi) {
        const int q = q0 + w * 32 + mi * 16 + r16;
        mb32[mi] = *reinterpret_cast<const unsigned int*>(
            mpk + ((long)q * NT + tile) * 16 + 4 * g);
      }
    }

    // S^T = K Q^T : 16 b128 reads feed 32 MFMAs
    floatx4 sacc[2][8];
#pragma unroll
    for (int mi = 0; mi < 2; ++mi)
#pragma unroll
      for (int ni = 0; ni < 8; ++ni) sacc[mi][ni] = floatx4{0.f, 0.f, 0.f, 0.f};
    const half_t* Kc = cur ? Kb1 : Kb0;
    __builtin_amdgcn_s_setprio(1);
#pragma unroll
    for (int ni = 0; ni < 8; ++ni) {
      const int rB = ni * 16 + r16;
      const half8 b0 = *reinterpret_cast<const half8*>(&Kc[rB * 64 + (g ^ (rB & 7)) * 8]);
      const half8 b1 = *reinterpret_cast<const half8*>(&Kc[rB * 64 + ((4 + g) ^ (rB & 7)) * 8]);
#pragma unroll
      for (int mi = 0; mi < 2; ++mi) {
        sacc[mi][ni] = __builtin_amdgcn_mfma_f32_16x16x32_f16(b0, aQ[mi][0], sacc[mi][ni], 0, 0, 0);
        sacc[mi][ni] = __builtin_amdgcn_mfma_f32_16x16x32_f16(b1, aQ[mi][1], sacc[mi][ni], 0, 0, 0);
      }
    }
    __builtin_amdgcn_s_setprio(0);
    // prefetch K(t+1) into the other buffer; lands under softmax+PV
    if (hn) stageK128(Kz, s0 + 128, cur ? Kb0 : Kb1, tid);
    asm volatile("" ::: "memory");

    // in-register softmax (separated phase): mask + exp2 only; row-sum
    // rides the PV ones-MFMA.
#pragma unroll
    for (int mi = 0; mi < 2; ++mi) {
      if constexpr (MASKED) {
        if (mb32[mi] != 0xffffffffu) {
#pragma unroll
          for (int reg = 0; reg < 4; ++reg)
#pragma unroll
            for (int ni = 0; ni < 8; ++ni)
              if (!((mb32[mi] >> (reg * 8 + ni)) & 1)) sacc[mi][ni][reg] = -__builtin_inff();
        }
      }
#pragma unroll
      for (int ni = 0; ni < 8; ++ni)
#pragma unroll
        for (int reg = 0; reg < 4; ++reg)
          sacc[mi][ni][reg] = __builtin_amdgcn_exp2f(sacc[mi][ni][reg]);
    }

    // V(t) ready (K(t+1) = newest 4 still in flight when hn)
    if (hn) { asm volatile("s_waitcnt vmcnt(4)" ::: "memory"); }
    else    { asm volatile("s_waitcnt vmcnt(0)" ::: "memory"); }
    __builtin_amdgcn_s_barrier();
    asm volatile("" ::: "memory");

    // O^T += V^T P^T ; l += ones·P^T (row-sum via matrix pipe)
#pragma unroll
    for (int c = 0; c < 4; ++c) {
      half8 bVv[4];
#pragma unroll
      for (int no = 0; no < 4; ++no) {
        const int rV = no * 16 + r16;
        bVv[no] = *reinterpret_cast<const half8*>(
            &Vb[rV * 128 + ((c * 4 + g) ^ (rV & 15)) * 8]);
      }
#pragma unroll
      for (int mi = 0; mi < 2; ++mi) {
        // butterfly P^T frag: target word p_t at lane g <-
        // pk[2c+(g>>1)][p_t&1] of lane 2(g&1)+(p_t>>1)
        int x0 = pkrtz(sacc[mi][2 * c][0],     sacc[mi][2 * c][1]);
        int x1 = pkrtz(sacc[mi][2 * c][2],     sacc[mi][2 * c][3]);
        int x2 = pkrtz(sacc[mi][2 * c + 1][0], sacc[mi][2 * c + 1][1]);
        int x3 = pkrtz(sacc[mi][2 * c + 1][2], sacc[mi][2 * c + 1][3]);
        pl32(x0, x2); pl32(x1, x3);   // resolve g1 <-> ni bit
        pl16(x0, x2); pl16(x1, x3);   // resolve g0 <-> word bit
        int4v wv; wv[0] = x0; wv[1] = x1; wv[2] = x2; wv[3] = x3;
        const half8 aP = __builtin_bit_cast(half8, wv);
        __builtin_amdgcn_s_setprio(1);
#pragma unroll
        for (int no = 0; no < 4; ++no)
          oaccT[mi][no] = __builtin_amdgcn_mfma_f32_16x16x32_f16(bVv[no], aP, oaccT[mi][no], 0, 0, 0);
        lacc4[mi] = __builtin_amdgcn_mfma_f32_16x16x32_f16(vones, aP, lacc4[mi], 0, 0, 0);
        __builtin_amdgcn_s_setprio(0);
      }
    }
    __builtin_amdgcn_s_barrier();
    asm volatile("" ::: "memory");
    // prefetch V(t+1); lands under next tile's QK^T + softmax
    if (hn) stageV128(Vz, s0 + 128, Slen, Vb, tid);
    asm volatile("" ::: "memory");
    cur ^= 1;
  }

  // epilogue: l_q sits in every lane's lacc4[mi][0] (col=lane&15=q).
  float ls2[2];
#pragma unroll
  for (int mi = 0; mi < 2; ++mi) ls2[mi] = lacc4[mi][0];

  float* slab = reinterpret_cast<float*>(Vb) + w * 1024;
#pragma unroll
  for (int mi = 0; mi < 2; ++mi) {
    const int tq = q0 + w * 32 + mi * 16;
    if constexpr (PARTIAL) {
      if (lane < 16) Lp[(long)z * Tc + tq + r16] = ls2[mi];
    }
    const float sc = PARTIAL ? 1.f : (1.f / ls2[mi]);
#pragma unroll
    for (int no = 0; no < 4; ++no) {
      floatx4 v = oaccT[mi][no];
      if constexpr (!PARTIAL) v *= sc;
      *reinterpret_cast<floatx4*>(&slab[r16 * 64 + no * 16 + (g ^ (r16 & 3)) * 4]) = v;
    }
#pragma unroll
    for (int it = 0; it < 4; ++it) {
      const int q2 = it * 4 + g;
      const int d4 = r16;
      const floatx4 v = *reinterpret_cast<const floatx4*>(
          &slab[q2 * 64 + (d4 >> 2) * 16 + ((d4 & 3) ^ (q2 & 3)) * 4]);
      const long off = ((long)(b * Tc + tq + q2)) * Cc + h * 64 + d4 * 4;
      half4v hh; hh[0] = (half_t)v[0]; hh[1] = (half_t)v[1];
      hh[2] = (half_t)v[2]; hh[3] = (half_t)v[3];
      if constexpr (PARTIAL) {
        *reinterpret_cast<half4v*>(&POh[off]) = hh;   // unnormalized f16
      } else {
        *reinterpret_cast<half4v*>(&outF[off]) = hh;
      }
    }
  }
}

// 768 blocks, each exactly 8 s-tiles (= 3 blocks/CU, one balanced round):
//  bx < 512:  att0 (chained, masked), s-half sh=(bx>>4)&1, unnormalized f16+L
//  bx >= 512: att1 (first), full s-range, normalized f16 -> DH2
__global__ __launch_bounds__(256, 3) void flash_both(
    const half_t* __restrict__ Q2, const half_t* __restrict__ KX,
    const half_t* __restrict__ VXT, const unsigned char* __restrict__ mpk,
    const half_t* __restrict__ QX, const half_t* __restrict__ KY,
    const half_t* __restrict__ VYT,
    half_t* __restrict__ POh, float* __restrict__ Lp, half_t* __restrict__ DH2)
{
  __shared__ __align__(16) half_t Kb0[8192];
  __shared__ __align__(16) half_t Kb1[8192];
  __shared__ __align__(16) half_t Vb[8192];
  const int bx = blockIdx.x;
  if (bx < 512) {
    const int z  = ((bx & 7) << 1) | ((bx >> 3) & 1);   // z-local per XCD
    const int sh = (bx >> 4) & 1;
    const int q0 = (bx >> 5) * 128;
    flash_body<true, true>(Q2, KX, VXT, mpk,
                           POh + (long)sh * BTC, Lp + (long)sh * ZT, nullptr,
                           Tc, sh * 1024, 1024, z, q0, Kb0, Kb1, Vb);
  } else {
    const int b2 = bx - 512;
    const int z  = ((b2 & 7) << 1) | ((b2 >> 3) & 1);
    const int q0 = (b2 >> 4) * 128;
    flash_body<false, false>(QX, KY, VYT, nullptr,
                             nullptr, nullptr, DH2,
                             Mc, 0, Mc, z, q0, Kb0, Kb1, Vb);
  }
}

// --------------------------- combine att0 s-halves + diff with DH2 -> DH
__global__ __launch_bounds__(256) void combine_k(
    const half_t* __restrict__ POh, const float* __restrict__ Lp,
    const half_t* __restrict__ DH2, half_t* __restrict__ DH)
{
  const long idx = (long)blockIdx.x * 256 + threadIdx.x;   // over BTC/4
  const long c4 = idx * 4;
  const int c = (int)(c4 & (Cc - 1));
  const long bt = c4 >> 9;
  const int h = c >> 6;
  const int b = (int)(bt >> 11), t = (int)(bt & (Tc - 1));
  const long zt = (long)(b * Hc + h) * Tc + t;
  const float ainv = 1.f / (Lp[zt] + Lp[ZT + zt]);
  const half4v oa0 = reinterpret_cast<const half4v*>(POh)[idx];
  const half4v oa1 = reinterpret_cast<const half4v*>(POh)[BTC / 4 + idx];
  const half4v dv = reinterpret_cast<const half4v*>(DH2)[idx];
  half4v r;
  r[0] = (half_t)((float)dv[0] - ((float)oa0[0] + (float)oa1[0]) * ainv);
  r[1] = (half_t)((float)dv[1] - ((float)oa0[1] + (float)oa1[1]) * ainv);
  r[2] = (half_t)((float)dv[2] - ((float)oa0[2] + (float)oa1[2]) * ainv);
  r[3] = (half_t)((float)dv[3] - ((float)oa0[3] + (float)oa1[3]) * ainv);
  reinterpret_cast<half4v*>(DH)[idx] = r;
}

// ----------------------------------------------- prep: converts + mask pack
__device__ __forceinline__ void cvt4(const float* in, half_t* out, long i) {
  const float4 f = reinterpret_cast<const float4*>(in)[i];
  half4v h; h[0] = (half_t)f.x; h[1] = (half_t)f.y; h[2] = (half_t)f.z; h[3] = (half_t)f.w;
  reinterpret_cast<half4v*>(out)[i] = h;
}

__global__ __launch_bounds__(256) void prep(
    const float* __restrict__ x, const float* __restrict__ y,
    const float* __restrict__ qw, const float* __restrict__ pw,
    const int* __restrict__ mask,
    half_t* __restrict__ XH, half_t* __restrict__ YH,
    half_t* __restrict__ WQ, half_t* __restrict__ WP,
    unsigned char* __restrict__ mpk)
{
  const long i = (long)blockIdx.x * 256 + threadIdx.x;
  constexpr long n0 = 524288;            // x/4
  constexpr long n1 = n0 + 262144;       // y/4
  constexpr long n2 = n1 + 196608;       // qkv_w/4
  constexpr long n3 = n2 + 65536;        // proj_w/4
  if (i < n0) cvt4(x, XH, i);
  else if (i < n1) cvt4(y, YH, i - n0);
  else if (i < n2) cvt4(qw, WQ, i - n1);
  else if (i < n3) cvt4(pw, WP, i - n2);
  else {
    const long idx = i - n3;             // [0, Tc*256)
    const int t = (int)(idx >> 8), tile = (int)((idx >> 4) & 15), r16 = (int)(idx & 15);
    const int* row = mask + (long)t * Tc + tile * 128 + r16;
    unsigned int bbits = 0;
#pragma unroll
    for (int ni = 0; ni < 8; ++ni)
      bbits |= (row[ni * 16] != 0 ? 1u : 0u) << ni;
    mpk[idx] = (unsigned char)bbits;
  }
}

// ------------------------------------------------------------- workspace map
constexpr size_t OFF_XH   = 0;                                   // [B*T,C] f16 (YH must follow!)
constexpr size_t OFF_YH   = OFF_XH   + (size_t)Bc*Tc*Cc*2;       // contiguous rows after XH
constexpr size_t OFF_WQ   = OFF_YH   + (size_t)Bc*Mc*Cc*2;
constexpr size_t OFF_WP   = OFF_WQ   + (size_t)3*Cc*Cc*2;
constexpr size_t OFF_QX   = OFF_WP   + (size_t)Cc*Cc*2;          // [z,T,D] *0.125*log2e
constexpr size_t OFF_KX   = OFF_QX   + (size_t)Bc*Hc*Tc*Dc*2;    // [z,T,D]
constexpr size_t OFF_VXT  = OFF_KX   + (size_t)Bc*Hc*Tc*Dc*2;    // [z,D,T]
constexpr size_t OFF_QYT  = OFF_VXT  + (size_t)Bc*Hc*Tc*Dc*2;    // [z,D,M] *0.125
constexpr size_t OFF_KY   = OFF_QYT  + (size_t)Bc*Hc*Mc*Dc*2;    // [z,M,D]
constexpr size_t OFF_KYT  = OFF_KY   + (size_t)Bc*Hc*Mc*Dc*2;    // [z,D,M]
constexpr size_t OFF_VYT  = OFF_KYT  + (size_t)Bc*Hc*Mc*Dc*2;    // [z,D,M]
constexpr size_t OFF_Q2   = OFF_VYT  + (size_t)Bc*Hc*Mc*Dc*2;    // [z,T,D]
constexpr size_t OFF_DH   = OFF_Q2   + (size_t)Bc*Hc*Tc*Dc*2;    // [B,T,C] diff f16
constexpr size_t OFF_DH2  = OFF_DH   + (size_t)Bc*Tc*Cc*2;       // [B,T,C] cval_x2y f16
constexpr size_t OFF_MPK  = OFF_DH2  + (size_t)Bc*Tc*Cc*2;       // [T,16,16] u8
constexpr size_t OFF_PO   = OFF_MPK  + (size_t)Tc*256;           // [2][B,T,C] f16 unnormalized
constexpr size_t OFF_L    = OFF_PO   + (size_t)2*BTC*2;          // [2][ZT] f32 row sums
// total ~47 MB

extern "C" void kernel_launch(void* const* d_in, const int* in_sizes, int n_in,
                              void* d_out, int out_size, void* d_ws, size_t ws_size,
                              hipStream_t stream) {
  const float* x      = (const float*)d_in[0];
  const float* y      = (const float*)d_in[1];
  const int*   mask   = (const int*)  d_in[2];
  const float* qkv_b  = (const float*)d_in[4];
  const float* proj_b = (const float*)d_in[6];
  float* out = (float*)d_out;
  char* ws = (char*)d_ws;

  half_t* XH   = (half_t*)(ws + OFF_XH);
  half_t* YH   = (half_t*)(ws + OFF_YH);
  half_t* WQ   = (half_t*)(ws + OFF_WQ);
  half_t* WP   = (half_t*)(ws + OFF_WP);
  half_t* QX   = (half_t*)(ws + OFF_QX);
  half_t* KX   = (half_t*)(ws + OFF_KX);
  half_t* VXT  = (half_t*)(ws + OFF_VXT);
  half_t* QYT  = (half_t*)(ws + OFF_QYT);
  half_t* KY   = (half_t*)(ws + OFF_KY);
  half_t* KYT  = (half_t*)(ws + OFF_KYT);
  half_t* VYT  = (half_t*)(ws + OFF_VYT);
  half_t* Q2   = (half_t*)(ws + OFF_Q2);
  half_t* DH   = (half_t*)(ws + OFF_DH);
  half_t* DH2  = (half_t*)(ws + OFF_DH2);
  unsigned char* MPK = (unsigned char*)(ws + OFF_MPK);
  half_t* POh  = (half_t*)(ws + OFF_PO);
  float*  Lp   = (float*) (ws + OFF_L);

  // converts + mask packing (one launch)
  prep<<<6144, 256, 0, stream>>>(x, y, (const float*)d_in[3], (const float*)d_in[5],
                                 mask, XH, YH, WQ, WP, MPK);

  // fused qkv projection for x and y (XH||YH contiguous: 6144 rows)
  {
    EpiParams ep{};
    ep.h0 = QX; ep.h1 = KX; ep.h2 = VXT; ep.h3 = QYT;
    ep.h4 = KY; ep.h5 = KYT; ep.h6 = VYT; ep.bias = qkv_b;
    gemm_nt<128,64,2,2,EPI_QKV_XY><<<dim3(24, 48, 1), 256, 0, stream>>>(
        XH, WQ, Cc, Cc, Cc, 0, 0, ep);
  }

  // fused WT+Q2: 16 t-chunks x 16 z = 256 blocks
  wtq2<<<dim3(16, 16), 256, 0, stream>>>(QYT, KYT, QX, Q2);

  // balanced flash: 512 att0-half blocks + 256 att1 blocks = 768 (3/CU)
  flash_both<<<dim3(768), 256, 0, stream>>>(
      Q2, KX, VXT, MPK, QX, KY, VYT, POh, Lp, DH2);

  // combine att0 halves + diff with DH2 -> DH
  combine_k<<<(int)(BTC/4/256), 256, 0, stream>>>(POh, Lp, DH2, DH);

  // out = DH @ proj_w^T + proj_b
  {
    EpiParams ep{}; ep.f0 = out; ep.bias = proj_b;
    gemm_nt<64,64,2,2,EPI_PROJ><<<dim3(8, 64, 1), 256, 0, stream>>>(
        DH, WP, Cc, Cc, Cc, 0, 0, ep);
  }
}

// Round 9
// 173.533 us; speedup vs baseline: 1.1199x; 1.0055x over previous
//
#include <hip/hip_runtime.h>

// CrossAttentionPro on MI355X — Round 21:
//  XCD L2-locality swizzle (guide T1, bijective chunked remap) on the three
//  GEMM-ish kernels:
//   - qkv (grid 24x48): the 24 blocks sharing one 128KB A-panel previously
//     round-robined over all 8 XCDs (panel fetched 8x). Remap gives each
//     XCD 6 contiguous panels -> panel fetched once into its L2.
//   - wtq2 (16x16): 16 t-chunk blocks sharing each z's QYT/KYT panels now
//     co-locate (2 z per XCD).
//   - proj (8x64): 8 blocks per A-panel co-locate.
//  Pure scheduling change — numerics bit-identical to R20.
//  Kept from R20: coalesced qkv transposed-output stores via LDS slab,
//  f16 PO, R19 flash (ones-MFMA row-sum, swapped-operand S^T=mfma(K,Q),
//  no-max exp2 softmax, pkrtz+permlane butterfly, K dbuf counted vmcnt,
//  48KB/3blk/CU, 768-block balanced grid), wtq2 fusion, bit-packed mask.

typedef _Float16 half_t;
typedef _Float16 half8 __attribute__((ext_vector_type(8)));
typedef _Float16 half4v __attribute__((ext_vector_type(4)));
typedef float floatx4 __attribute__((ext_vector_type(4)));
typedef int int4v __attribute__((ext_vector_type(4)));

constexpr int Bc = 2, Tc = 2048, Mc = 1024, Cc = 512, Hc = 8, Dc = 64;
constexpr long BTC = (long)Bc * Tc * Cc;
constexpr long ZT  = (long)Bc * Hc * Tc;
constexpr float S1 = 0.18033688f;                 // 0.125 * log2(e)

enum { EPI_F16STORE = 0, EPI_QKV_XY = 1, EPI_PROJ = 2 };

struct EpiParams {
  half_t* h0;        // QXs  / f16 dest
  half_t* h1;        // KX
  half_t* h2;        // VXT
  half_t* h3;        // QYT
  half_t* h4;        // KY
  half_t* h5;        // KYT
  half_t* h6;        // VYT
  float* f0;
  const float* bias;
  float scale;
  int ldc;
  long bstride;
};

// async global->LDS, 16B per lane; dst must be wave-uniform base + lane*16.
__device__ __forceinline__ void gld_lds16(const half_t* g, half_t* l) {
  __builtin_amdgcn_global_load_lds(
      (const __attribute__((address_space(1))) void*)g,
      (__attribute__((address_space(3))) void*)l, 16, 0, 0);
}

// pack 2 f32 -> 2 f16 (RTZ) as one u32
__device__ __forceinline__ int pkrtz(float a, float b) {
  return __builtin_bit_cast(int, __builtin_amdgcn_cvt_pkrtz(a, b));
}
// v_permlane16_swap: a.row1<->b.row0, a.row3<->b.row2 (rows = 16-lane groups)
__device__ __forceinline__ void pl16(int& a, int& b) {
  asm volatile("v_permlane16_swap_b32 %0, %1" : "+v"(a), "+v"(b));
}
// v_permlane32_swap: a.rows{2,3} <-> b.rows{0,1}
__device__ __forceinline__ void pl32(int& a, int& b) {
  asm volatile("v_permlane32_swap_b32 %0, %1" : "+v"(a), "+v"(b));
}

// ---------------------------------------------------------------- GEMM (NT)
// C[r,c] = sum_k A[r,k]*Bt[c,k]. BK=64 double-buffered async staging with
// counted vmcnt, swizzled chunks (conflict-free ds_read_b128).
// GX/GY: logical grid dims for XCD-chunked remap (0 = no remap). Blocks
// sharing an A-panel (same logical y) co-locate on one XCD's L2.
template <int BM, int BN, int WMG, int WNG, int EPI, int GX = 0, int GY = 0>
__global__ __launch_bounds__(256) void gemm_nt(
    const half_t* __restrict__ A, const half_t* __restrict__ Bt,
    int K, int lda, int ldb, long bsA, long bsB, EpiParams ep)
{
  constexpr int BK = 64;
  constexpr int WTM = BM / WMG, WTN = BN / WNG;
  constexpr int MI = WTM / 16, NI = WTN / 16;
  constexpr int AIT = BM * BK / 8 / 256;
  constexpr int BIT = BN * BK / 8 / 256;
  constexpr int NLD = AIT + BIT;
  __shared__ __align__(16) half_t As[2][BM * BK];
  __shared__ __align__(16) half_t Bs[2][BN * BK];

  const int tid = threadIdx.x;
  const int lane = tid & 63;
  const int wave = tid >> 6;
  const int wm = wave / WNG, wn = wave % WNG;
  const int r16 = lane & 15, g = lane >> 4;
  const int z = blockIdx.z;

  int bxl = blockIdx.x, byl = blockIdx.y;
  if constexpr (GX > 0) {
    // bijective chunked remap: XCD (f&7) owns chunk of contiguous logicals
    constexpr int CHUNK = GX * GY / 8;   // GX*GY % 8 == 0 required
    const int f = byl * GX + bxl;
    const int L = (f & 7) * CHUNK + (f >> 3);
    bxl = L % GX; byl = L / GX;
  }
  const long m0 = (long)byl * BM;
  const long n0 = (long)bxl * BN;
  const half_t* Abase = A + (long)z * bsA + m0 * (long)lda;
  const half_t* Bbase = Bt + (long)z * bsB + n0 * (long)ldb;

  const int rA = wm * WTM + r16;
  const int rB = wn * WTN + r16;

  floatx4 acc[MI][NI];
#pragma unroll
  for (int mi = 0; mi < MI; ++mi)
#pragma unroll
    for (int ni = 0; ni < NI; ++ni)
      acc[mi][ni] = floatx4{0.f, 0.f, 0.f, 0.f};

  auto stage = [&](int kt, int buf) {
#pragma unroll
    for (int i = 0; i < AIT; ++i) {
      const int c = tid + i * 256;
      const int row = c >> 3, js = c & 7;
      const int jg = js ^ (row & 7);
      gld_lds16(Abase + (long)row * lda + kt + jg * 8, &As[buf][c * 8]);
    }
#pragma unroll
    for (int i = 0; i < BIT; ++i) {
      const int c = tid + i * 256;
      const int row = c >> 3, js = c & 7;
      const int jg = js ^ (row & 7);
      gld_lds16(Bbase + (long)row * ldb + kt + jg * 8, &Bs[buf][c * 8]);
    }
  };

  const int NIT = K / BK;
  stage(0, 0);
  asm volatile("" ::: "memory");

  for (int it = 0; it < NIT; ++it) {
    const bool hn = (it + 1 < NIT);
    if (hn) stage((it + 1) * BK, (it + 1) & 1);
    asm volatile("" ::: "memory");
    if (hn) {
      if constexpr (NLD == 6) asm volatile("s_waitcnt vmcnt(6)" ::: "memory");
      else if constexpr (NLD == 4) asm volatile("s_waitcnt vmcnt(4)" ::: "memory");
      else if constexpr (NLD == 8) asm volatile("s_waitcnt vmcnt(8)" ::: "memory");
      else asm volatile("s_waitcnt vmcnt(0)" ::: "memory");
    } else {
      asm volatile("s_waitcnt vmcnt(0)" ::: "memory");
    }
    __builtin_amdgcn_s_barrier();
    asm volatile("" ::: "memory");

    const half_t* Ab = As[it & 1];
    const half_t* Bb = Bs[it & 1];
    half8 aF[MI][2], bF[NI][2];
#pragma unroll
    for (int mi = 0; mi < MI; ++mi)
#pragma unroll
      for (int k2 = 0; k2 < 2; ++k2)
        aF[mi][k2] = *reinterpret_cast<const half8*>(
            &Ab[(rA + mi * 16) * BK + ((k2 * 4 + g) ^ (r16 & 7)) * 8]);
#pragma unroll
    for (int ni = 0; ni < NI; ++ni)
#pragma unroll
      for (int k2 = 0; k2 < 2; ++k2)
        bF[ni][k2] = *reinterpret_cast<const half8*>(
            &Bb[(rB + ni * 16) * BK + ((k2 * 4 + g) ^ (r16 & 7)) * 8]);
    __builtin_amdgcn_s_setprio(1);
#pragma unroll
    for (int k2 = 0; k2 < 2; ++k2)
#pragma unroll
      for (int mi = 0; mi < MI; ++mi)
#pragma unroll
        for (int ni = 0; ni < NI; ++ni)
          acc[mi][ni] = __builtin_amdgcn_mfma_f32_16x16x32_f16(
              aF[mi][k2], bF[ni][k2], acc[mi][ni], 0, 0, 0);
    __builtin_amdgcn_s_setprio(0);
    asm volatile("s_waitcnt lgkmcnt(0)" ::: "memory");
    __builtin_amdgcn_s_barrier();
    asm volatile("" ::: "memory");
  }

  // epilogue: C/D layout col=lane&15, row=(lane>>4)*4+reg  [m89-verified]
  // transposed-output slab (reuses As, free after last barrier): [64][136]
  half_t* Txp = &As[0][0];
  const bool isx  = (m0 < (long)Bc * Tc);
  const int which = (int)(n0 >> 9);
  const int hh    = ((int)n0 & 511) >> 6;

#pragma unroll
  for (int mi = 0; mi < MI; ++mi) {
#pragma unroll
    for (int ni = 0; ni < NI; ++ni) {
#pragma unroll
      for (int reg = 0; reg < 4; ++reg) {
        const int r = (int)m0 + wm * WTM + mi * 16 + g * 4 + reg;
        const int c = (int)n0 + wn * WTN + ni * 16 + r16;
        const float v = acc[mi][ni][reg];
        if constexpr (EPI == EPI_F16STORE) {
          ep.h0[(long)z * ep.bstride + (long)r * ep.ldc + c] = (half_t)(v * ep.scale);
        } else if constexpr (EPI == EPI_QKV_XY) {
          const float val = v + ep.bias[c];
          const int d = c & 63;
          const int rloc = r - (int)m0;
          if (isx) {                    // x rows
            const int b = (int)(m0 >> 11);
            const int t = r & (Tc - 1);
            const long bh = (long)(b * Hc + hh);
            if (which == 0)      ep.h0[(bh * Tc + t) * Dc + d] = (half_t)(val * S1);  // QXs
            else if (which == 1) ep.h1[(bh * Tc + t) * Dc + d] = (half_t)val;         // KX
            else                 Txp[d * 136 + rloc] = (half_t)val;                   // VXT (LDS)
          } else {                      // y rows
            const long m2 = m0 - (long)Bc * Tc;
            const int b = (int)(m2 >> 10);
            const int t = (r - Bc * Tc) & (Mc - 1);
            const long bh = (long)(b * Hc + hh);
            if (which == 0)      Txp[d * 136 + rloc] = (half_t)(val * 0.125f);        // QYT (LDS)
            else if (which == 1) { ep.h4[(bh * Mc + t) * Dc + d] = (half_t)val;       // KY
                                   Txp[d * 136 + rloc] = (half_t)val; }               // KYT (LDS)
            else                 Txp[d * 136 + rloc] = (half_t)val;                   // VYT (LDS)
          }
        } else {  // EPI_PROJ
          ep.f0[(long)r * Cc + c] = v + ep.bias[c];
        }
      }
    }
  }

  if constexpr (EPI == EPI_QKV_XY && BM == 128) {
    const bool hasT = isx ? (which == 2) : true;
    if (hasT) {                     // block-uniform -> barrier is safe
      __syncthreads();
      half_t* dstT; int L; long tb; int b;
      if (isx) { dstT = ep.h2; L = Tc; tb = m0 & (Tc - 1); b = (int)(m0 >> 11); }
      else {
        const long m2 = m0 - (long)Bc * Tc;
        b = (int)(m2 >> 10); tb = m2 & (Mc - 1); L = Mc;
        dstT = (which == 0) ? ep.h3 : (which == 1) ? ep.h5 : ep.h6;
      }
      const long bh = (long)(b * Hc + hh);
      const int dr = tid >> 2, qd = tid & 3;       // 64 rows x 4 quarters
      half_t* gbase = dstT + (bh * 64 + dr) * L + tb + qd * 32;
#pragma unroll
      for (int j = 0; j < 4; ++j) {
        const half8 v8 = *reinterpret_cast<const half8*>(&Txp[dr * 136 + qd * 32 + j * 8]);
        *reinterpret_cast<half8*>(&gbase[j * 8]) = v8;
      }
    }
  }
}

// --------------------------------------------- fused WT+Q2 kernel
// grid 256 flat; logical (t-chunk, z) via XCD-chunked remap (same-z blocks
// co-locate: 2 z per XCD). Phase 1: WT[64][64] = 0.125 * QYTs[z] KYT[z]^T
// (K=1024, pipelined dbuf) -> LDS in phase-2 fragment layout. Phase 2:
// Q2[z, t0..t0+127, :] = QXs * WT^T (K=64, single tile, A staged async).
__global__ __launch_bounds__(256) void wtq2(
    const half_t* __restrict__ QYT, const half_t* __restrict__ KYT,
    const half_t* __restrict__ QX, half_t* __restrict__ Q2)
{
  __shared__ __align__(16) half_t As[2][4096];
  __shared__ __align__(16) half_t Bs[2][4096];
  __shared__ __align__(16) half_t WTs[4096];
  const int tid = threadIdx.x, lane = tid & 63, wave = tid >> 6;
  const int wm = wave >> 1, wn = wave & 1;
  const int r16 = lane & 15, g = lane >> 4;
  const int f = blockIdx.x;
  const int L = (f & 7) * 32 + (f >> 3);   // 256 blocks, chunk=32
  const int z = L >> 4;
  const int t0 = (L & 15) * 128;
  const half_t* Aq = QYT + (long)z * Dc * Mc;
  const half_t* Bk = KYT + (long)z * Dc * Mc;

  auto stage1 = [&](int kt, int buf) {
#pragma unroll
    for (int i = 0; i < 2; ++i) {
      const int c = tid + i * 256;
      const int row = c >> 3, js = c & 7, jg = js ^ (row & 7);
      gld_lds16(Aq + (long)row * Mc + kt + jg * 8, &As[buf][c * 8]);
    }
#pragma unroll
    for (int i = 0; i < 2; ++i) {
      const int c = tid + i * 256;
      const int row = c >> 3, js = c & 7, jg = js ^ (row & 7);
      gld_lds16(Bk + (long)row * Mc + kt + jg * 8, &Bs[buf][c * 8]);
    }
  };

  floatx4 acc[2][2];
#pragma unroll
  for (int mi = 0; mi < 2; ++mi)
#pragma unroll
    for (int ni = 0; ni < 2; ++ni) acc[mi][ni] = floatx4{0.f, 0.f, 0.f, 0.f};

  const int rA = wm * 32 + r16, rB = wn * 32 + r16;
  stage1(0, 0);
  asm volatile("" ::: "memory");
  for (int it = 0; it < 16; ++it) {
    const bool hn = (it < 15);
    if (hn) stage1((it + 1) * 64, (it + 1) & 1);
    asm volatile("" ::: "memory");
    if (hn) asm volatile("s_waitcnt vmcnt(4)" ::: "memory");
    else    asm volatile("s_waitcnt vmcnt(0)" ::: "memory");
    __builtin_amdgcn_s_barrier();
    asm volatile("" ::: "memory");
    const half_t* Ab = As[it & 1];
    const half_t* Bb = Bs[it & 1];
    half8 aF[2][2], bF[2][2];
#pragma unroll
    for (int mi = 0; mi < 2; ++mi)
#pragma unroll
      for (int k2 = 0; k2 < 2; ++k2)
        aF[mi][k2] = *reinterpret_cast<const half8*>(
            &Ab[(rA + mi * 16) * 64 + ((k2 * 4 + g) ^ (r16 & 7)) * 8]);
#pragma unroll
    for (int ni = 0; ni < 2; ++ni)
#pragma unroll
      for (int k2 = 0; k2 < 2; ++k2)
        bF[ni][k2] = *reinterpret_cast<const half8*>(
            &Bb[(rB + ni * 16) * 64 + ((k2 * 4 + g) ^ (r16 & 7)) * 8]);
    __builtin_amdgcn_s_setprio(1);
#pragma unroll
    for (int k2 = 0; k2 < 2; ++k2)
#pragma unroll
      for (int mi = 0; mi < 2; ++mi)
#pragma unroll
        for (int ni = 0; ni < 2; ++ni)
          acc[mi][ni] = __builtin_amdgcn_mfma_f32_16x16x32_f16(
              aF[mi][k2], bF[ni][k2], acc[mi][ni], 0, 0, 0);
    __builtin_amdgcn_s_setprio(0);
    asm volatile("s_waitcnt lgkmcnt(0)" ::: "memory");
    __builtin_amdgcn_s_barrier();
    asm volatile("" ::: "memory");
  }

  // phase-2 A stage (As fully free after final barrier): QX rows t0..t0+127
  half_t* P2 = &As[0][0];
#pragma unroll
  for (int i = 0; i < 4; ++i) {
    const int c = tid + i * 256;
    const int row = c >> 3, js = c & 7, jg = js ^ (row & 7);
    gld_lds16(QX + ((long)z * Tc + t0 + row) * 64 + jg * 8, P2 + c * 8);
  }
  // WT -> LDS f16 in phase-2 fragment layout (chunk swizzle js^(row&7))
#pragma unroll
  for (int mi = 0; mi < 2; ++mi)
#pragma unroll
    for (int ni = 0; ni < 2; ++ni)
#pragma unroll
      for (int reg = 0; reg < 4; ++reg) {
        const int r = wm * 32 + mi * 16 + g * 4 + reg;   // d2
        const int c = wn * 32 + ni * 16 + r16;           // d1
        WTs[r * 64 + (((c >> 3) ^ (r & 7)) << 3) + (c & 7)] =
            (half_t)(acc[mi][ni][reg] * 0.125f);
      }
  __syncthreads();   // drains vmcnt (QX stage) + lgkm (WTs writes)

  // phase 2: per wave 32 t-rows, full 64 d2 cols, K=64
  floatx4 a2[2][4];
#pragma unroll
  for (int mi = 0; mi < 2; ++mi)
#pragma unroll
    for (int ni = 0; ni < 4; ++ni) a2[mi][ni] = floatx4{0.f, 0.f, 0.f, 0.f};
  const int rA2 = wave * 32 + r16;
  half8 aF2[2][2], bF2[4][2];
#pragma unroll
  for (int mi = 0; mi < 2; ++mi)
#pragma unroll
    for (int k2 = 0; k2 < 2; ++k2)
      aF2[mi][k2] = *reinterpret_cast<const half8*>(
          &P2[(rA2 + mi * 16) * 64 + ((k2 * 4 + g) ^ (r16 & 7)) * 8]);
#pragma unroll
  for (int ni = 0; ni < 4; ++ni)
#pragma unroll
    for (int k2 = 0; k2 < 2; ++k2)
      bF2[ni][k2] = *reinterpret_cast<const half8*>(
          &WTs[(ni * 16 + r16) * 64 + ((k2 * 4 + g) ^ (r16 & 7)) * 8]);
#pragma unroll
  for (int k2 = 0; k2 < 2; ++k2)
#pragma unroll
    for (int mi = 0; mi < 2; ++mi)
#pragma unroll
      for (int ni = 0; ni < 4; ++ni)
        a2[mi][ni] = __builtin_amdgcn_mfma_f32_16x16x32_f16(
            aF2[mi][k2], bF2[ni][k2], a2[mi][ni], 0, 0, 0);
#pragma unroll
  for (int mi = 0; mi < 2; ++mi)
#pragma unroll
    for (int ni = 0; ni < 4; ++ni)
#pragma unroll
      for (int reg = 0; reg < 4; ++reg) {
        const int t = t0 + wave * 32 + mi * 16 + g * 4 + reg;
        const int c = ni * 16 + r16;
        Q2[((long)z * Tc + t) * 64 + c] = (half_t)a2[mi][ni][reg];
      }
}

// ------------------------------------------------------------ flash staging
__device__ __forceinline__ void stageK128(const half_t* Kz, int s0, half_t* dst, int tid) {
#pragma unroll
  for (int i = 0; i < 4; ++i) {
    const int c = tid + i * 256;
    const int row = c >> 3, js = c & 7;
    const int jg = js ^ (row & 7);
    gld_lds16(Kz + (long)(s0 + row) * 64 + jg * 8, dst + c * 8);
  }
}
__device__ __forceinline__ void stageV128(const half_t* Vz, int s0, int Slen, half_t* dst, int tid) {
#pragma unroll
  for (int i = 0; i < 4; ++i) {
    const int c = tid + i * 256;
    const int row = c >> 4, js = c & 15;
    const int jg = js ^ (row & 15);
    gld_lds16(Vz + (long)row * Slen + s0 + jg * 8, dst + c * 8);
  }
}

// --------------------------------------------------------- flash body (MI=2)
// R19 schedule (unchanged): vmcnt(4)+barrier [K(t) ready] ; QK MFMA cluster ;
// issue K(t+1) ; softmax (mask+exp2) ; vmcnt(4)+barrier [V(t) ready] ; PV
// (+ones-MFMA row-sum) ; barrier ; issue V(t+1).
// PARTIAL: unnormalized O -> f16 POh + row-sum -> Lp. else normalized f16.
template <bool MASKED, bool PARTIAL>
__device__ __forceinline__ void flash_body(
    const half_t* __restrict__ Qp, const half_t* __restrict__ Kp,
    const half_t* __restrict__ Vp, const unsigned char* __restrict__ mpk,
    half_t* __restrict__ POh, float* __restrict__ Lp, half_t* __restrict__ outF,
    int Slen, int sbeg, int scount, int z, int q0,
    half_t* Kb0, half_t* Kb1, half_t* Vb)
{
  const int tid = threadIdx.x, lane = tid & 63, w = tid >> 6;
  const int r16 = lane & 15, g = lane >> 4;
  const int b = z >> 3, h = z & 7;
  const int NT = Slen >> 7;
  const half_t* Qz = Qp + ((long)z * Tc + q0) * 64;
  const half_t* Kz = Kp + (long)z * Slen * 64;
  const half_t* Vz = Vp + (long)z * 64 * Slen;

  // prologue staging: K(0), V(0) (oldest 8 vmem ops, in this order)
  stageK128(Kz, sbeg, Kb0, tid);
  asm volatile("" ::: "memory");
  stageV128(Vz, sbeg, Slen, Vb, tid);
  asm volatile("" ::: "memory");

  half8 aQ[2][2];
#pragma unroll
  for (int mi = 0; mi < 2; ++mi)
#pragma unroll
    for (int k2 = 0; k2 < 2; ++k2)
      aQ[mi][k2] = *reinterpret_cast<const half8*>(
          Qz + (w * 32 + mi * 16 + r16) * 64 + k2 * 32 + g * 8);

  half8 vones;
#pragma unroll
  for (int j = 0; j < 8; ++j) vones[j] = (half_t)1.f;

  floatx4 oaccT[2][4];
  floatx4 lacc4[2];
#pragma unroll
  for (int mi = 0; mi < 2; ++mi) {
    lacc4[mi] = floatx4{0.f, 0.f, 0.f, 0.f};
#pragma unroll
    for (int no = 0; no < 4; ++no) oaccT[mi][no] = floatx4{0.f, 0.f, 0.f, 0.f};
  }

  const int send = sbeg + scount;
  int cur = 0;
  for (int s0 = sbeg; s0 < send; s0 += 128) {
    const bool hn = (s0 + 128 < send);
    // K(t) ready (V(t) may still fly; K is the oldest outstanding group)
    asm volatile("s_waitcnt vmcnt(4)" ::: "memory");
    __builtin_amdgcn_s_barrier();
    asm volatile("" ::: "memory");

    unsigned int mb32[2];
    if constexpr (MASKED) {
      const int tile = s0 >> 7;
#pragma unroll
      for (int mi = 0; mi < 2; ++mi) {
        const int q = q0 + w * 32 + mi * 16 + r16;
        mb32[mi] = *reinterpret_cast<const unsigned int*>(
            mpk + ((long)q * NT + tile) * 16 + 4 * g);
      }
    }

    // S^T = K Q^T : 16 b128 reads feed 32 MFMAs
    floatx4 sacc[2][8];
#pragma unroll
    for (int mi = 0; mi < 2; ++mi)
#pragma unroll
      for (int ni = 0; ni < 8; ++ni) sacc[mi][ni] = floatx4{0.f, 0.f, 0.f, 0.f};
    const half_t* Kc = cur ? Kb1 : Kb0;
    __builtin_amdgcn_s_setprio(1);
#pragma unroll
    for (int ni = 0; ni < 8; ++ni) {
      const int rB = ni * 16 + r16;
      const half8 b0 = *reinterpret_cast<const half8*>(&Kc[rB * 64 + (g ^ (rB & 7)) * 8]);
      const half8 b1 = *reinterpret_cast<const half8*>(&Kc[rB * 64 + ((4 + g) ^ (rB & 7)) * 8]);
#pragma unroll
      for (int mi = 0; mi < 2; ++mi) {
        sacc[mi][ni] = __builtin_amdgcn_mfma_f32_16x16x32_f16(b0, aQ[mi][0], sacc[mi][ni], 0, 0, 0);
        sacc[mi][ni] = __builtin_amdgcn_mfma_f32_16x16x32_f16(b1, aQ[mi][1], sacc[mi][ni], 0, 0, 0);
      }
    }
    __builtin_amdgcn_s_setprio(0);
    // prefetch K(t+1) into the other buffer; lands under softmax+PV
    if (hn) stageK128(Kz, s0 + 128, cur ? Kb0 : Kb1, tid);
    asm volatile("" ::: "memory");

    // in-register softmax (separated phase): mask + exp2 only; row-sum
    // rides the PV ones-MFMA.
#pragma unroll
    for (int mi = 0; mi < 2; ++mi) {
      if constexpr (MASKED) {
        if (mb32[mi] != 0xffffffffu) {
#pragma unroll
          for (int reg = 0; reg < 4; ++reg)
#pragma unroll
            for (int ni = 0; ni < 8; ++ni)
              if (!((mb32[mi] >> (reg * 8 + ni)) & 1)) sacc[mi][ni][reg] = -__builtin_inff();
        }
      }
#pragma unroll
      for (int ni = 0; ni < 8; ++ni)
#pragma unroll
        for (int reg = 0; reg < 4; ++reg)
          sacc[mi][ni][reg] = __builtin_amdgcn_exp2f(sacc[mi][ni][reg]);
    }

    // V(t) ready (K(t+1) = newest 4 still in flight when hn)
    if (hn) { asm volatile("s_waitcnt vmcnt(4)" ::: "memory"); }
    else    { asm volatile("s_waitcnt vmcnt(0)" ::: "memory"); }
    __builtin_amdgcn_s_barrier();
    asm volatile("" ::: "memory");

    // O^T += V^T P^T ; l += ones·P^T (row-sum via matrix pipe)
#pragma unroll
    for (int c = 0; c < 4; ++c) {
      half8 bVv[4];
#pragma unroll
      for (int no = 0; no < 4; ++no) {
        const int rV = no * 16 + r16;
        bVv[no] = *reinterpret_cast<const half8*>(
            &Vb[rV * 128 + ((c * 4 + g) ^ (rV & 15)) * 8]);
      }
#pragma unroll
      for (int mi = 0; mi < 2; ++mi) {
        // butterfly P^T frag: target word p_t at lane g <-
        // pk[2c+(g>>1)][p_t&1] of lane 2(g&1)+(p_t>>1)
        int x0 = pkrtz(sacc[mi][2 * c][0],     sacc[mi][2 * c][1]);
        int x1 = pkrtz(sacc[mi][2 * c][2],     sacc[mi][2 * c][3]);
        int x2 = pkrtz(sacc[mi][2 * c + 1][0], sacc[mi][2 * c + 1][1]);
        int x3 = pkrtz(sacc[mi][2 * c + 1][2], sacc[mi][2 * c + 1][3]);
        pl32(x0, x2); pl32(x1, x3);   // resolve g1 <-> ni bit
        pl16(x0, x2); pl16(x1, x3);   // resolve g0 <-> word bit
        int4v wv; wv[0] = x0; wv[1] = x1; wv[2] = x2; wv[3] = x3;
        const half8 aP = __builtin_bit_cast(half8, wv);
        __builtin_amdgcn_s_setprio(1);
#pragma unroll
        for (int no = 0; no < 4; ++no)
          oaccT[mi][no] = __builtin_amdgcn_mfma_f32_16x16x32_f16(bVv[no], aP, oaccT[mi][no], 0, 0, 0);
        lacc4[mi] = __builtin_amdgcn_mfma_f32_16x16x32_f16(vones, aP, lacc4[mi], 0, 0, 0);
        __builtin_amdgcn_s_setprio(0);
      }
    }
    __builtin_amdgcn_s_barrier();
    asm volatile("" ::: "memory");
    // prefetch V(t+1); lands under next tile's QK^T + softmax
    if (hn) stageV128(Vz, s0 + 128, Slen, Vb, tid);
    asm volatile("" ::: "memory");
    cur ^= 1;
  }

  // epilogue: l_q sits in every lane's lacc4[mi][0] (col=lane&15=q).
  float ls2[2];
#pragma unroll
  for (int mi = 0; mi < 2; ++mi) ls2[mi] = lacc4[mi][0];

  float* slab = reinterpret_cast<float*>(Vb) + w * 1024;
#pragma unroll
  for (int mi = 0; mi < 2; ++mi) {
    const int tq = q0 + w * 32 + mi * 16;
    if constexpr (PARTIAL) {
      if (lane < 16) Lp[(long)z * Tc + tq + r16] = ls2[mi];
    }
    const float sc = PARTIAL ? 1.f : (1.f / ls2[mi]);
#pragma unroll
    for (int no = 0; no < 4; ++no) {
      floatx4 v = oaccT[mi][no];
      if constexpr (!PARTIAL) v *= sc;
      *reinterpret_cast<floatx4*>(&slab[r16 * 64 + no * 16 + (g ^ (r16 & 3)) * 4]) = v;
    }
#pragma unroll
    for (int it = 0; it < 4; ++it) {
      const int q2 = it * 4 + g;
      const int d4 = r16;
      const floatx4 v = *reinterpret_cast<const floatx4*>(
          &slab[q2 * 64 + (d4 >> 2) * 16 + ((d4 & 3) ^ (q2 & 3)) * 4]);
      const long off = ((long)(b * Tc + tq + q2)) * Cc + h * 64 + d4 * 4;
      half4v hh; hh[0] = (half_t)v[0]; hh[1] = (half_t)v[1];
      hh[2] = (half_t)v[2]; hh[3] = (half_t)v[3];
      if constexpr (PARTIAL) {
        *reinterpret_cast<half4v*>(&POh[off]) = hh;   // unnormalized f16
      } else {
        *reinterpret_cast<half4v*>(&outF[off]) = hh;
      }
    }
  }
}

// 768 blocks, each exactly 8 s-tiles (= 3 blocks/CU, one balanced round):
//  bx < 512:  att0 (chained, masked), s-half sh=(bx>>4)&1, unnormalized f16+L
//  bx >= 512: att1 (first), full s-range, normalized f16 -> DH2
__global__ __launch_bounds__(256, 3) void flash_both(
    const half_t* __restrict__ Q2, const half_t* __restrict__ KX,
    const half_t* __restrict__ VXT, const unsigned char* __restrict__ mpk,
    const half_t* __restrict__ QX, const half_t* __restrict__ KY,
    const half_t* __restrict__ VYT,
    half_t* __restrict__ POh, float* __restrict__ Lp, half_t* __restrict__ DH2)
{
  __shared__ __align__(16) half_t Kb0[8192];
  __shared__ __align__(16) half_t Kb1[8192];
  __shared__ __align__(16) half_t Vb[8192];
  const int bx = blockIdx.x;
  if (bx < 512) {
    const int z  = ((bx & 7) << 1) | ((bx >> 3) & 1);   // z-local per XCD
    const int sh = (bx >> 4) & 1;
    const int q0 = (bx >> 5) * 128;
    flash_body<true, true>(Q2, KX, VXT, mpk,
                           POh + (long)sh * BTC, Lp + (long)sh * ZT, nullptr,
                           Tc, sh * 1024, 1024, z, q0, Kb0, Kb1, Vb);
  } else {
    const int b2 = bx - 512;
    const int z  = ((b2 & 7) << 1) | ((b2 >> 3) & 1);
    const int q0 = (b2 >> 4) * 128;
    flash_body<false, false>(QX, KY, VYT, nullptr,
                             nullptr, nullptr, DH2,
                             Mc, 0, Mc, z, q0, Kb0, Kb1, Vb);
  }
}

// --------------------------- combine att0 s-halves + diff with DH2 -> DH
__global__ __launch_bounds__(256) void combine_k(
    const half_t* __restrict__ POh, const float* __restrict__ Lp,
    const half_t* __restrict__ DH2, half_t* __restrict__ DH)
{
  const long idx = (long)blockIdx.x * 256 + threadIdx.x;   // over BTC/4
  const long c4 = idx * 4;
  const int c = (int)(c4 & (Cc - 1));
  const long bt = c4 >> 9;
  const int h = c >> 6;
  const int b = (int)(bt >> 11), t = (int)(bt & (Tc - 1));
  const long zt = (long)(b * Hc + h) * Tc + t;
  const float ainv = 1.f / (Lp[zt] + Lp[ZT + zt]);
  const half4v oa0 = reinterpret_cast<const half4v*>(POh)[idx];
  const half4v oa1 = reinterpret_cast<const half4v*>(POh)[BTC / 4 + idx];
  const half4v dv = reinterpret_cast<const half4v*>(DH2)[idx];
  half4v r;
  r[0] = (half_t)((float)dv[0] - ((float)oa0[0] + (float)oa1[0]) * ainv);
  r[1] = (half_t)((float)dv[1] - ((float)oa0[1] + (float)oa1[1]) * ainv);
  r[2] = (half_t)((float)dv[2] - ((float)oa0[2] + (float)oa1[2]) * ainv);
  r[3] = (half_t)((float)dv[3] - ((float)oa0[3] + (float)oa1[3]) * ainv);
  reinterpret_cast<half4v*>(DH)[idx] = r;
}

// ----------------------------------------------- prep: converts + mask pack
__device__ __forceinline__ void cvt4(const float* in, half_t* out, long i) {
  const float4 f = reinterpret_cast<const float4*>(in)[i];
  half4v h; h[0] = (half_t)f.x; h[1] = (half_t)f.y; h[2] = (half_t)f.z; h[3] = (half_t)f.w;
  reinterpret_cast<half4v*>(out)[i] = h;
}

__global__ __launch_bounds__(256) void prep(
    const float* __restrict__ x, const float* __restrict__ y,
    const float* __restrict__ qw, const float* __restrict__ pw,
    const int* __restrict__ mask,
    half_t* __restrict__ XH, half_t* __restrict__ YH,
    half_t* __restrict__ WQ, half_t* __restrict__ WP,
    unsigned char* __restrict__ mpk)
{
  const long i = (long)blockIdx.x * 256 + threadIdx.x;
  constexpr long n0 = 524288;            // x/4
  constexpr long n1 = n0 + 262144;       // y/4
  constexpr long n2 = n1 + 196608;       // qkv_w/4
  constexpr long n3 = n2 + 65536;        // proj_w/4
  if (i < n0) cvt4(x, XH, i);
  else if (i < n1) cvt4(y, YH, i - n0);
  else if (i < n2) cvt4(qw, WQ, i - n1);
  else if (i < n3) cvt4(pw, WP, i - n2);
  else {
    const long idx = i - n3;             // [0, Tc*256)
    const int t = (int)(idx >> 8), tile = (int)((idx >> 4) & 15), r16 = (int)(idx & 15);
    const int* row = mask + (long)t * Tc + tile * 128 + r16;
    unsigned int bbits = 0;
#pragma unroll
    for (int ni = 0; ni < 8; ++ni)
      bbits |= (row[ni * 16] != 0 ? 1u : 0u) << ni;
    mpk[idx] = (unsigned char)bbits;
  }
}

// ------------------------------------------------------------- workspace map
constexpr size_t OFF_XH   = 0;                                   // [B*T,C] f16 (YH must follow!)
constexpr size_t OFF_YH   = OFF_XH   + (size_t)Bc*Tc*Cc*2;       // contiguous rows after XH
constexpr size_t OFF_WQ   = OFF_YH   + (size_t)Bc*Mc*Cc*2;
constexpr size_t OFF_WP   = OFF_WQ   + (size_t)3*Cc*Cc*2;
constexpr size_t OFF_QX   = OFF_WP   + (size_t)Cc*Cc*2;          // [z,T,D] *0.125*log2e
constexpr size_t OFF_KX   = OFF_QX   + (size_t)Bc*Hc*Tc*Dc*2;    // [z,T,D]
constexpr size_t OFF_VXT  = OFF_KX   + (size_t)Bc*Hc*Tc*Dc*2;    // [z,D,T]
constexpr size_t OFF_QYT  = OFF_VXT  + (size_t)Bc*Hc*Tc*Dc*2;    // [z,D,M] *0.125
constexpr size_t OFF_KY   = OFF_QYT  + (size_t)Bc*Hc*Mc*Dc*2;    // [z,M,D]
constexpr size_t OFF_KYT  = OFF_KY   + (size_t)Bc*Hc*Mc*Dc*2;    // [z,D,M]
constexpr size_t OFF_VYT  = OFF_KYT  + (size_t)Bc*Hc*Mc*Dc*2;    // [z,D,M]
constexpr size_t OFF_Q2   = OFF_VYT  + (size_t)Bc*Hc*Mc*Dc*2;    // [z,T,D]
constexpr size_t OFF_DH   = OFF_Q2   + (size_t)Bc*Hc*Tc*Dc*2;    // [B,T,C] diff f16
constexpr size_t OFF_DH2  = OFF_DH   + (size_t)Bc*Tc*Cc*2;       // [B,T,C] cval_x2y f16
constexpr size_t OFF_MPK  = OFF_DH2  + (size_t)Bc*Tc*Cc*2;       // [T,16,16] u8
constexpr size_t OFF_PO   = OFF_MPK  + (size_t)Tc*256;           // [2][B,T,C] f16 unnormalized
constexpr size_t OFF_L    = OFF_PO   + (size_t)2*BTC*2;          // [2][ZT] f32 row sums
// total ~47 MB

extern "C" void kernel_launch(void* const* d_in, const int* in_sizes, int n_in,
                              void* d_out, int out_size, void* d_ws, size_t ws_size,
                              hipStream_t stream) {
  const float* x      = (const float*)d_in[0];
  const float* y      = (const float*)d_in[1];
  const int*   mask   = (const int*)  d_in[2];
  const float* qkv_b  = (const float*)d_in[4];
  const float* proj_b = (const float*)d_in[6];
  float* out = (float*)d_out;
  char* ws = (char*)d_ws;

  half_t* XH   = (half_t*)(ws + OFF_XH);
  half_t* YH   = (half_t*)(ws + OFF_YH);
  half_t* WQ   = (half_t*)(ws + OFF_WQ);
  half_t* WP   = (half_t*)(ws + OFF_WP);
  half_t* QX   = (half_t*)(ws + OFF_QX);
  half_t* KX   = (half_t*)(ws + OFF_KX);
  half_t* VXT  = (half_t*)(ws + OFF_VXT);
  half_t* QYT  = (half_t*)(ws + OFF_QYT);
  half_t* KY   = (half_t*)(ws + OFF_KY);
  half_t* KYT  = (half_t*)(ws + OFF_KYT);
  half_t* VYT  = (half_t*)(ws + OFF_VYT);
  half_t* Q2   = (half_t*)(ws + OFF_Q2);
  half_t* DH   = (half_t*)(ws + OFF_DH);
  half_t* DH2  = (half_t*)(ws + OFF_DH2);
  unsigned char* MPK = (unsigned char*)(ws + OFF_MPK);
  half_t* POh  = (half_t*)(ws + OFF_PO);
  float*  Lp   = (float*) (ws + OFF_L);

  // converts + mask packing (one launch)
  prep<<<6144, 256, 0, stream>>>(x, y, (const float*)d_in[3], (const float*)d_in[5],
                                 mask, XH, YH, WQ, WP, MPK);

  // fused qkv projection for x and y (XH||YH contiguous: 6144 rows)
  // XCD-chunked remap: 6 contiguous A-panels per XCD (GX=24, GY=48)
  {
    EpiParams ep{};
    ep.h0 = QX; ep.h1 = KX; ep.h2 = VXT; ep.h3 = QYT;
    ep.h4 = KY; ep.h5 = KYT; ep.h6 = VYT; ep.bias = qkv_b;
    gemm_nt<128,64,2,2,EPI_QKV_XY,24,48><<<dim3(24, 48, 1), 256, 0, stream>>>(
        XH, WQ, Cc, Cc, Cc, 0, 0, ep);
  }

  // fused WT+Q2: 256 flat blocks, XCD remap (2 z per XCD)
  wtq2<<<dim3(256), 256, 0, stream>>>(QYT, KYT, QX, Q2);

  // balanced flash: 512 att0-half blocks + 256 att1 blocks = 768 (3/CU)
  flash_both<<<dim3(768), 256, 0, stream>>>(
      Q2, KX, VXT, MPK, QX, KY, VYT, POh, Lp, DH2);

  // combine att0 halves + diff with DH2 -> DH
  combine_k<<<(int)(BTC/4/256), 256, 0, stream>>>(POh, Lp, DH2, DH);

  // out = DH @ proj_w^T + proj_b  (XCD remap: 8 A-panels per XCD)
  {
    EpiParams ep{}; ep.f0 = out; ep.bias = proj_b;
    gemm_nt<64,64,2,2,EPI_PROJ,8,64><<<dim3(8, 64, 1), 256, 0, stream>>>(
        DH, WP, Cc, Cc, Cc, 0, 0, ep);
  }
}

// Round 11
// 171.532 us; speedup vs baseline: 1.1330x; 1.0117x over previous
//
#include <hip/hip_runtime.h>

// CrossAttentionPro on MI355X — Round 23 (R22 retry, spill-free):
//  R22's NaN traced to __launch_bounds__(256,6) forcing VGPR cap 84 vs
//  ~110 live state => ~26 regs spilled through the inline-asm vmcnt /
//  raw-barrier / permlane region (codegen hazard, guide rule #18 family).
//  Fix: __launch_bounds__(256,4) -> natural allocation, zero spills.
//  24KB LDS still allows 6 blocks/CU; VGPRs give 4-5 -> occupancy still
//  rises vs R21's 3 blocks/CU, which was the point of the 64-s tiles:
//  1536 blocks x 8 tiles (att0 in 4 s-quarters, att1 in 2 s-halves), all
//  partial (unnormalized f16 O + L row-sums), combine merges 6 slabs.
//  Per-tile schedule = proven R19 rhythm (3 barriers, K dbuf, counted
//  vmcnt(2), separated softmax, ones-MFMA row-sum, pkrtz+permlane P-frag
//  butterfly, setprio). Kept: swapped-operand S^T=mfma(K,Q), no-max exp2
//  softmax, coalesced qkv epilogue via LDS slab, XCD-chunked GEMM remaps,
//  wtq2 fusion, bit-packed mask, XCD z-locality.

typedef _Float16 half_t;
typedef _Float16 half8 __attribute__((ext_vector_type(8)));
typedef _Float16 half4v __attribute__((ext_vector_type(4)));
typedef float floatx4 __attribute__((ext_vector_type(4)));
typedef int int4v __attribute__((ext_vector_type(4)));

constexpr int Bc = 2, Tc = 2048, Mc = 1024, Cc = 512, Hc = 8, Dc = 64;
constexpr long BTC = (long)Bc * Tc * Cc;
constexpr long ZT  = (long)Bc * Hc * Tc;
constexpr float S1 = 0.18033688f;                 // 0.125 * log2(e)

enum { EPI_F16STORE = 0, EPI_QKV_XY = 1, EPI_PROJ = 2 };

struct EpiParams {
  half_t* h0;        // QXs  / f16 dest
  half_t* h1;        // KX
  half_t* h2;        // VXT
  half_t* h3;        // QYT
  half_t* h4;        // KY
  half_t* h5;        // KYT
  half_t* h6;        // VYT
  float* f0;
  const float* bias;
  float scale;
  int ldc;
  long bstride;
};

// async global->LDS, 16B per lane; dst must be wave-uniform base + lane*16.
__device__ __forceinline__ void gld_lds16(const half_t* g, half_t* l) {
  __builtin_amdgcn_global_load_lds(
      (const __attribute__((address_space(1))) void*)g,
      (__attribute__((address_space(3))) void*)l, 16, 0, 0);
}

// pack 2 f32 -> 2 f16 (RTZ) as one u32
__device__ __forceinline__ int pkrtz(float a, float b) {
  return __builtin_bit_cast(int, __builtin_amdgcn_cvt_pkrtz(a, b));
}
// v_permlane16_swap: a.row1<->b.row0, a.row3<->b.row2 (rows = 16-lane groups)
__device__ __forceinline__ void pl16(int& a, int& b) {
  asm volatile("v_permlane16_swap_b32 %0, %1" : "+v"(a), "+v"(b));
}
// v_permlane32_swap: a.rows{2,3} <-> b.rows{0,1}
__device__ __forceinline__ void pl32(int& a, int& b) {
  asm volatile("v_permlane32_swap_b32 %0, %1" : "+v"(a), "+v"(b));
}

// ---------------------------------------------------------------- GEMM (NT)
// C[r,c] = sum_k A[r,k]*Bt[c,k]. BK=64 double-buffered async staging with
// counted vmcnt, swizzled chunks (conflict-free ds_read_b128).
// GX/GY: logical grid dims for XCD-chunked remap (0 = no remap).
template <int BM, int BN, int WMG, int WNG, int EPI, int GX = 0, int GY = 0>
__global__ __launch_bounds__(256) void gemm_nt(
    const half_t* __restrict__ A, const half_t* __restrict__ Bt,
    int K, int lda, int ldb, long bsA, long bsB, EpiParams ep)
{
  constexpr int BK = 64;
  constexpr int WTM = BM / WMG, WTN = BN / WNG;
  constexpr int MI = WTM / 16, NI = WTN / 16;
  constexpr int AIT = BM * BK / 8 / 256;
  constexpr int BIT = BN * BK / 8 / 256;
  constexpr int NLD = AIT + BIT;
  __shared__ __align__(16) half_t As[2][BM * BK];
  __shared__ __align__(16) half_t Bs[2][BN * BK];

  const int tid = threadIdx.x;
  const int lane = tid & 63;
  const int wave = tid >> 6;
  const int wm = wave / WNG, wn = wave % WNG;
  const int r16 = lane & 15, g = lane >> 4;
  const int z = blockIdx.z;

  int bxl = blockIdx.x, byl = blockIdx.y;
  if constexpr (GX > 0) {
    constexpr int CHUNK = GX * GY / 8;   // GX*GY % 8 == 0 required
    const int f = byl * GX + bxl;
    const int L = (f & 7) * CHUNK + (f >> 3);
    bxl = L % GX; byl = L / GX;
  }
  const long m0 = (long)byl * BM;
  const long n0 = (long)bxl * BN;
  const half_t* Abase = A + (long)z * bsA + m0 * (long)lda;
  const half_t* Bbase = Bt + (long)z * bsB + n0 * (long)ldb;

  const int rA = wm * WTM + r16;
  const int rB = wn * WTN + r16;

  floatx4 acc[MI][NI];
#pragma unroll
  for (int mi = 0; mi < MI; ++mi)
#pragma unroll
    for (int ni = 0; ni < NI; ++ni)
      acc[mi][ni] = floatx4{0.f, 0.f, 0.f, 0.f};

  auto stage = [&](int kt, int buf) {
#pragma unroll
    for (int i = 0; i < AIT; ++i) {
      const int c = tid + i * 256;
      const int row = c >> 3, js = c & 7;
      const int jg = js ^ (row & 7);
      gld_lds16(Abase + (long)row * lda + kt + jg * 8, &As[buf][c * 8]);
    }
#pragma unroll
    for (int i = 0; i < BIT; ++i) {
      const int c = tid + i * 256;
      const int row = c >> 3, js = c & 7;
      const int jg = js ^ (row & 7);
      gld_lds16(Bbase + (long)row * ldb + kt + jg * 8, &Bs[buf][c * 8]);
    }
  };

  const int NIT = K / BK;
  stage(0, 0);
  asm volatile("" ::: "memory");

  for (int it = 0; it < NIT; ++it) {
    const bool hn = (it + 1 < NIT);
    if (hn) stage((it + 1) * BK, (it + 1) & 1);
    asm volatile("" ::: "memory");
    if (hn) {
      if constexpr (NLD == 6) asm volatile("s_waitcnt vmcnt(6)" ::: "memory");
      else if constexpr (NLD == 4) asm volatile("s_waitcnt vmcnt(4)" ::: "memory");
      else if constexpr (NLD == 8) asm volatile("s_waitcnt vmcnt(8)" ::: "memory");
      else asm volatile("s_waitcnt vmcnt(0)" ::: "memory");
    } else {
      asm volatile("s_waitcnt vmcnt(0)" ::: "memory");
    }
    __builtin_amdgcn_s_barrier();
    asm volatile("" ::: "memory");

    const half_t* Ab = As[it & 1];
    const half_t* Bb = Bs[it & 1];
    half8 aF[MI][2], bF[NI][2];
#pragma unroll
    for (int mi = 0; mi < MI; ++mi)
#pragma unroll
      for (int k2 = 0; k2 < 2; ++k2)
        aF[mi][k2] = *reinterpret_cast<const half8*>(
            &Ab[(rA + mi * 16) * BK + ((k2 * 4 + g) ^ (r16 & 7)) * 8]);
#pragma unroll
    for (int ni = 0; ni < NI; ++ni)
#pragma unroll
      for (int k2 = 0; k2 < 2; ++k2)
        bF[ni][k2] = *reinterpret_cast<const half8*>(
            &Bb[(rB + ni * 16) * BK + ((k2 * 4 + g) ^ (r16 & 7)) * 8]);
    __builtin_amdgcn_s_setprio(1);
#pragma unroll
    for (int k2 = 0; k2 < 2; ++k2)
#pragma unroll
      for (int mi = 0; mi < MI; ++mi)
#pragma unroll
        for (int ni = 0; ni < NI; ++ni)
          acc[mi][ni] = __builtin_amdgcn_mfma_f32_16x16x32_f16(
              aF[mi][k2], bF[ni][k2], acc[mi][ni], 0, 0, 0);
    __builtin_amdgcn_s_setprio(0);
    asm volatile("s_waitcnt lgkmcnt(0)" ::: "memory");
    __builtin_amdgcn_s_barrier();
    asm volatile("" ::: "memory");
  }

  // epilogue: C/D layout col=lane&15, row=(lane>>4)*4+reg  [m89-verified]
  // transposed-output slab (reuses As, free after last barrier): [64][136]
  half_t* Txp = &As[0][0];
  const bool isx  = (m0 < (long)Bc * Tc);
  const int which = (int)(n0 >> 9);
  const int hh    = ((int)n0 & 511) >> 6;

#pragma unroll
  for (int mi = 0; mi < MI; ++mi) {
#pragma unroll
    for (int ni = 0; ni < NI; ++ni) {
#pragma unroll
      for (int reg = 0; reg < 4; ++reg) {
        const int r = (int)m0 + wm * WTM + mi * 16 + g * 4 + reg;
        const int c = (int)n0 + wn * WTN + ni * 16 + r16;
        const float v = acc[mi][ni][reg];
        if constexpr (EPI == EPI_F16STORE) {
          ep.h0[(long)z * ep.bstride + (long)r * ep.ldc + c] = (half_t)(v * ep.scale);
        } else if constexpr (EPI == EPI_QKV_XY) {
          const float val = v + ep.bias[c];
          const int d = c & 63;
          const int rloc = r - (int)m0;
          if (isx) {                    // x rows
            const int b = (int)(m0 >> 11);
            const int t = r & (Tc - 1);
            const long bh = (long)(b * Hc + hh);
            if (which == 0)      ep.h0[(bh * Tc + t) * Dc + d] = (half_t)(val * S1);  // QXs
            else if (which == 1) ep.h1[(bh * Tc + t) * Dc + d] = (half_t)val;         // KX
            else                 Txp[d * 136 + rloc] = (half_t)val;                   // VXT (LDS)
          } else {                      // y rows
            const long m2 = m0 - (long)Bc * Tc;
            const int b = (int)(m2 >> 10);
            const int t = (r - Bc * Tc) & (Mc - 1);
            const long bh = (long)(b * Hc + hh);
            if (which == 0)      Txp[d * 136 + rloc] = (half_t)(val * 0.125f);        // QYT (LDS)
            else if (which == 1) { ep.h4[(bh * Mc + t) * Dc + d] = (half_t)val;       // KY
                                   Txp[d * 136 + rloc] = (half_t)val; }               // KYT (LDS)
            else                 Txp[d * 136 + rloc] = (half_t)val;                   // VYT (LDS)
          }
        } else {  // EPI_PROJ
          ep.f0[(long)r * Cc + c] = v + ep.bias[c];
        }
      }
    }
  }

  if constexpr (EPI == EPI_QKV_XY && BM == 128) {
    const bool hasT = isx ? (which == 2) : true;
    if (hasT) {                     // block-uniform -> barrier is safe
      __syncthreads();
      half_t* dstT; int L; long tb; int b;
      if (isx) { dstT = ep.h2; L = Tc; tb = m0 & (Tc - 1); b = (int)(m0 >> 11); }
      else {
        const long m2 = m0 - (long)Bc * Tc;
        b = (int)(m2 >> 10); tb = m2 & (Mc - 1); L = Mc;
        dstT = (which == 0) ? ep.h3 : (which == 1) ? ep.h5 : ep.h6;
      }
      const long bh = (long)(b * Hc + hh);
      const int dr = tid >> 2, qd = tid & 3;       // 64 rows x 4 quarters
      half_t* gbase = dstT + (bh * 64 + dr) * L + tb + qd * 32;
#pragma unroll
      for (int j = 0; j < 4; ++j) {
        const half8 v8 = *reinterpret_cast<const half8*>(&Txp[dr * 136 + qd * 32 + j * 8]);
        *reinterpret_cast<half8*>(&gbase[j * 8]) = v8;
      }
    }
  }
}

// --------------------------------------------- fused WT+Q2 kernel
// grid 256 flat; logical (t-chunk, z) via XCD-chunked remap (same-z blocks
// co-locate). Phase 1: WT[64][64] = 0.125 * QYTs[z] KYT[z]^T (K=1024,
// pipelined dbuf) -> LDS in phase-2 fragment layout. Phase 2:
// Q2[z, t0..t0+127, :] = QXs * WT^T (K=64, single tile, A staged async).
__global__ __launch_bounds__(256) void wtq2(
    const half_t* __restrict__ QYT, const half_t* __restrict__ KYT,
    const half_t* __restrict__ QX, half_t* __restrict__ Q2)
{
  __shared__ __align__(16) half_t As[2][4096];
  __shared__ __align__(16) half_t Bs[2][4096];
  __shared__ __align__(16) half_t WTs[4096];
  const int tid = threadIdx.x, lane = tid & 63, wave = tid >> 6;
  const int wm = wave >> 1, wn = wave & 1;
  const int r16 = lane & 15, g = lane >> 4;
  const int f = blockIdx.x;
  const int L = (f & 7) * 32 + (f >> 3);   // 256 blocks, chunk=32
  const int z = L >> 4;
  const int t0 = (L & 15) * 128;
  const half_t* Aq = QYT + (long)z * Dc * Mc;
  const half_t* Bk = KYT + (long)z * Dc * Mc;

  auto stage1 = [&](int kt, int buf) {
#pragma unroll
    for (int i = 0; i < 2; ++i) {
      const int c = tid + i * 256;
      const int row = c >> 3, js = c & 7, jg = js ^ (row & 7);
      gld_lds16(Aq + (long)row * Mc + kt + jg * 8, &As[buf][c * 8]);
    }
#pragma unroll
    for (int i = 0; i < 2; ++i) {
      const int c = tid + i * 256;
      const int row = c >> 3, js = c & 7, jg = js ^ (row & 7);
      gld_lds16(Bk + (long)row * Mc + kt + jg * 8, &Bs[buf][c * 8]);
    }
  };

  floatx4 acc[2][2];
#pragma unroll
  for (int mi = 0; mi < 2; ++mi)
#pragma unroll
    for (int ni = 0; ni < 2; ++ni) acc[mi][ni] = floatx4{0.f, 0.f, 0.f, 0.f};

  const int rA = wm * 32 + r16, rB = wn * 32 + r16;
  stage1(0, 0);
  asm volatile("" ::: "memory");
  for (int it = 0; it < 16; ++it) {
    const bool hn = (it < 15);
    if (hn) stage1((it + 1) * 64, (it + 1) & 1);
    asm volatile("" ::: "memory");
    if (hn) asm volatile("s_waitcnt vmcnt(4)" ::: "memory");
    else    asm volatile("s_waitcnt vmcnt(0)" ::: "memory");
    __builtin_amdgcn_s_barrier();
    asm volatile("" ::: "memory");
    const half_t* Ab = As[it & 1];
    const half_t* Bb = Bs[it & 1];
    half8 aF[2][2], bF[2][2];
#pragma unroll
    for (int mi = 0; mi < 2; ++mi)
#pragma unroll
      for (int k2 = 0; k2 < 2; ++k2)
        aF[mi][k2] = *reinterpret_cast<const half8*>(
            &Ab[(rA + mi * 16) * 64 + ((k2 * 4 + g) ^ (r16 & 7)) * 8]);
#pragma unroll
    for (int ni = 0; ni < 2; ++ni)
#pragma unroll
      for (int k2 = 0; k2 < 2; ++k2)
        bF[ni][k2] = *reinterpret_cast<const half8*>(
            &Bb[(rB + ni * 16) * 64 + ((k2 * 4 + g) ^ (r16 & 7)) * 8]);
    __builtin_amdgcn_s_setprio(1);
#pragma unroll
    for (int k2 = 0; k2 < 2; ++k2)
#pragma unroll
      for (int mi = 0; mi < 2; ++mi)
#pragma unroll
        for (int ni = 0; ni < 2; ++ni)
          acc[mi][ni] = __builtin_amdgcn_mfma_f32_16x16x32_f16(
              aF[mi][k2], bF[ni][k2], acc[mi][ni], 0, 0, 0);
    __builtin_amdgcn_s_setprio(0);
    asm volatile("s_waitcnt lgkmcnt(0)" ::: "memory");
    __builtin_amdgcn_s_barrier();
    asm volatile("" ::: "memory");
  }

  // phase-2 A stage (As fully free after final barrier): QX rows t0..t0+127
  half_t* P2 = &As[0][0];
#pragma unroll
  for (int i = 0; i < 4; ++i) {
    const int c = tid + i * 256;
    const int row = c >> 3, js = c & 7, jg = js ^ (row & 7);
    gld_lds16(QX + ((long)z * Tc + t0 + row) * 64 + jg * 8, P2 + c * 8);
  }
  // WT -> LDS f16 in phase-2 fragment layout (chunk swizzle js^(row&7))
#pragma unroll
  for (int mi = 0; mi < 2; ++mi)
#pragma unroll
    for (int ni = 0; ni < 2; ++ni)
#pragma unroll
      for (int reg = 0; reg < 4; ++reg) {
        const int r = wm * 32 + mi * 16 + g * 4 + reg;   // d2
        const int c = wn * 32 + ni * 16 + r16;           // d1
        WTs[r * 64 + (((c >> 3) ^ (r & 7)) << 3) + (c & 7)] =
            (half_t)(acc[mi][ni][reg] * 0.125f);
      }
  __syncthreads();   // drains vmcnt (QX stage) + lgkm (WTs writes)

  // phase 2: per wave 32 t-rows, full 64 d2 cols, K=64
  floatx4 a2[2][4];
#pragma unroll
  for (int mi = 0; mi < 2; ++mi)
#pragma unroll
    for (int ni = 0; ni < 4; ++ni) a2[mi][ni] = floatx4{0.f, 0.f, 0.f, 0.f};
  const int rA2 = wave * 32 + r16;
  half8 aF2[2][2], bF2[4][2];
#pragma unroll
  for (int mi = 0; mi < 2; ++mi)
#pragma unroll
    for (int k2 = 0; k2 < 2; ++k2)
      aF2[mi][k2] = *reinterpret_cast<const half8*>(
          &P2[(rA2 + mi * 16) * 64 + ((k2 * 4 + g) ^ (r16 & 7)) * 8]);
#pragma unroll
  for (int ni = 0; ni < 4; ++ni)
#pragma unroll
    for (int k2 = 0; k2 < 2; ++k2)
      bF2[ni][k2] = *reinterpret_cast<const half8*>(
          &WTs[(ni * 16 + r16) * 64 + ((k2 * 4 + g) ^ (r16 & 7)) * 8]);
#pragma unroll
  for (int k2 = 0; k2 < 2; ++k2)
#pragma unroll
    for (int mi = 0; mi < 2; ++mi)
#pragma unroll
      for (int ni = 0; ni < 4; ++ni)
        a2[mi][ni] = __builtin_amdgcn_mfma_f32_16x16x32_f16(
            aF2[mi][k2], bF2[ni][k2], a2[mi][ni], 0, 0, 0);
#pragma unroll
  for (int mi = 0; mi < 2; ++mi)
#pragma unroll
    for (int ni = 0; ni < 4; ++ni)
#pragma unroll
      for (int reg = 0; reg < 4; ++reg) {
        const int t = t0 + wave * 32 + mi * 16 + g * 4 + reg;
        const int c = ni * 16 + r16;
        Q2[((long)z * Tc + t) * 64 + c] = (half_t)a2[mi][ni][reg];
      }
}

// ------------------------------------------------------------ flash staging
// s-tile 64: K tile [64 s][64 d] = 8KB, V^T tile [64 d][64 s] = 8KB.
// 2 gld_lds16 per thread each (counted vmcnt relies on this).
__device__ __forceinline__ void stageK64(const half_t* Kz, int s0, half_t* dst, int tid) {
#pragma unroll
  for (int i = 0; i < 2; ++i) {
    const int c = tid + i * 256;
    const int row = c >> 3, js = c & 7;
    const int jg = js ^ (row & 7);
    gld_lds16(Kz + (long)(s0 + row) * 64 + jg * 8, dst + c * 8);
  }
}
__device__ __forceinline__ void stageV64(const half_t* Vz, int s0, int Slen, half_t* dst, int tid) {
#pragma unroll
  for (int i = 0; i < 2; ++i) {
    const int c = tid + i * 256;
    const int row = c >> 3, js = c & 7;
    const int jg = js ^ (row & 7);
    gld_lds16(Vz + (long)row * Slen + s0 + jg * 8, dst + c * 8);
  }
}

// --------------------------------------------------------- flash body (MI=2)
// 128 q-rows/block, 8 s-tiles of 64 over [sbeg, sbeg+512). R19 rhythm:
//  vmcnt(2)+barrier [K(t) ready] ; QK MFMA cluster ; issue K(t+1) ; softmax
//  (mask+exp2) ; vmcnt(2)+barrier [V(t) ready] ; PV (+ones-MFMA row-sum) ;
//  barrier ; issue V(t+1). Always partial: unnormalized O f16 + row-sum L.
// lds layout (24KB): Kb0 = lds[0..4096), Kb1 = [4096..8192), Vb = [8192..12288)
template <bool MASKED>
__device__ __forceinline__ void flash_body(
    const half_t* __restrict__ Qp, const half_t* __restrict__ Kp,
    const half_t* __restrict__ Vp, const unsigned char* __restrict__ mpk,
    half_t* __restrict__ POh, float* __restrict__ Lp,
    int Slen, int sbeg, int z, int q0, half_t* lds)
{
  const int tid = threadIdx.x, lane = tid & 63, w = tid >> 6;
  const int r16 = lane & 15, g = lane >> 4;
  const int b = z >> 3, h = z & 7;
  const int NT = Slen >> 7;                 // 128-tile count (mask indexing)
  const half_t* Qz = Qp + ((long)z * Tc + q0) * 64;
  const half_t* Kz = Kp + (long)z * Slen * 64;
  const half_t* Vz = Vp + (long)z * 64 * Slen;
  half_t* Kb0 = lds;
  half_t* Kb1 = lds + 4096;
  half_t* Vb  = lds + 8192;

  // prologue staging: K(0), V(0) (oldest 4 vmem ops, in this order)
  stageK64(Kz, sbeg, Kb0, tid);
  asm volatile("" ::: "memory");
  stageV64(Vz, sbeg, Slen, Vb, tid);
  asm volatile("" ::: "memory");

  half8 aQ[2][2];
#pragma unroll
  for (int mi = 0; mi < 2; ++mi)
#pragma unroll
    for (int k2 = 0; k2 < 2; ++k2)
      aQ[mi][k2] = *reinterpret_cast<const half8*>(
          Qz + (w * 32 + mi * 16 + r16) * 64 + k2 * 32 + g * 8);

  half8 vones;
#pragma unroll
  for (int j = 0; j < 8; ++j) vones[j] = (half_t)1.f;

  floatx4 oaccT[2][4];
  floatx4 lacc4[2];
#pragma unroll
  for (int mi = 0; mi < 2; ++mi) {
    lacc4[mi] = floatx4{0.f, 0.f, 0.f, 0.f};
#pragma unroll
    for (int no = 0; no < 4; ++no) oaccT[mi][no] = floatx4{0.f, 0.f, 0.f, 0.f};
  }

  const int send = sbeg + 512;
  int cur = 0;
  for (int s0 = sbeg; s0 < send; s0 += 64) {
    const bool hn = (s0 + 64 < send);
    // K(t) ready (V(t) = 2 newest still flying)
    asm volatile("s_waitcnt vmcnt(2)" ::: "memory");
    __builtin_amdgcn_s_barrier();
    asm volatile("" ::: "memory");

    unsigned int mb32[2];
    if constexpr (MASKED) {
      const int tile = s0 >> 7;
#pragma unroll
      for (int mi = 0; mi < 2; ++mi) {
        const int q = q0 + w * 32 + mi * 16 + r16;
        mb32[mi] = *reinterpret_cast<const unsigned int*>(
            mpk + ((long)q * NT + tile) * 16 + 4 * g);
      }
    }
    const int hf4 = ((s0 >> 6) & 1) ? 4 : 0;   // which 64-half of the 128-tile
    const unsigned int fullm = hf4 ? 0xf0f0f0f0u : 0x0f0f0f0fu;

    // S^T = K Q^T : 8 b128 reads feed 16 MFMAs
    floatx4 sacc[2][4];
#pragma unroll
    for (int mi = 0; mi < 2; ++mi)
#pragma unroll
      for (int ni = 0; ni < 4; ++ni) sacc[mi][ni] = floatx4{0.f, 0.f, 0.f, 0.f};
    const half_t* Kc = cur ? Kb1 : Kb0;
    __builtin_amdgcn_s_setprio(1);
#pragma unroll
    for (int ni = 0; ni < 4; ++ni) {
      const int rB = ni * 16 + r16;
      const half8 b0 = *reinterpret_cast<const half8*>(&Kc[rB * 64 + (g ^ (rB & 7)) * 8]);
      const half8 b1 = *reinterpret_cast<const half8*>(&Kc[rB * 64 + ((4 + g) ^ (rB & 7)) * 8]);
#pragma unroll
      for (int mi = 0; mi < 2; ++mi) {
        sacc[mi][ni] = __builtin_amdgcn_mfma_f32_16x16x32_f16(b0, aQ[mi][0], sacc[mi][ni], 0, 0, 0);
        sacc[mi][ni] = __builtin_amdgcn_mfma_f32_16x16x32_f16(b1, aQ[mi][1], sacc[mi][ni], 0, 0, 0);
      }
    }
    __builtin_amdgcn_s_setprio(0);
    // prefetch K(t+1) into the other buffer; lands under softmax+PV
    if (hn) stageK64(Kz, s0 + 64, cur ? Kb0 : Kb1, tid);
    asm volatile("" ::: "memory");

    // in-register softmax (separated phase): mask + exp2 only
#pragma unroll
    for (int mi = 0; mi < 2; ++mi) {
      if constexpr (MASKED) {
        if ((mb32[mi] & fullm) != fullm) {
#pragma unroll
          for (int reg = 0; reg < 4; ++reg)
#pragma unroll
            for (int ni = 0; ni < 4; ++ni)
              if (!((mb32[mi] >> (reg * 8 + ni + hf4)) & 1)) sacc[mi][ni][reg] = -__builtin_inff();
        }
      }
#pragma unroll
      for (int ni = 0; ni < 4; ++ni)
#pragma unroll
        for (int reg = 0; reg < 4; ++reg)
          sacc[mi][ni][reg] = __builtin_amdgcn_exp2f(sacc[mi][ni][reg]);
    }

    // V(t) ready (K(t+1) = newest 2 still in flight when hn)
    if (hn) { asm volatile("s_waitcnt vmcnt(2)" ::: "memory"); }
    else    { asm volatile("s_waitcnt vmcnt(0)" ::: "memory"); }
    __builtin_amdgcn_s_barrier();
    asm volatile("" ::: "memory");

    // O^T += V^T P^T ; l += ones·P^T (row-sum via matrix pipe)
#pragma unroll
    for (int c = 0; c < 2; ++c) {
      half8 bVv[4];
#pragma unroll
      for (int no = 0; no < 4; ++no) {
        const int rV = no * 16 + r16;
        bVv[no] = *reinterpret_cast<const half8*>(
            &Vb[rV * 64 + ((c * 4 + g) ^ (rV & 7)) * 8]);
      }
#pragma unroll
      for (int mi = 0; mi < 2; ++mi) {
        // butterfly P^T frag: target word p_t at lane g <-
        // pk[2c+(g>>1)][p_t&1] of lane 2(g&1)+(p_t>>1)
        int x0 = pkrtz(sacc[mi][2 * c][0],     sacc[mi][2 * c][1]);
        int x1 = pkrtz(sacc[mi][2 * c][2],     sacc[mi][2 * c][3]);
        int x2 = pkrtz(sacc[mi][2 * c + 1][0], sacc[mi][2 * c + 1][1]);
        int x3 = pkrtz(sacc[mi][2 * c + 1][2], sacc[mi][2 * c + 1][3]);
        pl32(x0, x2); pl32(x1, x3);   // resolve g1 <-> ni bit
        pl16(x0, x2); pl16(x1, x3);   // resolve g0 <-> word bit
        int4v wv; wv[0] = x0; wv[1] = x1; wv[2] = x2; wv[3] = x3;
        const half8 aP = __builtin_bit_cast(half8, wv);
        __builtin_amdgcn_s_setprio(1);
#pragma unroll
        for (int no = 0; no < 4; ++no)
          oaccT[mi][no] = __builtin_amdgcn_mfma_f32_16x16x32_f16(bVv[no], aP, oaccT[mi][no], 0, 0, 0);
        lacc4[mi] = __builtin_amdgcn_mfma_f32_16x16x32_f16(vones, aP, lacc4[mi], 0, 0, 0);
        __builtin_amdgcn_s_setprio(0);
      }
    }
    __builtin_amdgcn_s_barrier();
    asm volatile("" ::: "memory");
    // prefetch V(t+1); lands under next tile's QK^T + softmax
    if (hn) stageV64(Vz, s0 + 64, Slen, Vb, tid);
    asm volatile("" ::: "memory");
    cur ^= 1;
  }

  // epilogue: l_q sits in every lane's lacc4[mi][0] (col=lane&15=q).
  // per-wave f32 slab (4KB) lives in the Kb0/Kb1 region (16KB, reads done:
  // all waves passed the post-PV barrier after their last QK/PV reads).
  float ls2[2];
#pragma unroll
  for (int mi = 0; mi < 2; ++mi) ls2[mi] = lacc4[mi][0];

  float* slab = reinterpret_cast<float*>(lds) + w * 1024;
#pragma unroll
  for (int mi = 0; mi < 2; ++mi) {
    const int tq = q0 + w * 32 + mi * 16;
    if (lane < 16) Lp[(long)z * Tc + tq + r16] = ls2[mi];
#pragma unroll
    for (int no = 0; no < 4; ++no) {
      floatx4 v = oaccT[mi][no];
      *reinterpret_cast<floatx4*>(&slab[r16 * 64 + no * 16 + (g ^ (r16 & 3)) * 4]) = v;
    }
#pragma unroll
    for (int it = 0; it < 4; ++it) {
      const int q2 = it * 4 + g;
      const int d4 = r16;
      const floatx4 v = *reinterpret_cast<const floatx4*>(
          &slab[q2 * 64 + (d4 >> 2) * 16 + ((d4 & 3) ^ (q2 & 3)) * 4]);
      const long off = ((long)(b * Tc + tq + q2)) * Cc + h * 64 + d4 * 4;
      half4v hh; hh[0] = (half_t)v[0]; hh[1] = (half_t)v[1];
      hh[2] = (half_t)v[2]; hh[3] = (half_t)v[3];
      *reinterpret_cast<half4v*>(&POh[off]) = hh;   // unnormalized f16
    }
  }
}

// 1536 blocks, each exactly 8 s-tiles of 64 (24KB LDS; launch_bounds(256,4)
// keeps natural regalloc — no spills — VGPRs decide 4-5 blocks/CU):
//  bx < 1024: att0 (chained, masked), s-quarter qt -> slabs 0-3
//  bx >= 1024: att1 (first), s-half sh -> slabs 4-5
__global__ __launch_bounds__(256, 4) void flash_both(
    const half_t* __restrict__ Q2, const half_t* __restrict__ KX,
    const half_t* __restrict__ VXT, const unsigned char* __restrict__ mpk,
    const half_t* __restrict__ QX, const half_t* __restrict__ KY,
    const half_t* __restrict__ VYT,
    half_t* __restrict__ POh, float* __restrict__ Lp)
{
  __shared__ __align__(16) half_t lds[12288];   // 24 KB
  const int bx = blockIdx.x;
  if (bx < 1024) {
    const int z  = ((bx & 7) << 1) | ((bx >> 3) & 1);   // z-local per XCD
    const int qt = (bx >> 4) & 3;
    const int q0 = (bx >> 6) * 128;
    flash_body<true>(Q2, KX, VXT, mpk,
                     POh + (long)qt * BTC, Lp + (long)qt * ZT,
                     Tc, qt * 512, z, q0, lds);
  } else {
    const int b2 = bx - 1024;
    const int z  = ((b2 & 7) << 1) | ((b2 >> 3) & 1);
    const int sh = (b2 >> 4) & 1;
    const int q0 = (b2 >> 5) * 128;
    flash_body<false>(QX, KY, VYT, nullptr,
                      POh + (long)(4 + sh) * BTC, Lp + (long)(4 + sh) * ZT,
                      Mc, sh * 512, z, q0, lds);
  }
}

// --------------------------- combine 6 slabs -> DH
// DH = (O4+O5)/(l4+l5) - (O0+O1+O2+O3)/(l0+l1+l2+l3)
__global__ __launch_bounds__(256) void combine_k(
    const half_t* __restrict__ POh, const float* __restrict__ Lp,
    half_t* __restrict__ DH)
{
  const long idx = (long)blockIdx.x * 256 + threadIdx.x;   // over BTC/4
  const long c4 = idx * 4;
  const int c = (int)(c4 & (Cc - 1));
  const long bt = c4 >> 9;
  const int h = c >> 6;
  const int b = (int)(bt >> 11), t = (int)(bt & (Tc - 1));
  const long zt = (long)(b * Hc + h) * Tc + t;
  const float i0 = 1.f / (Lp[zt] + Lp[ZT + zt] + Lp[2 * ZT + zt] + Lp[3 * ZT + zt]);
  const float i1 = 1.f / (Lp[4 * ZT + zt] + Lp[5 * ZT + zt]);
  float a0[4] = {0.f, 0.f, 0.f, 0.f}, a1[4] = {0.f, 0.f, 0.f, 0.f};
#pragma unroll
  for (int s = 0; s < 4; ++s) {
    const half4v o = reinterpret_cast<const half4v*>(POh)[s * (BTC / 4) + idx];
#pragma unroll
    for (int j = 0; j < 4; ++j) a0[j] += (float)o[j];
  }
#pragma unroll
  for (int s = 4; s < 6; ++s) {
    const half4v o = reinterpret_cast<const half4v*>(POh)[s * (BTC / 4) + idx];
#pragma unroll
    for (int j = 0; j < 4; ++j) a1[j] += (float)o[j];
  }
  half4v r;
#pragma unroll
  for (int j = 0; j < 4; ++j) r[j] = (half_t)(a1[j] * i1 - a0[j] * i0);
  reinterpret_cast<half4v*>(DH)[idx] = r;
}

// ----------------------------------------------- prep: converts + mask pack
__device__ __forceinline__ void cvt4(const float* in, half_t* out, long i) {
  const float4 f = reinterpret_cast<const float4*>(in)[i];
  half4v h; h[0] = (half_t)f.x; h[1] = (half_t)f.y; h[2] = (half_t)f.z; h[3] = (half_t)f.w;
  reinterpret_cast<half4v*>(out)[i] = h;
}

__global__ __launch_bounds__(256) void prep(
    const float* __restrict__ x, const float* __restrict__ y,
    const float* __restrict__ qw, const float* __restrict__ pw,
    const int* __restrict__ mask,
    half_t* __restrict__ XH, half_t* __restrict__ YH,
    half_t* __restrict__ WQ, half_t* __restrict__ WP,
    unsigned char* __restrict__ mpk)
{
  const long i = (long)blockIdx.x * 256 + threadIdx.x;
  constexpr long n0 = 524288;            // x/4
  constexpr long n1 = n0 + 262144;       // y/4
  constexpr long n2 = n1 + 196608;       // qkv_w/4
  constexpr long n3 = n2 + 65536;        // proj_w/4
  if (i < n0) cvt4(x, XH, i);
  else if (i < n1) cvt4(y, YH, i - n0);
  else if (i < n2) cvt4(qw, WQ, i - n1);
  else if (i < n3) cvt4(pw, WP, i - n2);
  else {
    const long idx = i - n3;             // [0, Tc*256)
    const int t = (int)(idx >> 8), tile = (int)((idx >> 4) & 15), r16 = (int)(idx & 15);
    const int* row = mask + (long)t * Tc + tile * 128 + r16;
    unsigned int bbits = 0;
#pragma unroll
    for (int ni = 0; ni < 8; ++ni)
      bbits |= (row[ni * 16] != 0 ? 1u : 0u) << ni;
    mpk[idx] = (unsigned char)bbits;
  }
}

// ------------------------------------------------------------- workspace map
constexpr size_t OFF_XH   = 0;                                   // [B*T,C] f16 (YH must follow!)
constexpr size_t OFF_YH   = OFF_XH   + (size_t)Bc*Tc*Cc*2;       // contiguous rows after XH
constexpr size_t OFF_WQ   = OFF_YH   + (size_t)Bc*Mc*Cc*2;
constexpr size_t OFF_WP   = OFF_WQ   + (size_t)3*Cc*Cc*2;
constexpr size_t OFF_QX   = OFF_WP   + (size_t)Cc*Cc*2;          // [z,T,D] *0.125*log2e
constexpr size_t OFF_KX   = OFF_QX   + (size_t)Bc*Hc*Tc*Dc*2;    // [z,T,D]
constexpr size_t OFF_VXT  = OFF_KX   + (size_t)Bc*Hc*Tc*Dc*2;    // [z,D,T]
constexpr size_t OFF_QYT  = OFF_VXT  + (size_t)Bc*Hc*Tc*Dc*2;    // [z,D,M] *0.125
constexpr size_t OFF_KY   = OFF_QYT  + (size_t)Bc*Hc*Mc*Dc*2;    // [z,M,D]
constexpr size_t OFF_KYT  = OFF_KY   + (size_t)Bc*Hc*Mc*Dc*2;    // [z,D,M]
constexpr size_t OFF_VYT  = OFF_KYT  + (size_t)Bc*Hc*Mc*Dc*2;    // [z,D,M]
constexpr size_t OFF_Q2   = OFF_VYT  + (size_t)Bc*Hc*Mc*Dc*2;    // [z,T,D]
constexpr size_t OFF_DH   = OFF_Q2   + (size_t)Bc*Hc*Tc*Dc*2;    // [B,T,C] diff f16
constexpr size_t OFF_MPK  = OFF_DH   + (size_t)Bc*Tc*Cc*2;       // [T,16,16] u8
constexpr size_t OFF_PO   = OFF_MPK  + (size_t)Tc*256;           // [6][B,T,C] f16 unnormalized
constexpr size_t OFF_L    = OFF_PO   + (size_t)6*BTC*2;          // [6][ZT] f32 row sums
// total ~65 MB

extern "C" void kernel_launch(void* const* d_in, const int* in_sizes, int n_in,
                              void* d_out, int out_size, void* d_ws, size_t ws_size,
                              hipStream_t stream) {
  const float* x      = (const float*)d_in[0];
  const float* y      = (const float*)d_in[1];
  const int*   mask   = (const int*)  d_in[2];
  const float* qkv_b  = (const float*)d_in[4];
  const float* proj_b = (const float*)d_in[6];
  float* out = (float*)d_out;
  char* ws = (char*)d_ws;

  half_t* XH   = (half_t*)(ws + OFF_XH);
  half_t* YH   = (half_t*)(ws + OFF_YH);
  half_t* WQ   = (half_t*)(ws + OFF_WQ);
  half_t* WP   = (half_t*)(ws + OFF_WP);
  half_t* QX   = (half_t*)(ws + OFF_QX);
  half_t* KX   = (half_t*)(ws + OFF_KX);
  half_t* VXT  = (half_t*)(ws + OFF_VXT);
  half_t* QYT  = (half_t*)(ws + OFF_QYT);
  half_t* KY   = (half_t*)(ws + OFF_KY);
  half_t* KYT  = (half_t*)(ws + OFF_KYT);
  half_t* VYT  = (half_t*)(ws + OFF_VYT);
  half_t* Q2   = (half_t*)(ws + OFF_Q2);
  half_t* DH   = (half_t*)(ws + OFF_DH);
  unsigned char* MPK = (unsigned char*)(ws + OFF_MPK);
  half_t* POh  = (half_t*)(ws + OFF_PO);
  float*  Lp   = (float*) (ws + OFF_L);

  // converts + mask packing (one launch)
  prep<<<6144, 256, 0, stream>>>(x, y, (const float*)d_in[3], (const float*)d_in[5],
                                 mask, XH, YH, WQ, WP, MPK);

  // fused qkv projection for x and y (XH||YH contiguous: 6144 rows)
  {
    EpiParams ep{};
    ep.h0 = QX; ep.h1 = KX; ep.h2 = VXT; ep.h3 = QYT;
    ep.h4 = KY; ep.h5 = KYT; ep.h6 = VYT; ep.bias = qkv_b;
    gemm_nt<128,64,2,2,EPI_QKV_XY,24,48><<<dim3(24, 48, 1), 256, 0, stream>>>(
        XH, WQ, Cc, Cc, Cc, 0, 0, ep);
  }

  // fused WT+Q2: 256 flat blocks, XCD remap (2 z per XCD)
  wtq2<<<dim3(256), 256, 0, stream>>>(QYT, KYT, QX, Q2);

  // occupancy-unlocked flash: 1024 att0-quarter + 512 att1-half = 1536
  flash_both<<<dim3(1536), 256, 0, stream>>>(
      Q2, KX, VXT, MPK, QX, KY, VYT, POh, Lp);

  // combine 6 slabs -> DH
  combine_k<<<(int)(BTC/4/256), 256, 0, stream>>>(POh, Lp, DH);

  // out = DH @ proj_w^T + proj_b  (XCD remap: 8 A-panels per XCD)
  {
    EpiParams ep{}; ep.f0 = out; ep.bias = proj_b;
    gemm_nt<64,64,2,2,EPI_PROJ,8,64><<<dim3(8, 64, 1), 256, 0, stream>>>(
        DH, WP, Cc, Cc, Cc, 0, 0, ep);
  }
}